// Round 2
// baseline (993.665 us; speedup 1.0000x reference)
//
#include <hip/hip_runtime.h>

#define STEPS 64
#define NUM_CPU 4
#define AGENTS 64
#define PHASES 8
#define FEATS 16
#define GNN 64
#define NN (STEPS*NUM_CPU*AGENTS*PHASES)   // 131072 nodes
#define NE (NN*8)                          // 1048576 edges
#define ROWS (NN/PHASES)                   // 16384 MLP rows
#define MLPW 256

// ---------------- layer 0: edge aggregate (16 feats) ----------------
__global__ __launch_bounds__(256) void k_edge0(const float* __restrict__ obs,
                                               const int* __restrict__ edge,
                                               float* __restrict__ agg0,
                                               float* __restrict__ deg) {
    int tid = blockIdx.x * 256 + threadIdx.x;      // NE*16 threads
    int e = tid >> 4, f = tid & 15;
    if (e >= NE) return;
    int src = edge[e];
    int dst = edge[NE + e];
    atomicAdd(&agg0[dst * 16 + f], obs[src * 16 + f]);
    if (f == 0) atomicAdd(&deg[dst], 1.0f);
}

// ---------------- layer 0: node transform -> h0 [N,128] ----------------
__global__ __launch_bounds__(256) void k_node0(const float* __restrict__ obs,
                                               const float* __restrict__ agg0,
                                               const float* __restrict__ deg,
                                               const float* __restrict__ ws0,
                                               const float* __restrict__ bs0,
                                               const float* __restrict__ wn0,
                                               const float* __restrict__ bn0,
                                               float* __restrict__ h0) {
    int node = blockIdx.x * 4 + (threadIdx.x >> 6);
    int j = threadIdx.x & 63;
    if (node >= NN) return;
    float d = deg[node]; d = d < 1.f ? 1.f : d;
    float inv = 1.f / d;
    float s = bs0[j], n = bn0[j];
    const float* x = obs + node * 16;
    const float* a = agg0 + node * 16;
#pragma unroll
    for (int k = 0; k < 16; ++k) {
        s += x[k] * ws0[k * 64 + j];
        n += (a[k] * inv) * wn0[k * 64 + j];
    }
    h0[node * 128 + j]      = s > 0.f ? s : 0.f;
    h0[node * 128 + 64 + j] = n > 0.f ? n : 0.f;
}

// ---------------- layer 1 pre-transform: y1 = h0 @ Wn1  [N,64] --------
// (mean is linear: aggregate the transformed vectors, 2x less edge traffic)
__global__ __launch_bounds__(256) void k_y1(const float* __restrict__ h0,
                                            const float* __restrict__ wn1,
                                            float* __restrict__ y1) {
    __shared__ float w[128 * 64];
    for (int t = threadIdx.x; t < 128 * 64; t += 256) w[t] = wn1[t];
    __syncthreads();
    int wv = threadIdx.x >> 6, j = threadIdx.x & 63;
    for (int node = blockIdx.x * 4 + wv; node < NN; node += gridDim.x * 4) {
        const float* x = h0 + (size_t)node * 128;
        float acc = 0.f;
#pragma unroll 8
        for (int k = 0; k < 128; ++k) acc += x[k] * w[k * 64 + j];
        y1[node * 64 + j] = acc;
    }
}

// ---------------- layer 1: edge aggregate (64 transformed feats) ------
__global__ __launch_bounds__(256) void k_edge1(const float* __restrict__ y1,
                                               const int* __restrict__ edge,
                                               float* __restrict__ agg1) {
    int tid = blockIdx.x * 256 + threadIdx.x;      // NE*64 threads
    int e = tid >> 6, f = tid & 63;
    if (e >= NE) return;
    int src = edge[e];
    int dst = edge[NE + e];
    atomicAdd(&agg1[dst * 64 + f], y1[src * 64 + f]);
}

// ---------------- layer 1: node transform -> h1 [N,128] ---------------
__global__ __launch_bounds__(256) void k_node1(const float* __restrict__ h0,
                                               const float* __restrict__ agg1,
                                               const float* __restrict__ deg,
                                               const float* __restrict__ ws1,
                                               const float* __restrict__ bs1,
                                               const float* __restrict__ bn1,
                                               float* __restrict__ h1) {
    __shared__ float w[128 * 64];
    for (int t = threadIdx.x; t < 128 * 64; t += 256) w[t] = ws1[t];
    __syncthreads();
    int wv = threadIdx.x >> 6, j = threadIdx.x & 63;
    for (int node = blockIdx.x * 4 + wv; node < NN; node += gridDim.x * 4) {
        float d = deg[node]; d = d < 1.f ? 1.f : d;
        float inv = 1.f / d;
        const float* x = h0 + (size_t)node * 128;
        float s = bs1[j];
#pragma unroll 8
        for (int k = 0; k < 128; ++k) s += x[k] * w[k * 64 + j];
        float n = agg1[node * 64 + j] * inv + bn1[j];
        h1[node * 128 + j]      = s > 0.f ? s : 0.f;
        h1[node * 128 + 64 + j] = n > 0.f ? n : 0.f;
    }
}

// ---------------- fused MLP: [16384,1024] -> 256 -> 256 -> 1 ----------
__global__ __launch_bounds__(256) void k_mlp(const float* __restrict__ h1,
                                             const float* __restrict__ w0,
                                             const float* __restrict__ b0,
                                             const float* __restrict__ w1,
                                             const float* __restrict__ b1,
                                             const float* __restrict__ w2,
                                             const float* __restrict__ b2,
                                             float* __restrict__ out) {
    __shared__ float xs[16 * 1024];                // 64 KB
    const int tid = threadIdx.x;
    const int row0 = blockIdx.x * 16;
    const float* base = h1 + (size_t)row0 * 1024;
    for (int t = tid; t < 16 * 1024; t += 256) xs[t] = base[t];
    __syncthreads();

    // layer 0: 1024 -> 256, thread = output column
    float acc[16];
#pragma unroll
    for (int r = 0; r < 16; ++r) acc[r] = b0[tid];
    for (int k = 0; k < 1024; k += 4) {
        float w4[4];
#pragma unroll
        for (int kk = 0; kk < 4; ++kk) w4[kk] = w0[(k + kk) * 256 + tid];
#pragma unroll
        for (int r = 0; r < 16; ++r) {
            float4 xv = *(const float4*)&xs[r * 1024 + k];
            acc[r] += xv.x * w4[0] + xv.y * w4[1] + xv.z * w4[2] + xv.w * w4[3];
        }
    }
    __syncthreads();                               // done reading rows
#pragma unroll
    for (int r = 0; r < 16; ++r) xs[r * 256 + tid] = tanhf(acc[r]);
    __syncthreads();

    // layer 1: 256 -> 256
    float acc2[16];
#pragma unroll
    for (int r = 0; r < 16; ++r) acc2[r] = b1[tid];
    for (int k = 0; k < 256; k += 4) {
        float w4[4];
#pragma unroll
        for (int kk = 0; kk < 4; ++kk) w4[kk] = w1[(k + kk) * 256 + tid];
#pragma unroll
        for (int r = 0; r < 16; ++r) {
            float4 xv = *(const float4*)&xs[r * 256 + k];
            acc2[r] += xv.x * w4[0] + xv.y * w4[1] + xv.z * w4[2] + xv.w * w4[3];
        }
    }
    __syncthreads();
#pragma unroll
    for (int r = 0; r < 16; ++r) xs[4096 + r * 256 + tid] = tanhf(acc2[r]);
    __syncthreads();

    // layer 2: 256 -> 1, one wave handles 4 rows
    const int wv = tid >> 6, l = tid & 63;
    for (int rr = 0; rr < 4; ++rr) {
        int r = wv * 4 + rr;
        const float* x2 = &xs[4096 + r * 256];
        float p = 0.f;
#pragma unroll
        for (int c = 0; c < 4; ++c) p += x2[c * 64 + l] * w2[c * 64 + l];
        for (int off = 32; off; off >>= 1) p += __shfl_down(p, off);
        if (l == 0) out[row0 + r] = p + b2[0];
    }
}

extern "C" void kernel_launch(void* const* d_in, const int* in_sizes, int n_in,
                              void* d_out, int out_size, void* d_ws, size_t ws_size,
                              hipStream_t stream) {
    const float* obs  = (const float*)d_in[0];
    const int*   edge = (const int*)d_in[1];
    const float* ws0  = (const float*)d_in[2];
    const float* bs0  = (const float*)d_in[3];
    const float* wn0  = (const float*)d_in[4];
    const float* bn0  = (const float*)d_in[5];
    const float* ws1  = (const float*)d_in[6];
    const float* bs1  = (const float*)d_in[7];
    const float* wn1  = (const float*)d_in[8];
    const float* bn1  = (const float*)d_in[9];
    const float* w0   = (const float*)d_in[10];
    const float* b0   = (const float*)d_in[11];
    const float* w1   = (const float*)d_in[12];
    const float* b1   = (const float*)d_in[13];
    const float* w2   = (const float*)d_in[14];
    const float* b2   = (const float*)d_in[15];
    float* out = (float*)d_out;

    float* ws   = (float*)d_ws;
    float* agg0 = ws;                         // NN*16
    float* deg  = agg0 + (size_t)NN * 16;     // NN
    float* h0   = deg  + NN;                  // NN*128
    float* y1   = h0   + (size_t)NN * 128;    // NN*64
    float* agg1 = y1   + (size_t)NN * 64;     // NN*64
    float* h1   = agg1 + (size_t)NN * 64;     // NN*128

    hipMemsetAsync(agg0, 0, (size_t)NN * 16 * sizeof(float), stream);
    hipMemsetAsync(deg,  0, (size_t)NN * sizeof(float), stream);
    hipMemsetAsync(agg1, 0, (size_t)NN * 64 * sizeof(float), stream);

    k_edge0<<<dim3((NE * 16) / 256), dim3(256), 0, stream>>>(obs, edge, agg0, deg);
    k_node0<<<dim3(NN / 4), dim3(256), 0, stream>>>(obs, agg0, deg, ws0, bs0, wn0, bn0, h0);
    k_y1<<<dim3(8192), dim3(256), 0, stream>>>(h0, wn1, y1);
    k_edge1<<<dim3((NE * 64) / 256), dim3(256), 0, stream>>>(y1, edge, agg1);
    k_node1<<<dim3(8192), dim3(256), 0, stream>>>(h0, agg1, deg, ws1, bs1, bn1, h1);
    k_mlp<<<dim3(ROWS / 16), dim3(256), 0, stream>>>(h1, w0, b0, w1, b1, w2, b2, out);
}

// Round 3
// 979.823 us; speedup vs baseline: 1.0141x; 1.0141x over previous
//
#include <hip/hip_runtime.h>

#define STEPS 64
#define NUM_CPU 4
#define AGENTS 64
#define PHASES 8
#define FEATS 16
#define GNN 64
#define NN (STEPS*NUM_CPU*AGENTS*PHASES)   // 131072 nodes
#define NE (NN*8)                          // 1048576 edges
#define ROWS (NN/PHASES)                   // 16384 MLP rows
#define MLPW 256

// ================= CSR construction (counting sort by dst) =============
__global__ __launch_bounds__(256) void k_hist(const int* __restrict__ edge,
                                              int* __restrict__ deg_i) {
    int e = blockIdx.x * 256 + threadIdx.x;
    if (e < NE) atomicAdd(&deg_i[edge[NE + e]], 1);
}

// exclusive scan of deg_i[NN] -> off[NN+1]; also seed cursor = off
__global__ __launch_bounds__(1024) void k_scan(const int* __restrict__ deg_i,
                                               int* __restrict__ off,
                                               int* __restrict__ cursor) {
    __shared__ int s[1024];
    const int t = threadIdx.x;
    const int base = t * (NN / 1024);          // 128 nodes per thread
    int loc[NN / 1024];
    int sum = 0;
    for (int i = 0; i < NN / 1024; ++i) { loc[i] = sum; sum += deg_i[base + i]; }
    s[t] = sum;
    __syncthreads();
    // Hillis-Steele inclusive scan over 1024 partials
    for (int d = 1; d < 1024; d <<= 1) {
        int v = (t >= d) ? s[t - d] : 0;
        __syncthreads();
        s[t] += v;
        __syncthreads();
    }
    int pre = s[t] - sum;                      // exclusive prefix for this thread
    for (int i = 0; i < NN / 1024; ++i) {
        int o = pre + loc[i];
        off[base + i] = o;
        cursor[base + i] = o;
    }
    if (t == 1023) off[NN] = s[1023];
}

__global__ __launch_bounds__(256) void k_scatter(const int* __restrict__ edge,
                                                 int* __restrict__ cursor,
                                                 int* __restrict__ csr) {
    int e = blockIdx.x * 256 + threadIdx.x;
    if (e >= NE) return;
    int dst = edge[NE + e];
    int pos = atomicAdd(&cursor[dst], 1);
    csr[pos] = edge[e];
}

// ================= layer 0: per-node aggregate of obs (16 feats) ========
__global__ __launch_bounds__(256) void k_agg0(const float* __restrict__ obs,
                                              const int* __restrict__ off,
                                              const int* __restrict__ csr,
                                              float* __restrict__ agg0) {
    int gid = blockIdx.x * 256 + threadIdx.x;  // NN*16 threads
    int node = gid >> 4, f = gid & 15;
    if (node >= NN) return;
    int e0 = off[node], e1 = off[node + 1];
    float s = 0.f;
    for (int e = e0; e < e1; ++e) s += obs[csr[e] * 16 + f];
    agg0[node * 16 + f] = s;
}

// ================= layer 0: node transform -> h0 [N,128] ================
__global__ __launch_bounds__(256) void k_node0(const float* __restrict__ obs,
                                               const float* __restrict__ agg0,
                                               const int* __restrict__ off,
                                               const float* __restrict__ ws0,
                                               const float* __restrict__ bs0,
                                               const float* __restrict__ wn0,
                                               const float* __restrict__ bn0,
                                               float* __restrict__ h0) {
    int node = blockIdx.x * 4 + (threadIdx.x >> 6);
    int j = threadIdx.x & 63;
    if (node >= NN) return;
    int d = off[node + 1] - off[node];
    float inv = 1.f / (float)(d < 1 ? 1 : d);
    float s = bs0[j], n = bn0[j];
    const float* x = obs + node * 16;
    const float* a = agg0 + node * 16;
#pragma unroll
    for (int k = 0; k < 16; ++k) {
        s += x[k] * ws0[k * 64 + j];
        n += (a[k] * inv) * wn0[k * 64 + j];
    }
    h0[node * 128 + j]      = s > 0.f ? s : 0.f;
    h0[node * 128 + 64 + j] = n > 0.f ? n : 0.f;
}

// ====== layer 1 pre-transform: y1 = h0 @ Wn1  [N,64] (mean is linear) ===
__global__ __launch_bounds__(256) void k_y1(const float* __restrict__ h0,
                                            const float* __restrict__ wn1,
                                            float* __restrict__ y1) {
    __shared__ float w[128 * 64];
    for (int t = threadIdx.x; t < 128 * 64; t += 256) w[t] = wn1[t];
    __syncthreads();
    int wv = threadIdx.x >> 6, j = threadIdx.x & 63;
    for (int node = blockIdx.x * 4 + wv; node < NN; node += gridDim.x * 4) {
        const float* x = h0 + (size_t)node * 128;
        float acc = 0.f;
#pragma unroll 8
        for (int k = 0; k < 128; ++k) acc += x[k] * w[k * 64 + j];
        y1[node * 64 + j] = acc;
    }
}

// ============ layer 1: per-node aggregate of y1 (64 feats) ==============
__global__ __launch_bounds__(256) void k_agg1(const float* __restrict__ y1,
                                              const int* __restrict__ off,
                                              const int* __restrict__ csr,
                                              float* __restrict__ agg1) {
    int node = blockIdx.x * 4 + (threadIdx.x >> 6);
    int lane = threadIdx.x & 63;
    if (node >= NN) return;
    int e0 = off[node], e1 = off[node + 1];
    float s = 0.f;
    for (int e = e0; e < e1; ++e) s += y1[csr[e] * 64 + lane];
    agg1[node * 64 + lane] = s;
}

// ================= layer 1: node transform -> h1 [N,128] ================
__global__ __launch_bounds__(256) void k_node1(const float* __restrict__ h0,
                                               const float* __restrict__ agg1,
                                               const int* __restrict__ off,
                                               const float* __restrict__ ws1,
                                               const float* __restrict__ bs1,
                                               const float* __restrict__ bn1,
                                               float* __restrict__ h1) {
    __shared__ float w[128 * 64];
    for (int t = threadIdx.x; t < 128 * 64; t += 256) w[t] = ws1[t];
    __syncthreads();
    int wv = threadIdx.x >> 6, j = threadIdx.x & 63;
    for (int node = blockIdx.x * 4 + wv; node < NN; node += gridDim.x * 4) {
        int d = off[node + 1] - off[node];
        float inv = 1.f / (float)(d < 1 ? 1 : d);
        const float* x = h0 + (size_t)node * 128;
        float s = bs1[j];
#pragma unroll 8
        for (int k = 0; k < 128; ++k) s += x[k] * w[k * 64 + j];
        float n = agg1[node * 64 + j] * inv + bn1[j];
        h1[node * 128 + j]      = s > 0.f ? s : 0.f;
        h1[node * 128 + 64 + j] = n > 0.f ? n : 0.f;
    }
}

// ============ fused MLP: [16384,1024] -> 256 -> 256 -> 1 ================
__global__ __launch_bounds__(256) void k_mlp(const float* __restrict__ h1,
                                             const float* __restrict__ w0,
                                             const float* __restrict__ b0,
                                             const float* __restrict__ w1,
                                             const float* __restrict__ b1,
                                             const float* __restrict__ w2,
                                             const float* __restrict__ b2,
                                             float* __restrict__ out) {
    __shared__ float xs[16 * 1024];                // 64 KB
    const int tid = threadIdx.x;
    const int row0 = blockIdx.x * 16;
    const float* base = h1 + (size_t)row0 * 1024;
    for (int t = tid; t < 16 * 1024; t += 256) xs[t] = base[t];
    __syncthreads();

    float acc[16];
#pragma unroll
    for (int r = 0; r < 16; ++r) acc[r] = b0[tid];
    for (int k = 0; k < 1024; k += 4) {
        float w4[4];
#pragma unroll
        for (int kk = 0; kk < 4; ++kk) w4[kk] = w0[(k + kk) * 256 + tid];
#pragma unroll
        for (int r = 0; r < 16; ++r) {
            float4 xv = *(const float4*)&xs[r * 1024 + k];
            acc[r] += xv.x * w4[0] + xv.y * w4[1] + xv.z * w4[2] + xv.w * w4[3];
        }
    }
    __syncthreads();
#pragma unroll
    for (int r = 0; r < 16; ++r) xs[r * 256 + tid] = tanhf(acc[r]);
    __syncthreads();

    float acc2[16];
#pragma unroll
    for (int r = 0; r < 16; ++r) acc2[r] = b1[tid];
    for (int k = 0; k < 256; k += 4) {
        float w4[4];
#pragma unroll
        for (int kk = 0; kk < 4; ++kk) w4[kk] = w1[(k + kk) * 256 + tid];
#pragma unroll
        for (int r = 0; r < 16; ++r) {
            float4 xv = *(const float4*)&xs[r * 256 + k];
            acc2[r] += xv.x * w4[0] + xv.y * w4[1] + xv.z * w4[2] + xv.w * w4[3];
        }
    }
    __syncthreads();
#pragma unroll
    for (int r = 0; r < 16; ++r) xs[4096 + r * 256 + tid] = tanhf(acc2[r]);
    __syncthreads();

    const int wv = tid >> 6, l = tid & 63;
    for (int rr = 0; rr < 4; ++rr) {
        int r = wv * 4 + rr;
        const float* x2 = &xs[4096 + r * 256];
        float p = 0.f;
#pragma unroll
        for (int c = 0; c < 4; ++c) p += x2[c * 64 + l] * w2[c * 64 + l];
        for (int off2 = 32; off2; off2 >>= 1) p += __shfl_down(p, off2);
        if (l == 0) out[row0 + r] = p + b2[0];
    }
}

extern "C" void kernel_launch(void* const* d_in, const int* in_sizes, int n_in,
                              void* d_out, int out_size, void* d_ws, size_t ws_size,
                              hipStream_t stream) {
    const float* obs  = (const float*)d_in[0];
    const int*   edge = (const int*)d_in[1];
    const float* ws0  = (const float*)d_in[2];
    const float* bs0  = (const float*)d_in[3];
    const float* wn0  = (const float*)d_in[4];
    const float* bn0  = (const float*)d_in[5];
    const float* ws1  = (const float*)d_in[6];
    const float* bs1  = (const float*)d_in[7];
    const float* wn1  = (const float*)d_in[8];
    const float* bn1  = (const float*)d_in[9];
    const float* w0   = (const float*)d_in[10];
    const float* b0   = (const float*)d_in[11];
    const float* w1   = (const float*)d_in[12];
    const float* b1   = (const float*)d_in[13];
    const float* w2   = (const float*)d_in[14];
    const float* b2   = (const float*)d_in[15];
    float* out = (float*)d_out;

    // workspace layout (floats/ints, 4B units)
    char* wsb = (char*)d_ws;
    int*   deg_i  = (int*)wsb;                                  // NN
    int*   off    = deg_i + NN;                                 // NN+1
    int*   cursor = off + NN + 1;                               // NN
    int*   csr    = cursor + NN;                                // NE
    float* agg0   = (float*)(csr + NE);                         // NN*16
    float* h0     = agg0 + (size_t)NN * 16;                     // NN*128
    float* y1     = h0   + (size_t)NN * 128;                    // NN*64
    float* agg1   = y1   + (size_t)NN * 64;                     // NN*64
    float* h1     = agg1 + (size_t)NN * 64;                     // NN*128

    hipMemsetAsync(deg_i, 0, (size_t)NN * sizeof(int), stream);

    k_hist   <<<dim3(NE / 256),        dim3(256),  0, stream>>>(edge, deg_i);
    k_scan   <<<dim3(1),               dim3(1024), 0, stream>>>(deg_i, off, cursor);
    k_scatter<<<dim3(NE / 256),        dim3(256),  0, stream>>>(edge, cursor, csr);

    k_agg0   <<<dim3(NN * 16 / 256),   dim3(256),  0, stream>>>(obs, off, csr, agg0);
    k_node0  <<<dim3(NN / 4),          dim3(256),  0, stream>>>(obs, agg0, off, ws0, bs0, wn0, bn0, h0);
    k_y1     <<<dim3(8192),            dim3(256),  0, stream>>>(h0, wn1, y1);
    k_agg1   <<<dim3(NN / 4),          dim3(256),  0, stream>>>(y1, off, csr, agg1);
    k_node1  <<<dim3(8192),            dim3(256),  0, stream>>>(h0, agg1, off, ws1, bs1, bn1, h1);
    k_mlp    <<<dim3(ROWS / 16),       dim3(256),  0, stream>>>(h1, w0, b0, w1, b1, w2, b2, out);
}

// Round 4
// 860.139 us; speedup vs baseline: 1.1552x; 1.1391x over previous
//
#include <hip/hip_runtime.h>

#define STEPS 64
#define NUM_CPU 4
#define AGENTS 64
#define PHASES 8
#define FEATS 16
#define GNN 64
#define NN (STEPS*NUM_CPU*AGENTS*PHASES)   // 131072 nodes
#define NE (NN*8)                          // 1048576 edges
#define ROWS (NN/PHASES)                   // 16384 MLP rows
#define MLPW 256

// ================= CSR construction (counting sort by dst) =============
__global__ __launch_bounds__(256) void k_hist(const int* __restrict__ edge,
                                              int* __restrict__ deg_i) {
    int e = blockIdx.x * 256 + threadIdx.x;
    if (e < NE) atomicAdd(&deg_i[edge[NE + e]], 1);
}

__global__ __launch_bounds__(1024) void k_scan(const int* __restrict__ deg_i,
                                               int* __restrict__ off,
                                               int* __restrict__ cursor) {
    __shared__ int s[1024];
    const int t = threadIdx.x;
    const int base = t * (NN / 1024);
    int loc[NN / 1024];
    int sum = 0;
    for (int i = 0; i < NN / 1024; ++i) { loc[i] = sum; sum += deg_i[base + i]; }
    s[t] = sum;
    __syncthreads();
    for (int d = 1; d < 1024; d <<= 1) {
        int v = (t >= d) ? s[t - d] : 0;
        __syncthreads();
        s[t] += v;
        __syncthreads();
    }
    int pre = s[t] - sum;
    for (int i = 0; i < NN / 1024; ++i) {
        int o = pre + loc[i];
        off[base + i] = o;
        cursor[base + i] = o;
    }
    if (t == 1023) off[NN] = s[1023];
}

__global__ __launch_bounds__(256) void k_scatter(const int* __restrict__ edge,
                                                 int* __restrict__ cursor,
                                                 int* __restrict__ csr) {
    int e = blockIdx.x * 256 + threadIdx.x;
    if (e >= NE) return;
    int dst = edge[NE + e];
    int pos = atomicAdd(&cursor[dst], 1);
    csr[pos] = edge[e];
}

// ================= layer 0: per-node aggregate of obs (16 feats) ========
__global__ __launch_bounds__(256) void k_agg0(const float* __restrict__ obs,
                                              const int* __restrict__ off,
                                              const int* __restrict__ csr,
                                              float* __restrict__ agg0) {
    int gid = blockIdx.x * 256 + threadIdx.x;  // NN*16 threads
    int node = gid >> 4, f = gid & 15;
    if (node >= NN) return;
    int e0 = off[node], e1 = off[node + 1];
    float s = 0.f;
    for (int e = e0; e < e1; ++e) s += obs[csr[e] * 16 + f];
    agg0[node * 16 + f] = s;
}

// ================= layer 0: node transform -> h0 [N,128] ================
__global__ __launch_bounds__(256) void k_node0(const float* __restrict__ obs,
                                               const float* __restrict__ agg0,
                                               const int* __restrict__ off,
                                               const float* __restrict__ ws0,
                                               const float* __restrict__ bs0,
                                               const float* __restrict__ wn0,
                                               const float* __restrict__ bn0,
                                               float* __restrict__ h0) {
    int node = blockIdx.x * 4 + (threadIdx.x >> 6);
    int j = threadIdx.x & 63;
    if (node >= NN) return;
    int d = off[node + 1] - off[node];
    float inv = 1.f / (float)(d < 1 ? 1 : d);
    float s = bs0[j], n = bn0[j];
    const float* x = obs + node * 16;
    const float* a = agg0 + node * 16;
#pragma unroll
    for (int k = 0; k < 16; ++k) {
        s += x[k] * ws0[k * 64 + j];
        n += (a[k] * inv) * wn0[k * 64 + j];
    }
    h0[node * 128 + j]      = s > 0.f ? s : 0.f;
    h0[node * 128 + 64 + j] = n > 0.f ? n : 0.f;
}

// ==== fused layer-1 GEMMs: per 16-node tile, compute BOTH
//      h1_self = relu(h0 @ Ws1 + bs1)  (written to h1 cols 0..63)
//      y1      = h0 @ Wn1              (pre-transform; mean is linear)
// thread = 4 rows x 1 col-pair; X read via broadcast float4 global loads.
__global__ __launch_bounds__(256) void k_fused1(const float* __restrict__ h0,
                                                const float* __restrict__ ws1,
                                                const float* __restrict__ bs1,
                                                const float* __restrict__ wn1,
                                                float* __restrict__ h1,
                                                float* __restrict__ y1) {
    const int tid = threadIdx.x;
    const int rt = tid >> 6, ct = tid & 63;
    const int n0 = blockIdx.x * 16;
    float accS[4], accN[4];
    const float bsv = bs1[ct];
#pragma unroll
    for (int i = 0; i < 4; ++i) { accS[i] = bsv; accN[i] = 0.f; }
    const float* xrow[4];
#pragma unroll
    for (int i = 0; i < 4; ++i) xrow[i] = h0 + (size_t)(n0 + rt * 4 + i) * 128;

    for (int k = 0; k < 128; k += 4) {
        float4 xv[4];
#pragma unroll
        for (int i = 0; i < 4; ++i) xv[i] = *(const float4*)(xrow[i] + k);
#pragma unroll
        for (int kk = 0; kk < 4; ++kk) {
            const float wsv = ws1[(k + kk) * 64 + ct];
            const float wnv = wn1[(k + kk) * 64 + ct];
#pragma unroll
            for (int i = 0; i < 4; ++i) {
                const float xk = kk == 0 ? xv[i].x : kk == 1 ? xv[i].y : kk == 2 ? xv[i].z : xv[i].w;
                accS[i] += xk * wsv;
                accN[i] += xk * wnv;
            }
        }
    }
#pragma unroll
    for (int i = 0; i < 4; ++i) {
        const size_t node = n0 + rt * 4 + i;
        h1[node * 128 + ct] = accS[i] > 0.f ? accS[i] : 0.f;
        y1[node * 64 + ct]  = accN[i];
    }
}

// ==== layer-1 neighbor aggregate + epilogue: h1 cols 64..127 ============
__global__ __launch_bounds__(256) void k_agg1f(const float* __restrict__ y1,
                                               const int* __restrict__ off,
                                               const int* __restrict__ csr,
                                               const float* __restrict__ bn1,
                                               float* __restrict__ h1) {
    int node = blockIdx.x * 4 + (threadIdx.x >> 6);
    int lane = threadIdx.x & 63;
    if (node >= NN) return;
    int e0 = off[node], e1 = off[node + 1];
    float s = 0.f;
    for (int e = e0; e < e1; ++e) s += y1[(size_t)csr[e] * 64 + lane];
    int d = e1 - e0;
    float inv = 1.f / (float)(d < 1 ? 1 : d);
    float v = s * inv + bn1[lane];
    h1[(size_t)node * 128 + 64 + lane] = v > 0.f ? v : 0.f;
}

// ============ fused MLP: [16384,1024] -> 256 -> 256 -> 1 ================
// 16 rows/block; thread = 4 rows x 4 cols; X via broadcast global float4
// (rows are wave-private -> no LDS staging needed for layer 0).
__global__ __launch_bounds__(256) void k_mlp(const float* __restrict__ h1,
                                             const float* __restrict__ w0,
                                             const float* __restrict__ b0,
                                             const float* __restrict__ w1,
                                             const float* __restrict__ b1,
                                             const float* __restrict__ w2,
                                             const float* __restrict__ b2,
                                             float* __restrict__ out) {
    __shared__ float xs[16 * 256];                 // 16 KB inter-layer buffer
    const int tid = threadIdx.x;
    const int rt = tid >> 6, ct = tid & 63;
    const int row0 = blockIdx.x * 16;

    // ---- layer 0: 1024 -> 256 ----
    float acc[4][4];
    {
        const float4 bv = *(const float4*)(b0 + ct * 4);
#pragma unroll
        for (int i = 0; i < 4; ++i) { acc[i][0] = bv.x; acc[i][1] = bv.y; acc[i][2] = bv.z; acc[i][3] = bv.w; }
    }
    const float* xrow[4];
#pragma unroll
    for (int i = 0; i < 4; ++i) xrow[i] = h1 + (size_t)(row0 + rt * 4 + i) * 1024;

    for (int k = 0; k < 1024; k += 4) {
        float4 xv[4];
#pragma unroll
        for (int i = 0; i < 4; ++i) xv[i] = *(const float4*)(xrow[i] + k);
#pragma unroll
        for (int kk = 0; kk < 4; ++kk) {
            const float4 wv = *(const float4*)(w0 + (size_t)(k + kk) * 256 + ct * 4);
#pragma unroll
            for (int i = 0; i < 4; ++i) {
                const float xk = kk == 0 ? xv[i].x : kk == 1 ? xv[i].y : kk == 2 ? xv[i].z : xv[i].w;
                acc[i][0] += xk * wv.x; acc[i][1] += xk * wv.y;
                acc[i][2] += xk * wv.z; acc[i][3] += xk * wv.w;
            }
        }
    }
#pragma unroll
    for (int i = 0; i < 4; ++i)
#pragma unroll
        for (int j = 0; j < 4; ++j)
            xs[(rt * 4 + i) * 256 + ct * 4 + j] = tanhf(acc[i][j]);
    __syncthreads();

    // ---- layer 1: 256 -> 256 ----
    float acc2[4][4];
    {
        const float4 bv = *(const float4*)(b1 + ct * 4);
#pragma unroll
        for (int i = 0; i < 4; ++i) { acc2[i][0] = bv.x; acc2[i][1] = bv.y; acc2[i][2] = bv.z; acc2[i][3] = bv.w; }
    }
    for (int k = 0; k < 256; k += 4) {
        float4 xv[4];
#pragma unroll
        for (int i = 0; i < 4; ++i) xv[i] = *(const float4*)&xs[(rt * 4 + i) * 256 + k];
#pragma unroll
        for (int kk = 0; kk < 4; ++kk) {
            const float4 wv = *(const float4*)(w1 + (size_t)(k + kk) * 256 + ct * 4);
#pragma unroll
            for (int i = 0; i < 4; ++i) {
                const float xk = kk == 0 ? xv[i].x : kk == 1 ? xv[i].y : kk == 2 ? xv[i].z : xv[i].w;
                acc2[i][0] += xk * wv.x; acc2[i][1] += xk * wv.y;
                acc2[i][2] += xk * wv.z; acc2[i][3] += xk * wv.w;
            }
        }
    }
    __syncthreads();                               // all reads of xs done
#pragma unroll
    for (int i = 0; i < 4; ++i)
#pragma unroll
        for (int j = 0; j < 4; ++j)
            xs[(rt * 4 + i) * 256 + ct * 4 + j] = tanhf(acc2[i][j]);
    __syncthreads();

    // ---- layer 2: 256 -> 1, wave rt reduces its 4 rows ----
    const int l = tid & 63;
#pragma unroll
    for (int i = 0; i < 4; ++i) {
        const int r = rt * 4 + i;
        float p = 0.f;
#pragma unroll
        for (int c = 0; c < 4; ++c) p += xs[r * 256 + c * 64 + l] * w2[c * 64 + l];
        for (int o = 32; o; o >>= 1) p += __shfl_down(p, o);
        if (l == 0) out[row0 + r] = p + b2[0];
    }
}

extern "C" void kernel_launch(void* const* d_in, const int* in_sizes, int n_in,
                              void* d_out, int out_size, void* d_ws, size_t ws_size,
                              hipStream_t stream) {
    const float* obs  = (const float*)d_in[0];
    const int*   edge = (const int*)d_in[1];
    const float* ws0  = (const float*)d_in[2];
    const float* bs0  = (const float*)d_in[3];
    const float* wn0  = (const float*)d_in[4];
    const float* bn0  = (const float*)d_in[5];
    const float* ws1  = (const float*)d_in[6];
    const float* bs1  = (const float*)d_in[7];
    const float* wn1  = (const float*)d_in[8];
    const float* bn1  = (const float*)d_in[9];
    const float* w0   = (const float*)d_in[10];
    const float* b0   = (const float*)d_in[11];
    const float* w1   = (const float*)d_in[12];
    const float* b1   = (const float*)d_in[13];
    const float* w2   = (const float*)d_in[14];
    const float* b2   = (const float*)d_in[15];
    float* out = (float*)d_out;

    char* wsb = (char*)d_ws;
    int*   deg_i  = (int*)wsb;                                  // NN
    int*   off    = deg_i + NN;                                 // NN+1
    int*   cursor = off + NN + 1;                               // NN
    int*   csr    = cursor + NN;                                // NE
    float* agg0   = (float*)(csr + NE);                         // NN*16
    float* h0     = agg0 + (size_t)NN * 16;                     // NN*128
    float* y1     = h0   + (size_t)NN * 128;                    // NN*64
    float* h1     = y1   + (size_t)NN * 64;                     // NN*128

    hipMemsetAsync(deg_i, 0, (size_t)NN * sizeof(int), stream);

    k_hist   <<<dim3(NE / 256),      dim3(256),  0, stream>>>(edge, deg_i);
    k_scan   <<<dim3(1),             dim3(1024), 0, stream>>>(deg_i, off, cursor);
    k_scatter<<<dim3(NE / 256),      dim3(256),  0, stream>>>(edge, cursor, csr);

    k_agg0   <<<dim3(NN * 16 / 256), dim3(256),  0, stream>>>(obs, off, csr, agg0);
    k_node0  <<<dim3(NN / 4),        dim3(256),  0, stream>>>(obs, agg0, off, ws0, bs0, wn0, bn0, h0);
    k_fused1 <<<dim3(NN / 16),       dim3(256),  0, stream>>>(h0, ws1, bs1, wn1, h1, y1);
    k_agg1f  <<<dim3(NN / 4),        dim3(256),  0, stream>>>(y1, off, csr, bn1, h1);
    k_mlp    <<<dim3(ROWS / 16),     dim3(256),  0, stream>>>(h1, w0, b0, w1, b1, w2, b2, out);
}

// Round 5
// 682.098 us; speedup vs baseline: 1.4568x; 1.2610x over previous
//
#include <hip/hip_runtime.h>

#define STEPS 64
#define NUM_CPU 4
#define AGENTS 64
#define PHASES 8
#define NN (STEPS*NUM_CPU*AGENTS*PHASES)   // 131072 nodes
#define NE (NN*8)                          // 1048576 edges
#define ROWS (NN/PHASES)                   // 16384 MLP rows

typedef __attribute__((ext_vector_type(8))) short bf16x8;
typedef __attribute__((ext_vector_type(4))) float f32x4;

__device__ inline unsigned short f2bf(float x) {
    unsigned int b = __float_as_uint(x);
    return (unsigned short)((b + 0x7FFF + ((b >> 16) & 1)) >> 16);
}
__device__ inline float bf2f(unsigned short h) {
    return __uint_as_float(((unsigned int)h) << 16);
}
__device__ inline void split8(const float* a, bf16x8& hi, bf16x8& lo) {
#pragma unroll
    for (int i = 0; i < 8; ++i) {
        float x = a[i];
        unsigned short h = f2bf(x);
        hi[i] = (short)h;
        lo[i] = (short)f2bf(x - bf2f(h));
    }
}

// ================= CSR construction (counting sort by dst) =============
__global__ __launch_bounds__(256) void k_hist(const int* __restrict__ edge,
                                              int* __restrict__ deg_i) {
    int e = blockIdx.x * 256 + threadIdx.x;
    if (e < NE) atomicAdd(&deg_i[edge[NE + e]], 1);
}

__global__ __launch_bounds__(1024) void k_scan(const int* __restrict__ deg_i,
                                               int* __restrict__ off,
                                               int* __restrict__ cursor) {
    __shared__ int s[1024];
    const int t = threadIdx.x;
    const int base = t * (NN / 1024);
    int loc[NN / 1024];
    int sum = 0;
    for (int i = 0; i < NN / 1024; ++i) { loc[i] = sum; sum += deg_i[base + i]; }
    s[t] = sum;
    __syncthreads();
    for (int d = 1; d < 1024; d <<= 1) {
        int v = (t >= d) ? s[t - d] : 0;
        __syncthreads();
        s[t] += v;
        __syncthreads();
    }
    int pre = s[t] - sum;
    for (int i = 0; i < NN / 1024; ++i) {
        int o = pre + loc[i];
        off[base + i] = o;
        cursor[base + i] = o;
    }
    if (t == 1023) off[NN] = s[1023];
}

__global__ __launch_bounds__(256) void k_scatter(const int* __restrict__ edge,
                                                 int* __restrict__ cursor,
                                                 int* __restrict__ csr) {
    int e = blockIdx.x * 256 + threadIdx.x;
    if (e >= NE) return;
    int dst = edge[NE + e];
    int pos = atomicAdd(&cursor[dst], 1);
    csr[pos] = edge[e];
}

// ===== weight prep: src[K][N] f32 -> dst[N][K] bf16 hi/lo planes ========
__global__ __launch_bounds__(256) void k_prep(const float* __restrict__ src,
                                              unsigned short* __restrict__ dhi,
                                              unsigned short* __restrict__ dlo,
                                              int K, int N) {
    __shared__ float tile[32][33];
    const int tx = threadIdx.x & 31, ty = threadIdx.x >> 5;  // 8 rows
    const int n0 = blockIdx.x * 32, k0 = blockIdx.y * 32;
#pragma unroll
    for (int i = ty; i < 32; i += 8)
        tile[i][tx] = src[(size_t)(k0 + i) * N + n0 + tx];
    __syncthreads();
#pragma unroll
    for (int i = ty; i < 32; i += 8) {
        float x = tile[tx][i];
        unsigned short h = f2bf(x);
        size_t o = (size_t)(n0 + i) * K + k0 + tx;
        dhi[o] = h;
        dlo[o] = f2bf(x - bf2f(h));
    }
}

// ================= layer 0: per-node aggregate of obs (16 feats) ========
__global__ __launch_bounds__(256) void k_agg0(const float* __restrict__ obs,
                                              const int* __restrict__ off,
                                              const int* __restrict__ csr,
                                              float* __restrict__ agg0) {
    int gid = blockIdx.x * 256 + threadIdx.x;
    int node = gid >> 4, f = gid & 15;
    if (node >= NN) return;
    int e0 = off[node], e1 = off[node + 1];
    float s = 0.f;
    for (int e = e0; e < e1; ++e) s += obs[csr[e] * 16 + f];
    agg0[node * 16 + f] = s;
}

// ================= layer 0: node transform -> h0 [N,128] ================
__global__ __launch_bounds__(256) void k_node0(const float* __restrict__ obs,
                                               const float* __restrict__ agg0,
                                               const int* __restrict__ off,
                                               const float* __restrict__ ws0,
                                               const float* __restrict__ bs0,
                                               const float* __restrict__ wn0,
                                               const float* __restrict__ bn0,
                                               float* __restrict__ h0) {
    int node = blockIdx.x * 4 + (threadIdx.x >> 6);
    int j = threadIdx.x & 63;
    if (node >= NN) return;
    int d = off[node + 1] - off[node];
    float inv = 1.f / (float)(d < 1 ? 1 : d);
    float s = bs0[j], n = bn0[j];
    const float* x = obs + node * 16;
    const float* a = agg0 + node * 16;
#pragma unroll
    for (int k = 0; k < 16; ++k) {
        s += x[k] * ws0[k * 64 + j];
        n += (a[k] * inv) * wn0[k * 64 + j];
    }
    h0[node * 128 + j]      = s > 0.f ? s : 0.f;
    h0[node * 128 + 64 + j] = n > 0.f ? n : 0.f;
}

// ==== fused layer-1 GEMMs (MFMA, hi/lo split): per 64-node tile compute
//      h1_self = relu(h0 @ Ws1 + bs1)  -> h1 cols 0..63
//      y1      = h0 @ Wn1              -> pre-transform (mean is linear)
__global__ __launch_bounds__(256) void k_fused1(const float* __restrict__ h0,
                                                const unsigned short* __restrict__ ws1t_hi,
                                                const unsigned short* __restrict__ ws1t_lo,
                                                const unsigned short* __restrict__ wn1t_hi,
                                                const unsigned short* __restrict__ wn1t_lo,
                                                const float* __restrict__ bs1,
                                                float* __restrict__ h1,
                                                float* __restrict__ y1) {
    const int tid = threadIdx.x;
    const int wv = tid >> 6, l = tid & 63;
    const int lr = l & 15, lg = l >> 4;
    const int mrow0 = blockIdx.x * 64 + wv * 16;   // this wave's 16 nodes

    f32x4 acc[8];
#pragma unroll
    for (int t = 0; t < 8; ++t) {
        float bv = (t < 4) ? bs1[t * 16 + lr] : 0.f;
        acc[t] = (f32x4){bv, bv, bv, bv};
    }
    for (int kc = 0; kc < 4; ++kc) {               // K = 128 in chunks of 32
        float a8[8];
        const float* ap = h0 + (size_t)(mrow0 + lr) * 128 + kc * 32 + lg * 8;
        *(float4*)&a8[0] = *(const float4*)ap;
        *(float4*)&a8[4] = *(const float4*)(ap + 4);
        bf16x8 ahi, alo;
        split8(a8, ahi, alo);
#pragma unroll
        for (int t = 0; t < 8; ++t) {
            const unsigned short* bh = (t < 4) ? ws1t_hi : wn1t_hi;
            const unsigned short* bl = (t < 4) ? ws1t_lo : wn1t_lo;
            size_t boff = (size_t)((t & 3) * 16 + lr) * 128 + kc * 32 + lg * 8;
            bf16x8 bhi = *(const bf16x8*)(bh + boff);
            bf16x8 blo = *(const bf16x8*)(bl + boff);
            acc[t] = __builtin_amdgcn_mfma_f32_16x16x32_bf16(ahi, bhi, acc[t], 0, 0, 0);
            acc[t] = __builtin_amdgcn_mfma_f32_16x16x32_bf16(alo, bhi, acc[t], 0, 0, 0);
            acc[t] = __builtin_amdgcn_mfma_f32_16x16x32_bf16(ahi, blo, acc[t], 0, 0, 0);
        }
    }
    // C layout: col = lane&15, row = (lane>>4)*4 + reg   [m89-verified]
#pragma unroll
    for (int t = 0; t < 8; ++t) {
#pragma unroll
        for (int r = 0; r < 4; ++r) {
            size_t node = mrow0 + lg * 4 + r;
            int col = t * 16 + lr;
            if (t < 4) {
                float v = acc[t][r];
                h1[node * 128 + col] = v > 0.f ? v : 0.f;
            } else {
                y1[node * 64 + (col - 64)] = acc[t][r];
            }
        }
    }
}

// ==== layer-1 neighbor aggregate + epilogue: h1 cols 64..127 ============
__global__ __launch_bounds__(256) void k_agg1f(const float* __restrict__ y1,
                                               const int* __restrict__ off,
                                               const int* __restrict__ csr,
                                               const float* __restrict__ bn1,
                                               float* __restrict__ h1) {
    int node = blockIdx.x * 4 + (threadIdx.x >> 6);
    int lane = threadIdx.x & 63;
    if (node >= NN) return;
    int e0 = off[node], e1 = off[node + 1];
    float s = 0.f;
    for (int e = e0; e < e1; ++e) s += y1[(size_t)csr[e] * 64 + lane];
    int d = e1 - e0;
    float inv = 1.f / (float)(d < 1 ? 1 : d);
    float v = s * inv + bn1[lane];
    h1[(size_t)node * 128 + 64 + lane] = v > 0.f ? v : 0.f;
}

// ============ fused MLP (MFMA hi/lo): [16384,1024] -> 256 -> 256 -> 1 ===
#define XS_S 260                                   // LDS row stride (f32)
__global__ __launch_bounds__(256) void k_mlp(const float* __restrict__ h1,
                                             const unsigned short* __restrict__ w0t_hi,
                                             const unsigned short* __restrict__ w0t_lo,
                                             const float* __restrict__ b0,
                                             const unsigned short* __restrict__ w1t_hi,
                                             const unsigned short* __restrict__ w1t_lo,
                                             const float* __restrict__ b1,
                                             const float* __restrict__ w2,
                                             const float* __restrict__ b2,
                                             float* __restrict__ out) {
    __shared__ float xs[64 * XS_S];
    const int tid = threadIdx.x;
    const int wv = tid >> 6, l = tid & 63;
    const int lr = l & 15, lg = l >> 4;
    const int row0 = blockIdx.x * 64;
    const int mrow0 = row0 + wv * 16;

    // ---- layer 0: 1024 -> 256 ----
    f32x4 acc[16];
#pragma unroll
    for (int t = 0; t < 16; ++t) {
        float bv = b0[t * 16 + lr];
        acc[t] = (f32x4){bv, bv, bv, bv};
    }
    for (int kc = 0; kc < 32; ++kc) {
        float a8[8];
        const float* ap = h1 + (size_t)(mrow0 + lr) * 1024 + kc * 32 + lg * 8;
        *(float4*)&a8[0] = *(const float4*)ap;
        *(float4*)&a8[4] = *(const float4*)(ap + 4);
        bf16x8 ahi, alo;
        split8(a8, ahi, alo);
#pragma unroll
        for (int t = 0; t < 16; ++t) {
            size_t boff = (size_t)(t * 16 + lr) * 1024 + kc * 32 + lg * 8;
            bf16x8 bhi = *(const bf16x8*)(w0t_hi + boff);
            bf16x8 blo = *(const bf16x8*)(w0t_lo + boff);
            acc[t] = __builtin_amdgcn_mfma_f32_16x16x32_bf16(ahi, bhi, acc[t], 0, 0, 0);
            acc[t] = __builtin_amdgcn_mfma_f32_16x16x32_bf16(alo, bhi, acc[t], 0, 0, 0);
            acc[t] = __builtin_amdgcn_mfma_f32_16x16x32_bf16(ahi, blo, acc[t], 0, 0, 0);
        }
    }
#pragma unroll
    for (int t = 0; t < 16; ++t)
#pragma unroll
        for (int r = 0; r < 4; ++r)
            xs[(wv * 16 + lg * 4 + r) * XS_S + t * 16 + lr] = tanhf(acc[t][r]);
    __syncthreads();

    // ---- layer 1: 256 -> 256 ----
    f32x4 acc2[16];
#pragma unroll
    for (int t = 0; t < 16; ++t) {
        float bv = b1[t * 16 + lr];
        acc2[t] = (f32x4){bv, bv, bv, bv};
    }
    for (int kc = 0; kc < 8; ++kc) {
        float a8[8];
        const float* ap = &xs[(wv * 16 + lr) * XS_S + kc * 32 + lg * 8];
        *(float4*)&a8[0] = *(const float4*)ap;
        *(float4*)&a8[4] = *(const float4*)(ap + 4);
        bf16x8 ahi, alo;
        split8(a8, ahi, alo);
#pragma unroll
        for (int t = 0; t < 16; ++t) {
            size_t boff = (size_t)(t * 16 + lr) * 256 + kc * 32 + lg * 8;
            bf16x8 bhi = *(const bf16x8*)(w1t_hi + boff);
            bf16x8 blo = *(const bf16x8*)(w1t_lo + boff);
            acc2[t] = __builtin_amdgcn_mfma_f32_16x16x32_bf16(ahi, bhi, acc2[t], 0, 0, 0);
            acc2[t] = __builtin_amdgcn_mfma_f32_16x16x32_bf16(alo, bhi, acc2[t], 0, 0, 0);
            acc2[t] = __builtin_amdgcn_mfma_f32_16x16x32_bf16(ahi, blo, acc2[t], 0, 0, 0);
        }
    }
    __syncthreads();                               // all xs reads done
#pragma unroll
    for (int t = 0; t < 16; ++t)
#pragma unroll
        for (int r = 0; r < 4; ++r)
            xs[(wv * 16 + lg * 4 + r) * XS_S + t * 16 + lr] = tanhf(acc2[t][r]);
    __syncthreads();

    // ---- layer 2: 256 -> 1 ----  thread = (row, quarter)
    {
        const int row = tid >> 2, q = tid & 3;
        float p = 0.f;
#pragma unroll
        for (int c = 0; c < 64; ++c)
            p += xs[row * XS_S + q * 64 + c] * w2[q * 64 + c];
        p += __shfl_xor(p, 1);
        p += __shfl_xor(p, 2);
        if (q == 0) out[row0 + row] = p + b2[0];
    }
}

extern "C" void kernel_launch(void* const* d_in, const int* in_sizes, int n_in,
                              void* d_out, int out_size, void* d_ws, size_t ws_size,
                              hipStream_t stream) {
    const float* obs  = (const float*)d_in[0];
    const int*   edge = (const int*)d_in[1];
    const float* ws0  = (const float*)d_in[2];
    const float* bs0  = (const float*)d_in[3];
    const float* wn0  = (const float*)d_in[4];
    const float* bn0  = (const float*)d_in[5];
    const float* ws1  = (const float*)d_in[6];
    const float* bs1  = (const float*)d_in[7];
    const float* wn1  = (const float*)d_in[8];
    const float* bn1  = (const float*)d_in[9];
    const float* w0   = (const float*)d_in[10];
    const float* b0   = (const float*)d_in[11];
    const float* w1   = (const float*)d_in[12];
    const float* b1   = (const float*)d_in[13];
    const float* w2   = (const float*)d_in[14];
    const float* b2   = (const float*)d_in[15];
    float* out = (float*)d_out;

    char* wsb = (char*)d_ws;
    int*   deg_i  = (int*)wsb;                                  // NN
    int*   off    = deg_i + NN;                                 // NN+1
    int*   cursor = off + NN + 1;                               // NN
    int*   csr    = cursor + NN;                                // NE
    float* agg0   = (float*)(csr + NE);                         // NN*16
    float* h0     = agg0 + (size_t)NN * 16;                     // NN*128
    float* y1     = h0   + (size_t)NN * 128;                    // NN*64
    float* h1     = y1   + (size_t)NN * 64;                     // NN*128
    unsigned short* w0t_hi  = (unsigned short*)(h1 + (size_t)NN * 128); // 256x1024
    unsigned short* w0t_lo  = w0t_hi + 256 * 1024;
    unsigned short* w1t_hi  = w0t_lo + 256 * 1024;              // 256x256
    unsigned short* w1t_lo  = w1t_hi + 256 * 256;
    unsigned short* ws1t_hi = w1t_lo + 256 * 256;               // 64x128
    unsigned short* ws1t_lo = ws1t_hi + 64 * 128;
    unsigned short* wn1t_hi = ws1t_lo + 64 * 128;
    unsigned short* wn1t_lo = wn1t_hi + 64 * 128;

    hipMemsetAsync(deg_i, 0, (size_t)NN * sizeof(int), stream);

    k_prep<<<dim3(256 / 32, 1024 / 32), dim3(256), 0, stream>>>(w0, w0t_hi, w0t_lo, 1024, 256);
    k_prep<<<dim3(256 / 32, 256 / 32),  dim3(256), 0, stream>>>(w1, w1t_hi, w1t_lo, 256, 256);
    k_prep<<<dim3(64 / 32, 128 / 32),   dim3(256), 0, stream>>>(ws1, ws1t_hi, ws1t_lo, 128, 64);
    k_prep<<<dim3(64 / 32, 128 / 32),   dim3(256), 0, stream>>>(wn1, wn1t_hi, wn1t_lo, 128, 64);

    k_hist   <<<dim3(NE / 256),      dim3(256),  0, stream>>>(edge, deg_i);
    k_scan   <<<dim3(1),             dim3(1024), 0, stream>>>(deg_i, off, cursor);
    k_scatter<<<dim3(NE / 256),      dim3(256),  0, stream>>>(edge, cursor, csr);

    k_agg0   <<<dim3(NN * 16 / 256), dim3(256),  0, stream>>>(obs, off, csr, agg0);
    k_node0  <<<dim3(NN / 4),        dim3(256),  0, stream>>>(obs, agg0, off, ws0, bs0, wn0, bn0, h0);
    k_fused1 <<<dim3(NN / 64),       dim3(256),  0, stream>>>(h0, ws1t_hi, ws1t_lo, wn1t_hi, wn1t_lo, bs1, h1, y1);
    k_agg1f  <<<dim3(NN / 4),        dim3(256),  0, stream>>>(y1, off, csr, bn1, h1);
    k_mlp    <<<dim3(ROWS / 64),     dim3(256),  0, stream>>>(h1, w0t_hi, w0t_lo, b0, w1t_hi, w1t_lo, b1, w2, b2, out);
}

// Round 6
// 662.323 us; speedup vs baseline: 1.5003x; 1.0299x over previous
//
#include <hip/hip_runtime.h>

#define STEPS 64
#define NUM_CPU 4
#define AGENTS 64
#define PHASES 8
#define NN (STEPS*NUM_CPU*AGENTS*PHASES)   // 131072 nodes
#define NE (NN*8)                          // 1048576 edges
#define ROWS (NN/PHASES)                   // 16384 MLP rows

typedef __attribute__((ext_vector_type(8))) short bf16x8;
typedef __attribute__((ext_vector_type(4))) float f32x4;

__device__ inline unsigned short f2bf(float x) {
    unsigned int b = __float_as_uint(x);
    return (unsigned short)((b + 0x7FFF + ((b >> 16) & 1)) >> 16);
}
__device__ inline float bf2f(unsigned short h) {
    return __uint_as_float(((unsigned int)h) << 16);
}
__device__ inline void split8(const float* a, bf16x8& hi, bf16x8& lo) {
#pragma unroll
    for (int i = 0; i < 8; ++i) {
        float x = a[i];
        unsigned short h = f2bf(x);
        hi[i] = (short)h;
        lo[i] = (short)f2bf(x - bf2f(h));
    }
}

// ================= CSR construction (counting sort by dst) =============
__global__ __launch_bounds__(256) void k_hist(const int* __restrict__ edge,
                                              int* __restrict__ deg_i) {
    int e = blockIdx.x * 256 + threadIdx.x;
    if (e < NE) atomicAdd(&deg_i[edge[NE + e]], 1);
}

__global__ __launch_bounds__(1024) void k_scan(const int* __restrict__ deg_i,
                                               int* __restrict__ off,
                                               int* __restrict__ cursor) {
    __shared__ int s[1024];
    const int t = threadIdx.x;
    const int base = t * (NN / 1024);
    int loc[NN / 1024];
    int sum = 0;
    for (int i = 0; i < NN / 1024; ++i) { loc[i] = sum; sum += deg_i[base + i]; }
    s[t] = sum;
    __syncthreads();
    for (int d = 1; d < 1024; d <<= 1) {
        int v = (t >= d) ? s[t - d] : 0;
        __syncthreads();
        s[t] += v;
        __syncthreads();
    }
    int pre = s[t] - sum;
    for (int i = 0; i < NN / 1024; ++i) {
        int o = pre + loc[i];
        off[base + i] = o;
        cursor[base + i] = o;
    }
    if (t == 1023) off[NN] = s[1023];
}

__global__ __launch_bounds__(256) void k_scatter(const int* __restrict__ edge,
                                                 int* __restrict__ cursor,
                                                 int* __restrict__ csr) {
    int e = blockIdx.x * 256 + threadIdx.x;
    if (e >= NE) return;
    int dst = edge[NE + e];
    int pos = atomicAdd(&cursor[dst], 1);
    csr[pos] = edge[e];
}

// ===== weight prep: src[K][N] f32 -> dst[N][K] bf16 hi/lo planes ========
__global__ __launch_bounds__(256) void k_prep(const float* __restrict__ src,
                                              unsigned short* __restrict__ dhi,
                                              unsigned short* __restrict__ dlo,
                                              int K, int N) {
    __shared__ float tile[32][33];
    const int tx = threadIdx.x & 31, ty = threadIdx.x >> 5;
    const int n0 = blockIdx.x * 32, k0 = blockIdx.y * 32;
#pragma unroll
    for (int i = ty; i < 32; i += 8)
        tile[i][tx] = src[(size_t)(k0 + i) * N + n0 + tx];
    __syncthreads();
#pragma unroll
    for (int i = ty; i < 32; i += 8) {
        float x = tile[tx][i];
        unsigned short h = f2bf(x);
        size_t o = (size_t)(n0 + i) * K + k0 + tx;
        dhi[o] = h;
        dlo[o] = f2bf(x - bf2f(h));
    }
}

// ================= layer 0: per-node aggregate of obs (16 feats) ========
__global__ __launch_bounds__(256) void k_agg0(const float* __restrict__ obs,
                                              const int* __restrict__ off,
                                              const int* __restrict__ csr,
                                              float* __restrict__ agg0) {
    int gid = blockIdx.x * 256 + threadIdx.x;
    int node = gid >> 4, f = gid & 15;
    if (node >= NN) return;
    int e0 = off[node], e1 = off[node + 1];
    float s = 0.f;
    for (int e = e0; e < e1; ++e) s += obs[csr[e] * 16 + f];
    agg0[node * 16 + f] = s;
}

// ================= layer 0: node transform -> h0 [N,128] ================
__global__ __launch_bounds__(256) void k_node0(const float* __restrict__ obs,
                                               const float* __restrict__ agg0,
                                               const int* __restrict__ off,
                                               const float* __restrict__ ws0,
                                               const float* __restrict__ bs0,
                                               const float* __restrict__ wn0,
                                               const float* __restrict__ bn0,
                                               float* __restrict__ h0) {
    int node = blockIdx.x * 4 + (threadIdx.x >> 6);
    int j = threadIdx.x & 63;
    if (node >= NN) return;
    int d = off[node + 1] - off[node];
    float inv = 1.f / (float)(d < 1 ? 1 : d);
    float s = bs0[j], n = bn0[j];
    const float* x = obs + node * 16;
    const float* a = agg0 + node * 16;
#pragma unroll
    for (int k = 0; k < 16; ++k) {
        s += x[k] * ws0[k * 64 + j];
        n += (a[k] * inv) * wn0[k * 64 + j];
    }
    h0[node * 128 + j]      = s > 0.f ? s : 0.f;
    h0[node * 128 + 64 + j] = n > 0.f ? n : 0.f;
}

// ==== fused layer-1 GEMMs (MFMA, hi/lo split): per 64-node tile compute
//      h1_self = relu(h0 @ Ws1 + bs1)  -> h1 planes, per-row cols 0..63
//      y1      = h0 @ Wn1              -> pre-transform (mean is linear)
// h1 planes layout: row = node>>3, col = (node&7)*128 + c   [MLP row-major]
__global__ __launch_bounds__(256) void k_fused1(const float* __restrict__ h0,
                                                const unsigned short* __restrict__ ws1t_hi,
                                                const unsigned short* __restrict__ ws1t_lo,
                                                const unsigned short* __restrict__ wn1t_hi,
                                                const unsigned short* __restrict__ wn1t_lo,
                                                const float* __restrict__ bs1,
                                                unsigned short* __restrict__ h1_hi,
                                                unsigned short* __restrict__ h1_lo,
                                                float* __restrict__ y1) {
    const int tid = threadIdx.x;
    const int wv = tid >> 6, l = tid & 63;
    const int lr = l & 15, lg = l >> 4;
    const int mrow0 = blockIdx.x * 64 + wv * 16;

    f32x4 acc[8];
#pragma unroll
    for (int t = 0; t < 8; ++t) {
        float bv = (t < 4) ? bs1[t * 16 + lr] : 0.f;
        acc[t] = (f32x4){bv, bv, bv, bv};
    }
    for (int kc = 0; kc < 4; ++kc) {
        float a8[8];
        const float* ap = h0 + (size_t)(mrow0 + lr) * 128 + kc * 32 + lg * 8;
        *(float4*)&a8[0] = *(const float4*)ap;
        *(float4*)&a8[4] = *(const float4*)(ap + 4);
        bf16x8 ahi, alo;
        split8(a8, ahi, alo);
#pragma unroll
        for (int t = 0; t < 8; ++t) {
            const unsigned short* bh = (t < 4) ? ws1t_hi : wn1t_hi;
            const unsigned short* bl = (t < 4) ? ws1t_lo : wn1t_lo;
            size_t boff = (size_t)((t & 3) * 16 + lr) * 128 + kc * 32 + lg * 8;
            bf16x8 bhi = *(const bf16x8*)(bh + boff);
            bf16x8 blo = *(const bf16x8*)(bl + boff);
            acc[t] = __builtin_amdgcn_mfma_f32_16x16x32_bf16(ahi, bhi, acc[t], 0, 0, 0);
            acc[t] = __builtin_amdgcn_mfma_f32_16x16x32_bf16(alo, bhi, acc[t], 0, 0, 0);
            acc[t] = __builtin_amdgcn_mfma_f32_16x16x32_bf16(ahi, blo, acc[t], 0, 0, 0);
        }
    }
    // C layout: col = lane&15, row = (lane>>4)*4 + reg   [m89-verified]
#pragma unroll
    for (int t = 0; t < 8; ++t) {
#pragma unroll
        for (int r = 0; r < 4; ++r) {
            size_t node = mrow0 + lg * 4 + r;
            if (t < 4) {
                float v = acc[t][r];
                v = v > 0.f ? v : 0.f;
                unsigned short h = f2bf(v);
                size_t o = (node >> 3) * 1024 + (node & 7) * 128 + t * 16 + lr;
                h1_hi[o] = h;
                h1_lo[o] = f2bf(v - bf2f(h));
            } else {
                y1[node * 64 + (t - 4) * 16 + lr] = acc[t][r];
            }
        }
    }
}

// ==== layer-1 neighbor aggregate + epilogue -> h1 planes cols 64..127 ===
__global__ __launch_bounds__(256) void k_agg1f(const float* __restrict__ y1,
                                               const int* __restrict__ off,
                                               const int* __restrict__ csr,
                                               const float* __restrict__ bn1,
                                               unsigned short* __restrict__ h1_hi,
                                               unsigned short* __restrict__ h1_lo) {
    int node = blockIdx.x * 4 + (threadIdx.x >> 6);
    int lane = threadIdx.x & 63;
    if (node >= NN) return;
    int e0 = off[node], e1 = off[node + 1];
    float s = 0.f;
    for (int e = e0; e < e1; ++e) s += y1[(size_t)csr[e] * 64 + lane];
    int d = e1 - e0;
    float inv = 1.f / (float)(d < 1 ? 1 : d);
    float v = s * inv + bn1[lane];
    v = v > 0.f ? v : 0.f;
    unsigned short h = f2bf(v);
    size_t o = (size_t)(node >> 3) * 1024 + (node & 7) * 128 + 64 + lane;
    h1_hi[o] = h;
    h1_lo[o] = f2bf(v - bf2f(h));
}

// ============ fused MLP (MFMA hi/lo): [16384,1024] -> 256 -> 256 -> 1 ===
// 16 rows/block (1024 blocks = 4/CU); waves split N into 64-col quadrants.
#define S1 264                                     // bf16 LDS row stride
#define S2 260                                     // f32  LDS row stride
__global__ __launch_bounds__(256) void k_mlp(const unsigned short* __restrict__ h1_hi,
                                             const unsigned short* __restrict__ h1_lo,
                                             const unsigned short* __restrict__ w0t_hi,
                                             const unsigned short* __restrict__ w0t_lo,
                                             const float* __restrict__ b0,
                                             const unsigned short* __restrict__ w1t_hi,
                                             const unsigned short* __restrict__ w1t_lo,
                                             const float* __restrict__ b1,
                                             const float* __restrict__ w2,
                                             const float* __restrict__ b2,
                                             float* __restrict__ out) {
    __shared__ unsigned short xs_hi[16 * S1];
    __shared__ unsigned short xs_lo[16 * S1];
    __shared__ float xs2[16 * S2];
    const int tid = threadIdx.x;
    const int wv = tid >> 6, l = tid & 63;
    const int lr = l & 15, lg = l >> 4;
    const int row0 = blockIdx.x * 16;

    // ---- layer 0: 1024 -> 256 (this wave: cols wv*64 .. wv*64+63) ----
    f32x4 acc[4];
#pragma unroll
    for (int t = 0; t < 4; ++t) {
        float bv = b0[wv * 64 + t * 16 + lr];
        acc[t] = (f32x4){bv, bv, bv, bv};
    }
    for (int kc = 0; kc < 32; ++kc) {
        const size_t aoff = (size_t)(row0 + lr) * 1024 + kc * 32 + lg * 8;
        bf16x8 ahi = *(const bf16x8*)(h1_hi + aoff);
        bf16x8 alo = *(const bf16x8*)(h1_lo + aoff);
#pragma unroll
        for (int t = 0; t < 4; ++t) {
            size_t boff = (size_t)(wv * 64 + t * 16 + lr) * 1024 + kc * 32 + lg * 8;
            bf16x8 bhi = *(const bf16x8*)(w0t_hi + boff);
            bf16x8 blo = *(const bf16x8*)(w0t_lo + boff);
            acc[t] = __builtin_amdgcn_mfma_f32_16x16x32_bf16(ahi, bhi, acc[t], 0, 0, 0);
            acc[t] = __builtin_amdgcn_mfma_f32_16x16x32_bf16(alo, bhi, acc[t], 0, 0, 0);
            acc[t] = __builtin_amdgcn_mfma_f32_16x16x32_bf16(ahi, blo, acc[t], 0, 0, 0);
        }
    }
#pragma unroll
    for (int t = 0; t < 4; ++t)
#pragma unroll
        for (int r = 0; r < 4; ++r) {
            float v = tanhf(acc[t][r]);
            unsigned short h = f2bf(v);
            int o = (lg * 4 + r) * S1 + wv * 64 + t * 16 + lr;
            xs_hi[o] = h;
            xs_lo[o] = f2bf(v - bf2f(h));
        }
    __syncthreads();

    // ---- layer 1: 256 -> 256 ----
    f32x4 acc2[4];
#pragma unroll
    for (int t = 0; t < 4; ++t) {
        float bv = b1[wv * 64 + t * 16 + lr];
        acc2[t] = (f32x4){bv, bv, bv, bv};
    }
    for (int kc = 0; kc < 8; ++kc) {
        const int aoff = lr * S1 + kc * 32 + lg * 8;
        bf16x8 ahi = *(const bf16x8*)(xs_hi + aoff);
        bf16x8 alo = *(const bf16x8*)(xs_lo + aoff);
#pragma unroll
        for (int t = 0; t < 4; ++t) {
            size_t boff = (size_t)(wv * 64 + t * 16 + lr) * 256 + kc * 32 + lg * 8;
            bf16x8 bhi = *(const bf16x8*)(w1t_hi + boff);
            bf16x8 blo = *(const bf16x8*)(w1t_lo + boff);
            acc2[t] = __builtin_amdgcn_mfma_f32_16x16x32_bf16(ahi, bhi, acc2[t], 0, 0, 0);
            acc2[t] = __builtin_amdgcn_mfma_f32_16x16x32_bf16(alo, bhi, acc2[t], 0, 0, 0);
            acc2[t] = __builtin_amdgcn_mfma_f32_16x16x32_bf16(ahi, blo, acc2[t], 0, 0, 0);
        }
    }
#pragma unroll
    for (int t = 0; t < 4; ++t)
#pragma unroll
        for (int r = 0; r < 4; ++r)
            xs2[(lg * 4 + r) * S2 + wv * 64 + t * 16 + lr] = tanhf(acc2[t][r]);
    __syncthreads();

    // ---- layer 2: 256 -> 1; thread = (row, 16-col segment) ----
    {
        const int row = tid >> 4, seg = tid & 15;
        float p = 0.f;
#pragma unroll
        for (int c = 0; c < 16; ++c)
            p += xs2[row * S2 + seg * 16 + c] * w2[seg * 16 + c];
        p += __shfl_xor(p, 1);
        p += __shfl_xor(p, 2);
        p += __shfl_xor(p, 4);
        p += __shfl_xor(p, 8);
        if (seg == 0) out[row0 + row] = p + b2[0];
    }
}

extern "C" void kernel_launch(void* const* d_in, const int* in_sizes, int n_in,
                              void* d_out, int out_size, void* d_ws, size_t ws_size,
                              hipStream_t stream) {
    const float* obs  = (const float*)d_in[0];
    const int*   edge = (const int*)d_in[1];
    const float* ws0  = (const float*)d_in[2];
    const float* bs0  = (const float*)d_in[3];
    const float* wn0  = (const float*)d_in[4];
    const float* bn0  = (const float*)d_in[5];
    const float* ws1  = (const float*)d_in[6];
    const float* bs1  = (const float*)d_in[7];
    const float* wn1  = (const float*)d_in[8];
    const float* bn1  = (const float*)d_in[9];
    const float* w0   = (const float*)d_in[10];
    const float* b0   = (const float*)d_in[11];
    const float* w1   = (const float*)d_in[12];
    const float* b1   = (const float*)d_in[13];
    const float* w2   = (const float*)d_in[14];
    const float* b2   = (const float*)d_in[15];
    float* out = (float*)d_out;

    char* wsb = (char*)d_ws;
    int*   deg_i  = (int*)wsb;                                  // NN
    int*   off    = deg_i + NN;                                 // NN+1
    int*   cursor = off + NN + 1;                               // NN
    int*   csr    = cursor + NN;                                // NE
    float* agg0   = (float*)(csr + NE);                         // NN*16
    float* h0     = agg0 + (size_t)NN * 16;                     // NN*128
    float* y1     = h0   + (size_t)NN * 128;                    // NN*64
    unsigned short* h1_hi   = (unsigned short*)(y1 + (size_t)NN * 64); // ROWS*1024
    unsigned short* h1_lo   = h1_hi + (size_t)ROWS * 1024;
    unsigned short* w0t_hi  = h1_lo + (size_t)ROWS * 1024;      // 256x1024
    unsigned short* w0t_lo  = w0t_hi + 256 * 1024;
    unsigned short* w1t_hi  = w0t_lo + 256 * 1024;              // 256x256
    unsigned short* w1t_lo  = w1t_hi + 256 * 256;
    unsigned short* ws1t_hi = w1t_lo + 256 * 256;               // 64x128
    unsigned short* ws1t_lo = ws1t_hi + 64 * 128;
    unsigned short* wn1t_hi = ws1t_lo + 64 * 128;
    unsigned short* wn1t_lo = wn1t_hi + 64 * 128;

    hipMemsetAsync(deg_i, 0, (size_t)NN * sizeof(int), stream);

    k_prep<<<dim3(256 / 32, 1024 / 32), dim3(256), 0, stream>>>(w0, w0t_hi, w0t_lo, 1024, 256);
    k_prep<<<dim3(256 / 32, 256 / 32),  dim3(256), 0, stream>>>(w1, w1t_hi, w1t_lo, 256, 256);
    k_prep<<<dim3(64 / 32, 128 / 32),   dim3(256), 0, stream>>>(ws1, ws1t_hi, ws1t_lo, 128, 64);
    k_prep<<<dim3(64 / 32, 128 / 32),   dim3(256), 0, stream>>>(wn1, wn1t_hi, wn1t_lo, 128, 64);

    k_hist   <<<dim3(NE / 256),      dim3(256),  0, stream>>>(edge, deg_i);
    k_scan   <<<dim3(1),             dim3(1024), 0, stream>>>(deg_i, off, cursor);
    k_scatter<<<dim3(NE / 256),      dim3(256),  0, stream>>>(edge, cursor, csr);

    k_agg0   <<<dim3(NN * 16 / 256), dim3(256),  0, stream>>>(obs, off, csr, agg0);
    k_node0  <<<dim3(NN / 4),        dim3(256),  0, stream>>>(obs, agg0, off, ws0, bs0, wn0, bn0, h0);
    k_fused1 <<<dim3(NN / 64),       dim3(256),  0, stream>>>(h0, ws1t_hi, ws1t_lo, wn1t_hi, wn1t_lo, bs1, h1_hi, h1_lo, y1);
    k_agg1f  <<<dim3(NN / 4),        dim3(256),  0, stream>>>(y1, off, csr, bn1, h1_hi, h1_lo);
    k_mlp    <<<dim3(ROWS / 16),     dim3(256),  0, stream>>>(h1_hi, h1_lo, w0t_hi, w0t_lo, b0, w1t_hi, w1t_lo, b1, w2, b2, out);
}

// Round 7
// 468.182 us; speedup vs baseline: 2.1224x; 1.4147x over previous
//
#include <hip/hip_runtime.h>

#define STEPS 64
#define NUM_CPU 4
#define AGENTS 64
#define PHASES 8
#define NN (STEPS*NUM_CPU*AGENTS*PHASES)   // 131072 nodes
#define NE (NN*8)                          // 1048576 edges
#define ROWS (NN/PHASES)                   // 16384 MLP rows

typedef __attribute__((ext_vector_type(8))) short bf16x8;
typedef __attribute__((ext_vector_type(4))) float f32x4;

__device__ inline unsigned short f2bf(float x) {
    unsigned int b = __float_as_uint(x);
    return (unsigned short)((b + 0x7FFF + ((b >> 16) & 1)) >> 16);
}
__device__ inline float bf2f(unsigned short h) {
    return __uint_as_float(((unsigned int)h) << 16);
}
__device__ inline void split8(const float* a, bf16x8& hi, bf16x8& lo) {
#pragma unroll
    for (int i = 0; i < 8; ++i) {
        float x = a[i];
        unsigned short h = f2bf(x);
        hi[i] = (short)h;
        lo[i] = (short)f2bf(x - bf2f(h));
    }
}

// fragment-tile offset: value (n, k) lives at
//   ((n>>4)*TK + (k>>5))*512 + ((n&15) + 16*((k>>3)&3))*8 + (k&7)
// where TK = K/32. A load for lane l (=lr+16*lg) of tile (nt, kc) is then
// the contiguous range  [ (nt*TK+kc)*512 + l*8 , +8 )  -> fully coalesced.

// ================= CSR construction (counting sort by dst) =============
__global__ __launch_bounds__(256) void k_hist(const int* __restrict__ edge,
                                              int* __restrict__ deg_i) {
    int e = blockIdx.x * 256 + threadIdx.x;
    if (e < NE) atomicAdd(&deg_i[edge[NE + e]], 1);
}

// ---- two-level exclusive scan: 256 blocks x 512 elems ----
__global__ __launch_bounds__(256) void k_scanA(const int* __restrict__ deg,
                                               int* __restrict__ bsum) {
    __shared__ int s[256];
    const int b = blockIdx.x, t = threadIdx.x;
    const int2 v = *(const int2*)&deg[b * 512 + t * 2];
    s[t] = v.x + v.y;
    __syncthreads();
    for (int d = 128; d; d >>= 1) {
        if (t < d) s[t] += s[t + d];
        __syncthreads();
    }
    if (t == 0) bsum[b] = s[0];
}

__global__ __launch_bounds__(256) void k_scanB(const int* __restrict__ bsum,
                                               int* __restrict__ boff) {
    __shared__ int s[256];
    const int t = threadIdx.x;
    int v = bsum[t];
    s[t] = v;
    __syncthreads();
    for (int d = 1; d < 256; d <<= 1) {
        int x = (t >= d) ? s[t - d] : 0;
        __syncthreads();
        s[t] += x;
        __syncthreads();
    }
    boff[t] = s[t] - v;
}

__global__ __launch_bounds__(256) void k_scanC(const int* __restrict__ deg,
                                               const int* __restrict__ boff,
                                               int* __restrict__ off,
                                               int* __restrict__ cursor) {
    __shared__ int s[256];
    const int b = blockIdx.x, t = threadIdx.x;
    const int2 v = *(const int2*)&deg[b * 512 + t * 2];
    const int pair = v.x + v.y;
    s[t] = pair;
    __syncthreads();
    for (int d = 1; d < 256; d <<= 1) {
        int x = (t >= d) ? s[t - d] : 0;
        __syncthreads();
        s[t] += x;
        __syncthreads();
    }
    int pre = boff[b] + s[t] - pair;
    int i0 = b * 512 + t * 2;
    off[i0] = pre;          cursor[i0] = pre;
    off[i0 + 1] = pre + v.x; cursor[i0 + 1] = pre + v.x;
    if (b == 255 && t == 255) off[NN] = pre + pair;
}

__global__ __launch_bounds__(256) void k_scatter(const int* __restrict__ edge,
                                                 int* __restrict__ cursor,
                                                 int* __restrict__ csr) {
    int e = blockIdx.x * 256 + threadIdx.x;
    if (e >= NE) return;
    int dst = edge[NE + e];
    int pos = atomicAdd(&cursor[dst], 1);
    csr[pos] = edge[e];
}

// ===== weight prep: src[K][N] f32 -> fragment-tile bf16 hi/lo planes ====
__global__ __launch_bounds__(256) void k_prep(const float* __restrict__ src,
                                              unsigned short* __restrict__ dhi,
                                              unsigned short* __restrict__ dlo,
                                              int nshift, int nmask, int tk, int total) {
    int gid = blockIdx.x * 256 + threadIdx.x;
    if (gid >= total) return;
    int k = gid >> nshift, n = gid & nmask;
    float x = src[gid];
    unsigned short h = f2bf(x);
    size_t o = ((size_t)(n >> 4) * tk + (k >> 5)) * 512
             + ((n & 15) + 16 * ((k >> 3) & 3)) * 8 + (k & 7);
    dhi[o] = h;
    dlo[o] = f2bf(x - bf2f(h));
}

// ================= layer 0: per-node aggregate of obs (16 feats) ========
__global__ __launch_bounds__(256) void k_agg0(const float* __restrict__ obs,
                                              const int* __restrict__ off,
                                              const int* __restrict__ csr,
                                              float* __restrict__ agg0) {
    int gid = blockIdx.x * 256 + threadIdx.x;
    int node = gid >> 4, f = gid & 15;
    if (node >= NN) return;
    int e0 = off[node], e1 = off[node + 1];
    float s = 0.f;
    for (int e = e0; e < e1; ++e) s += obs[csr[e] * 16 + f];
    agg0[node * 16 + f] = s;
}

// ====== layer 0: node transform -> h0 fragment tiles (f32, K=128) =======
__global__ __launch_bounds__(256) void k_node0(const float* __restrict__ obs,
                                               const float* __restrict__ agg0,
                                               const int* __restrict__ off,
                                               const float* __restrict__ ws0,
                                               const float* __restrict__ bs0,
                                               const float* __restrict__ wn0,
                                               const float* __restrict__ bn0,
                                               float* __restrict__ h0t) {
    int node = blockIdx.x * 4 + (threadIdx.x >> 6);
    int j = threadIdx.x & 63;
    if (node >= NN) return;
    int d = off[node + 1] - off[node];
    float inv = 1.f / (float)(d < 1 ? 1 : d);
    float s = bs0[j], n = bn0[j];
    const float* x = obs + node * 16;
    const float* a = agg0 + node * 16;
#pragma unroll
    for (int k = 0; k < 16; ++k) {
        s += x[k] * ws0[k * 64 + j];
        n += (a[k] * inv) * wn0[k * 64 + j];
    }
    // h0 tile layout (K=128, TK=4): self at k=j, neigh at k=64+j
    size_t tb = (size_t)(node >> 4) * 4;
    size_t lanepart = (size_t)((node & 15) + 16 * ((j >> 3) & 3)) * 8 + (j & 7);
    h0t[(tb + (j >> 5)) * 512 + lanepart]     = s > 0.f ? s : 0.f;
    h0t[(tb + 2 + (j >> 5)) * 512 + lanepart] = n > 0.f ? n : 0.f;
}

// ==== fused layer-1 GEMMs (MFMA, hi/lo split): per 64-node tile compute
//      h1_self = relu(h0 @ Ws1 + bs1)  -> h1 planes (fragment tiles)
//      y1      = h0 @ Wn1              -> pre-transform (mean is linear)
__global__ __launch_bounds__(256) void k_fused1(const float* __restrict__ h0t,
                                                const unsigned short* __restrict__ ws1tt_hi,
                                                const unsigned short* __restrict__ ws1tt_lo,
                                                const unsigned short* __restrict__ wn1tt_hi,
                                                const unsigned short* __restrict__ wn1tt_lo,
                                                const float* __restrict__ bs1,
                                                unsigned short* __restrict__ h1_hi,
                                                unsigned short* __restrict__ h1_lo,
                                                float* __restrict__ y1) {
    const int tid = threadIdx.x;
    const int wv = tid >> 6, l = tid & 63;
    const int lr = l & 15, lg = l >> 4;
    const int tile = blockIdx.x * 4 + wv;          // 16-node tile index
    const int mrow0 = tile * 16;

    f32x4 acc[8];
#pragma unroll
    for (int t = 0; t < 8; ++t) {
        float bv = (t < 4) ? bs1[t * 16 + lr] : 0.f;
        acc[t] = (f32x4){bv, bv, bv, bv};
    }
    for (int kc = 0; kc < 4; ++kc) {
        float a8[8];
        const float* ap = h0t + ((size_t)tile * 4 + kc) * 512 + l * 8;
        *(float4*)&a8[0] = *(const float4*)ap;
        *(float4*)&a8[4] = *(const float4*)(ap + 4);
        bf16x8 ahi, alo;
        split8(a8, ahi, alo);
#pragma unroll
        for (int t = 0; t < 8; ++t) {
            const unsigned short* bh = (t < 4) ? ws1tt_hi : wn1tt_hi;
            const unsigned short* bl = (t < 4) ? ws1tt_lo : wn1tt_lo;
            size_t boff = ((size_t)(t & 3) * 4 + kc) * 512 + l * 8;
            bf16x8 bhi = *(const bf16x8*)(bh + boff);
            bf16x8 blo = *(const bf16x8*)(bl + boff);
            acc[t] = __builtin_amdgcn_mfma_f32_16x16x32_bf16(ahi, bhi, acc[t], 0, 0, 0);
            acc[t] = __builtin_amdgcn_mfma_f32_16x16x32_bf16(alo, bhi, acc[t], 0, 0, 0);
            acc[t] = __builtin_amdgcn_mfma_f32_16x16x32_bf16(ahi, blo, acc[t], 0, 0, 0);
        }
    }
    // D layout (verified by R5 pass): m = lg*4+reg, n = lr
#pragma unroll
    for (int t = 0; t < 8; ++t) {
#pragma unroll
        for (int r = 0; r < 4; ++r) {
            size_t node = mrow0 + lg * 4 + r;
            if (t < 4) {
                float v = acc[t][r];
                v = v > 0.f ? v : 0.f;
                unsigned short h = f2bf(v);
                int c = t * 16 + lr;               // h1 col 0..63
                size_t o = ((node >> 7) * 32 + (node & 7) * 4 + (c >> 5)) * 512
                         + ((node >> 3) & 15) * 8 + ((c >> 3) & 3) * 128 + (c & 7);
                h1_hi[o] = h;
                h1_lo[o] = f2bf(v - bf2f(h));
            } else {
                y1[node * 64 + (t - 4) * 16 + lr] = acc[t][r];
            }
        }
    }
}

// ==== layer-1 neighbor aggregate + epilogue -> h1 planes cols 64..127 ===
__global__ __launch_bounds__(256) void k_agg1f(const float* __restrict__ y1,
                                               const int* __restrict__ off,
                                               const int* __restrict__ csr,
                                               const float* __restrict__ bn1,
                                               unsigned short* __restrict__ h1_hi,
                                               unsigned short* __restrict__ h1_lo) {
    int node = blockIdx.x * 4 + (threadIdx.x >> 6);
    int lane = threadIdx.x & 63;
    if (node >= NN) return;
    int e0 = off[node], e1 = off[node + 1];
    float s = 0.f;
    for (int e = e0; e < e1; ++e) s += y1[(size_t)csr[e] * 64 + lane];
    int d = e1 - e0;
    float inv = 1.f / (float)(d < 1 ? 1 : d);
    float v = s * inv + bn1[lane];
    v = v > 0.f ? v : 0.f;
    unsigned short h = f2bf(v);
    int c = 64 + lane;
    size_t o = ((size_t)(node >> 7) * 32 + (node & 7) * 4 + (c >> 5)) * 512
             + ((node >> 3) & 15) * 8 + ((c >> 3) & 3) * 128 + (c & 7);
    h1_hi[o] = h;
    h1_lo[o] = f2bf(v - bf2f(h));
}

// ============ fused MLP (MFMA hi/lo): [16384,1024] -> 256 -> 256 -> 1 ===
// 16 rows/block; waves split N into 64-col quadrants; ALL global fragment
// loads are lane-contiguous (fragment-tile layout).
#define S1 264                                     // bf16 LDS row stride
#define S2 260                                     // f32  LDS row stride
__global__ __launch_bounds__(256) void k_mlp(const unsigned short* __restrict__ h1_hi,
                                             const unsigned short* __restrict__ h1_lo,
                                             const unsigned short* __restrict__ w0tt_hi,
                                             const unsigned short* __restrict__ w0tt_lo,
                                             const float* __restrict__ b0,
                                             const unsigned short* __restrict__ w1tt_hi,
                                             const unsigned short* __restrict__ w1tt_lo,
                                             const float* __restrict__ b1,
                                             const float* __restrict__ w2,
                                             const float* __restrict__ b2,
                                             float* __restrict__ out) {
    __shared__ unsigned short xs_hi[16 * S1];
    __shared__ unsigned short xs_lo[16 * S1];
    __shared__ float xs2[16 * S2];
    const int tid = threadIdx.x;
    const int wv = tid >> 6, l = tid & 63;
    const int lr = l & 15, lg = l >> 4;
    const int row0 = blockIdx.x * 16;

    // ---- layer 0: 1024 -> 256 (this wave: cols wv*64 .. wv*64+63) ----
    f32x4 acc[4];
#pragma unroll
    for (int t = 0; t < 4; ++t) {
        float bv = b0[wv * 64 + t * 16 + lr];
        acc[t] = (f32x4){bv, bv, bv, bv};
    }
    for (int kc = 0; kc < 32; ++kc) {
        const size_t aoff = ((size_t)blockIdx.x * 32 + kc) * 512 + l * 8;
        bf16x8 ahi = *(const bf16x8*)(h1_hi + aoff);
        bf16x8 alo = *(const bf16x8*)(h1_lo + aoff);
#pragma unroll
        for (int t = 0; t < 4; ++t) {
            size_t boff = ((size_t)(wv * 4 + t) * 32 + kc) * 512 + l * 8;
            bf16x8 bhi = *(const bf16x8*)(w0tt_hi + boff);
            bf16x8 blo = *(const bf16x8*)(w0tt_lo + boff);
            acc[t] = __builtin_amdgcn_mfma_f32_16x16x32_bf16(ahi, bhi, acc[t], 0, 0, 0);
            acc[t] = __builtin_amdgcn_mfma_f32_16x16x32_bf16(alo, bhi, acc[t], 0, 0, 0);
            acc[t] = __builtin_amdgcn_mfma_f32_16x16x32_bf16(ahi, blo, acc[t], 0, 0, 0);
        }
    }
#pragma unroll
    for (int t = 0; t < 4; ++t)
#pragma unroll
        for (int r = 0; r < 4; ++r) {
            float v = tanhf(acc[t][r]);
            unsigned short h = f2bf(v);
            int o = (lg * 4 + r) * S1 + wv * 64 + t * 16 + lr;
            xs_hi[o] = h;
            xs_lo[o] = f2bf(v - bf2f(h));
        }
    __syncthreads();

    // ---- layer 1: 256 -> 256 ----
    f32x4 acc2[4];
#pragma unroll
    for (int t = 0; t < 4; ++t) {
        float bv = b1[wv * 64 + t * 16 + lr];
        acc2[t] = (f32x4){bv, bv, bv, bv};
    }
    for (int kc = 0; kc < 8; ++kc) {
        const int aoff = lr * S1 + kc * 32 + lg * 8;
        bf16x8 ahi = *(const bf16x8*)(xs_hi + aoff);
        bf16x8 alo = *(const bf16x8*)(xs_lo + aoff);
#pragma unroll
        for (int t = 0; t < 4; ++t) {
            size_t boff = ((size_t)(wv * 4 + t) * 8 + kc) * 512 + l * 8;
            bf16x8 bhi = *(const bf16x8*)(w1tt_hi + boff);
            bf16x8 blo = *(const bf16x8*)(w1tt_lo + boff);
            acc2[t] = __builtin_amdgcn_mfma_f32_16x16x32_bf16(ahi, bhi, acc2[t], 0, 0, 0);
            acc2[t] = __builtin_amdgcn_mfma_f32_16x16x32_bf16(alo, bhi, acc2[t], 0, 0, 0);
            acc2[t] = __builtin_amdgcn_mfma_f32_16x16x32_bf16(ahi, blo, acc2[t], 0, 0, 0);
        }
    }
#pragma unroll
    for (int t = 0; t < 4; ++t)
#pragma unroll
        for (int r = 0; r < 4; ++r)
            xs2[(lg * 4 + r) * S2 + wv * 64 + t * 16 + lr] = tanhf(acc2[t][r]);
    __syncthreads();

    // ---- layer 2: 256 -> 1; thread = (row, 16-col segment) ----
    {
        const int row = tid >> 4, seg = tid & 15;
        float p = 0.f;
#pragma unroll
        for (int c = 0; c < 16; ++c)
            p += xs2[row * S2 + seg * 16 + c] * w2[seg * 16 + c];
        p += __shfl_xor(p, 1);
        p += __shfl_xor(p, 2);
        p += __shfl_xor(p, 4);
        p += __shfl_xor(p, 8);
        if (seg == 0) out[row0 + row] = p + b2[0];
    }
}

extern "C" void kernel_launch(void* const* d_in, const int* in_sizes, int n_in,
                              void* d_out, int out_size, void* d_ws, size_t ws_size,
                              hipStream_t stream) {
    const float* obs  = (const float*)d_in[0];
    const int*   edge = (const int*)d_in[1];
    const float* ws0  = (const float*)d_in[2];
    const float* bs0  = (const float*)d_in[3];
    const float* wn0  = (const float*)d_in[4];
    const float* bn0  = (const float*)d_in[5];
    const float* ws1  = (const float*)d_in[6];
    const float* bs1  = (const float*)d_in[7];
    const float* wn1  = (const float*)d_in[8];
    const float* bn1  = (const float*)d_in[9];
    const float* w0   = (const float*)d_in[10];
    const float* b0   = (const float*)d_in[11];
    const float* w1   = (const float*)d_in[12];
    const float* b1   = (const float*)d_in[13];
    const float* w2   = (const float*)d_in[14];
    const float* b2   = (const float*)d_in[15];
    float* out = (float*)d_out;

    char* wsb = (char*)d_ws;
    int*   deg_i  = (int*)wsb;                                  // NN
    int*   off    = deg_i + NN;                                 // NN+1
    int*   cursor = off + NN + 1;                               // NN
    int*   bsum   = cursor + NN;                                // 256
    int*   boff   = bsum + 256;                                 // 256
    int*   csr    = boff + 256;                                 // NE
    float* agg0   = (float*)(csr + NE);                         // NN*16
    float* h0t    = agg0 + (size_t)NN * 16;                     // NN*128
    float* y1     = h0t  + (size_t)NN * 128;                    // NN*64
    unsigned short* h1_hi   = (unsigned short*)(y1 + (size_t)NN * 64); // ROWS*1024
    unsigned short* h1_lo   = h1_hi + (size_t)ROWS * 1024;
    unsigned short* w0tt_hi = h1_lo + (size_t)ROWS * 1024;      // 256x1024
    unsigned short* w0tt_lo = w0tt_hi + 256 * 1024;
    unsigned short* w1tt_hi = w0tt_lo + 256 * 1024;             // 256x256
    unsigned short* w1tt_lo = w1tt_hi + 256 * 256;
    unsigned short* ws1tt_hi = w1tt_lo + 256 * 256;             // 64x128
    unsigned short* ws1tt_lo = ws1tt_hi + 64 * 128;
    unsigned short* wn1tt_hi = ws1tt_lo + 64 * 128;
    unsigned short* wn1tt_lo = wn1tt_hi + 64 * 128;

    hipMemsetAsync(deg_i, 0, (size_t)NN * sizeof(int), stream);

    k_prep<<<dim3(1024), dim3(256), 0, stream>>>(w0,  w0tt_hi, w0tt_lo, 8, 255, 32, 1024 * 256);
    k_prep<<<dim3(256),  dim3(256), 0, stream>>>(w1,  w1tt_hi, w1tt_lo, 8, 255, 8,  256 * 256);
    k_prep<<<dim3(32),   dim3(256), 0, stream>>>(ws1, ws1tt_hi, ws1tt_lo, 6, 63, 4, 128 * 64);
    k_prep<<<dim3(32),   dim3(256), 0, stream>>>(wn1, wn1tt_hi, wn1tt_lo, 6, 63, 4, 128 * 64);

    k_hist   <<<dim3(NE / 256), dim3(256), 0, stream>>>(edge, deg_i);
    k_scanA  <<<dim3(256),      dim3(256), 0, stream>>>(deg_i, bsum);
    k_scanB  <<<dim3(1),        dim3(256), 0, stream>>>(bsum, boff);
    k_scanC  <<<dim3(256),      dim3(256), 0, stream>>>(deg_i, boff, off, cursor);
    k_scatter<<<dim3(NE / 256), dim3(256), 0, stream>>>(edge, cursor, csr);

    k_agg0   <<<dim3(NN * 16 / 256), dim3(256), 0, stream>>>(obs, off, csr, agg0);
    k_node0  <<<dim3(NN / 4),        dim3(256), 0, stream>>>(obs, agg0, off, ws0, bs0, wn0, bn0, h0t);
    k_fused1 <<<dim3(NN / 64),       dim3(256), 0, stream>>>(h0t, ws1tt_hi, ws1tt_lo, wn1tt_hi, wn1tt_lo, bs1, h1_hi, h1_lo, y1);
    k_agg1f  <<<dim3(NN / 4),        dim3(256), 0, stream>>>(y1, off, csr, bn1, h1_hi, h1_lo);
    k_mlp    <<<dim3(ROWS / 16),     dim3(256), 0, stream>>>(h1_hi, h1_lo, w0tt_hi, w0tt_lo, b0, w1tt_hi, w1tt_lo, b1, w2, b2, out);
}

// Round 8
// 421.928 us; speedup vs baseline: 2.3551x; 1.1096x over previous
//
#include <hip/hip_runtime.h>

#define STEPS 64
#define NUM_CPU 4
#define AGENTS 64
#define PHASES 8
#define NN (STEPS*NUM_CPU*AGENTS*PHASES)   // 131072 nodes
#define NE (NN*8)                          // 1048576 edges
#define ROWS (NN/PHASES)                   // 16384 MLP rows

typedef __attribute__((ext_vector_type(8))) short bf16x8;
typedef __attribute__((ext_vector_type(4))) float f32x4;

__device__ inline unsigned short f2bf(float x) {
    unsigned int b = __float_as_uint(x);
    return (unsigned short)((b + 0x7FFF + ((b >> 16) & 1)) >> 16);
}
__device__ inline float bf2f(unsigned short h) {
    return __uint_as_float(((unsigned int)h) << 16);
}
__device__ inline void split8(const float* a, bf16x8& hi, bf16x8& lo) {
#pragma unroll
    for (int i = 0; i < 8; ++i) {
        float x = a[i];
        unsigned short h = f2bf(x);
        hi[i] = (short)h;
        lo[i] = (short)f2bf(x - bf2f(h));
    }
}

// fragment-tile offset: value (n, k) lives at
//   ((n>>4)*TK + (k>>5))*512 + ((n&15) + 16*((k>>3)&3))*8 + (k&7),  TK=K/32.

// ================= CSR construction (counting sort by dst) =============
__global__ __launch_bounds__(256) void k_hist(const int* __restrict__ edge,
                                              int* __restrict__ deg_i) {
    int e = blockIdx.x * 256 + threadIdx.x;
    if (e < NE) atomicAdd(&deg_i[edge[NE + e]], 1);
}

__global__ __launch_bounds__(256) void k_scanA(const int* __restrict__ deg,
                                               int* __restrict__ bsum) {
    __shared__ int s[256];
    const int b = blockIdx.x, t = threadIdx.x;
    const int2 v = *(const int2*)&deg[b * 512 + t * 2];
    s[t] = v.x + v.y;
    __syncthreads();
    for (int d = 128; d; d >>= 1) {
        if (t < d) s[t] += s[t + d];
        __syncthreads();
    }
    if (t == 0) bsum[b] = s[0];
}

__global__ __launch_bounds__(256) void k_scanB(const int* __restrict__ bsum,
                                               int* __restrict__ boff) {
    __shared__ int s[256];
    const int t = threadIdx.x;
    int v = bsum[t];
    s[t] = v;
    __syncthreads();
    for (int d = 1; d < 256; d <<= 1) {
        int x = (t >= d) ? s[t - d] : 0;
        __syncthreads();
        s[t] += x;
        __syncthreads();
    }
    boff[t] = s[t] - v;
}

__global__ __launch_bounds__(256) void k_scanC(const int* __restrict__ deg,
                                               const int* __restrict__ boff,
                                               int* __restrict__ off,
                                               int* __restrict__ cursor) {
    __shared__ int s[256];
    const int b = blockIdx.x, t = threadIdx.x;
    const int2 v = *(const int2*)&deg[b * 512 + t * 2];
    const int pair = v.x + v.y;
    s[t] = pair;
    __syncthreads();
    for (int d = 1; d < 256; d <<= 1) {
        int x = (t >= d) ? s[t - d] : 0;
        __syncthreads();
        s[t] += x;
        __syncthreads();
    }
    int pre = boff[b] + s[t] - pair;
    int i0 = b * 512 + t * 2;
    off[i0] = pre;          cursor[i0] = pre;
    off[i0 + 1] = pre + v.x; cursor[i0 + 1] = pre + v.x;
    if (b == 255 && t == 255) off[NN] = pre + pair;
}

__global__ __launch_bounds__(256) void k_scatter(const int* __restrict__ edge,
                                                 int* __restrict__ cursor,
                                                 int* __restrict__ csr) {
    int e = blockIdx.x * 256 + threadIdx.x;
    if (e >= NE) return;
    int dst = edge[NE + e];
    int pos = atomicAdd(&cursor[dst], 1);
    csr[pos] = edge[e];
}

// ===== weight prep: src[K][N] f32 -> fragment-tile bf16 hi/lo planes ====
__global__ __launch_bounds__(256) void k_prep(const float* __restrict__ src,
                                              unsigned short* __restrict__ dhi,
                                              unsigned short* __restrict__ dlo,
                                              int nshift, int nmask, int tk, int total) {
    int gid = blockIdx.x * 256 + threadIdx.x;
    if (gid >= total) return;
    int k = gid >> nshift, n = gid & nmask;
    float x = src[gid];
    unsigned short h = f2bf(x);
    size_t o = ((size_t)(n >> 4) * tk + (k >> 5)) * 512
             + ((n & 15) + 16 * ((k >> 3) & 3)) * 8 + (k & 7);
    dhi[o] = h;
    dlo[o] = f2bf(x - bf2f(h));
}

// ================= layer 0: per-node aggregate of obs (16 feats) ========
__global__ __launch_bounds__(256) void k_agg0(const float* __restrict__ obs,
                                              const int* __restrict__ off,
                                              const int* __restrict__ csr,
                                              float* __restrict__ agg0) {
    int gid = blockIdx.x * 256 + threadIdx.x;
    int node = gid >> 4, f = gid & 15;
    if (node >= NN) return;
    int e0 = off[node], e1 = off[node + 1];
    float s0 = 0.f, s1 = 0.f, s2 = 0.f, s3 = 0.f;
    int e = e0;
    for (; e + 3 < e1; e += 4) {
        s0 += obs[csr[e] * 16 + f];
        s1 += obs[csr[e + 1] * 16 + f];
        s2 += obs[csr[e + 2] * 16 + f];
        s3 += obs[csr[e + 3] * 16 + f];
    }
    for (; e < e1; ++e) s0 += obs[csr[e] * 16 + f];
    agg0[node * 16 + f] = (s0 + s1) + (s2 + s3);
}

// ====== layer 0: node transform -> h0 fragment tiles (f32, K=128) =======
__global__ __launch_bounds__(256) void k_node0(const float* __restrict__ obs,
                                               const float* __restrict__ agg0,
                                               const int* __restrict__ off,
                                               const float* __restrict__ ws0,
                                               const float* __restrict__ bs0,
                                               const float* __restrict__ wn0,
                                               const float* __restrict__ bn0,
                                               float* __restrict__ h0t) {
    int node = blockIdx.x * 4 + (threadIdx.x >> 6);
    int j = threadIdx.x & 63;
    if (node >= NN) return;
    int d = off[node + 1] - off[node];
    float inv = 1.f / (float)(d < 1 ? 1 : d);
    float s = bs0[j], n = bn0[j];
    const float* x = obs + node * 16;
    const float* a = agg0 + node * 16;
#pragma unroll
    for (int k = 0; k < 16; ++k) {
        s += x[k] * ws0[k * 64 + j];
        n += (a[k] * inv) * wn0[k * 64 + j];
    }
    size_t tb = (size_t)(node >> 4) * 4;
    size_t lanepart = (size_t)((node & 15) + 16 * ((j >> 3) & 3)) * 8 + (j & 7);
    h0t[(tb + (j >> 5)) * 512 + lanepart]     = s > 0.f ? s : 0.f;
    h0t[(tb + 2 + (j >> 5)) * 512 + lanepart] = n > 0.f ? n : 0.f;
}

// ==== fused layer-1 GEMMs (MFMA, hi/lo split), 128 nodes/block =========
//  h1_self -> LDS-staged fragment tiles (full-line writes);  y1 -> bf16
__global__ __launch_bounds__(256) void k_fused1(const float* __restrict__ h0t,
                                                const unsigned short* __restrict__ ws1tt_hi,
                                                const unsigned short* __restrict__ ws1tt_lo,
                                                const unsigned short* __restrict__ wn1tt_hi,
                                                const unsigned short* __restrict__ wn1tt_lo,
                                                const float* __restrict__ bs1,
                                                unsigned short* __restrict__ h1_hi,
                                                unsigned short* __restrict__ h1_lo,
                                                unsigned short* __restrict__ y1b) {
    __shared__ __align__(16) unsigned short s_hi[16 * 512];
    __shared__ __align__(16) unsigned short s_lo[16 * 512];
    const int tid = threadIdx.x;
    const int wv = tid >> 6, l = tid & 63;
    const int lr = l & 15, lg = l >> 4;
    const int nt = blockIdx.x;                    // 128-node / 16-MLP-row tile

    for (int half = 0; half < 2; ++half) {
        const int tile = nt * 8 + wv * 2 + half;  // 16-node tile index
        const int mrow0 = tile * 16;
        f32x4 acc[8];
#pragma unroll
        for (int t = 0; t < 8; ++t) {
            float bv = (t < 4) ? bs1[t * 16 + lr] : 0.f;
            acc[t] = (f32x4){bv, bv, bv, bv};
        }
        for (int kc = 0; kc < 4; ++kc) {
            float a8[8];
            const float* ap = h0t + ((size_t)tile * 4 + kc) * 512 + l * 8;
            *(float4*)&a8[0] = *(const float4*)ap;
            *(float4*)&a8[4] = *(const float4*)(ap + 4);
            bf16x8 ahi, alo;
            split8(a8, ahi, alo);
#pragma unroll
            for (int t = 0; t < 8; ++t) {
                const unsigned short* bh = (t < 4) ? ws1tt_hi : wn1tt_hi;
                const unsigned short* bl = (t < 4) ? ws1tt_lo : wn1tt_lo;
                size_t boff = ((size_t)(t & 3) * 4 + kc) * 512 + l * 8;
                bf16x8 bhi = *(const bf16x8*)(bh + boff);
                bf16x8 blo = *(const bf16x8*)(bl + boff);
                acc[t] = __builtin_amdgcn_mfma_f32_16x16x32_bf16(ahi, bhi, acc[t], 0, 0, 0);
                acc[t] = __builtin_amdgcn_mfma_f32_16x16x32_bf16(alo, bhi, acc[t], 0, 0, 0);
                acc[t] = __builtin_amdgcn_mfma_f32_16x16x32_bf16(ahi, blo, acc[t], 0, 0, 0);
            }
        }
        // D layout: m = lg*4+r, n = lr
#pragma unroll
        for (int t = 0; t < 8; ++t) {
#pragma unroll
            for (int r = 0; r < 4; ++r) {
                size_t node = mrow0 + lg * 4 + r;
                if (t < 4) {
                    float v = acc[t][r];
                    v = v > 0.f ? v : 0.f;
                    unsigned short h = f2bf(v);
                    int c = t * 16 + lr;           // col 0..63
                    int nl = (int)(node & 127);
                    int lt = (nl & 7) * 2 + (c >> 5);
                    int o = lt * 512 + ((nl >> 3) + 16 * ((c >> 3) & 3)) * 8 + (c & 7);
                    s_hi[o] = h;
                    s_lo[o] = f2bf(v - bf2f(h));
                } else {
                    y1b[node * 64 + (t - 4) * 16 + lr] = f2bf(acc[t][r]);
                }
            }
        }
    }
    __syncthreads();
    // copy tiles out: global tile g = nt*32 + (lt>>1)*4 + (lt&1)  (kc ≡ 0,1 mod 4)
    for (int idx = tid; idx < 1024; idx += 256) {
        int lt = idx >> 6, chunk = idx & 63;
        size_t goff = ((size_t)nt * 32 + (lt >> 1) * 4 + (lt & 1)) * 512 + chunk * 8;
        int loff = lt * 512 + chunk * 8;
        *(uint4*)&h1_hi[goff] = *(const uint4*)&s_hi[loff];
        *(uint4*)&h1_lo[goff] = *(const uint4*)&s_lo[loff];
    }
}

// ==== layer-1 neighbor aggregate (bf16 gather) + epilogue, 128/block ====
__global__ __launch_bounds__(256) void k_agg1f(const unsigned short* __restrict__ y1b,
                                               const int* __restrict__ off,
                                               const int* __restrict__ csr,
                                               const float* __restrict__ bn1,
                                               unsigned short* __restrict__ h1_hi,
                                               unsigned short* __restrict__ h1_lo) {
    __shared__ __align__(16) unsigned short s_hi[16 * 512];
    __shared__ __align__(16) unsigned short s_lo[16 * 512];
    const int tid = threadIdx.x;
    const int wv = tid >> 6, lane = tid & 63;
    const int nt = blockIdx.x;
    const float bias = bn1[lane];
    const int c = 64 + lane;

    for (int i = 0; i < 32; ++i) {
        int node = nt * 128 + wv * 32 + i;
        int e0 = off[node], e1 = off[node + 1];
        float s0 = 0.f, s1 = 0.f, s2 = 0.f, s3 = 0.f;
        int e = e0;
        for (; e + 3 < e1; e += 4) {
            s0 += bf2f(y1b[(size_t)csr[e] * 64 + lane]);
            s1 += bf2f(y1b[(size_t)csr[e + 1] * 64 + lane]);
            s2 += bf2f(y1b[(size_t)csr[e + 2] * 64 + lane]);
            s3 += bf2f(y1b[(size_t)csr[e + 3] * 64 + lane]);
        }
        for (; e < e1; ++e) s0 += bf2f(y1b[(size_t)csr[e] * 64 + lane]);
        float s = (s0 + s1) + (s2 + s3);
        int d = e1 - e0;
        float inv = 1.f / (float)(d < 1 ? 1 : d);
        float v = s * inv + bias;
        v = v > 0.f ? v : 0.f;
        unsigned short h = f2bf(v);
        int nl = node & 127;
        int lt = (nl & 7) * 2 + ((c >> 5) & 1);
        int o = lt * 512 + ((nl >> 3) + 16 * ((c >> 3) & 3)) * 8 + (c & 7);
        s_hi[o] = h;
        s_lo[o] = f2bf(v - bf2f(h));
    }
    __syncthreads();
    // global tile g = nt*32 + (lt>>1)*4 + 2 + (lt&1)   (kc ≡ 2,3 mod 4)
    for (int idx = tid; idx < 1024; idx += 256) {
        int lt = idx >> 6, chunk = idx & 63;
        size_t goff = ((size_t)nt * 32 + (lt >> 1) * 4 + 2 + (lt & 1)) * 512 + chunk * 8;
        int loff = lt * 512 + chunk * 8;
        *(uint4*)&h1_hi[goff] = *(const uint4*)&s_hi[loff];
        *(uint4*)&h1_lo[goff] = *(const uint4*)&s_lo[loff];
    }
}

// ============ fused MLP (MFMA hi/lo): [16384,1024] -> 256 -> 256 -> 1 ===
#define S1 264                                     // bf16 LDS row stride
#define S2 260                                     // f32  LDS row stride
__global__ __launch_bounds__(256) void k_mlp(const unsigned short* __restrict__ h1_hi,
                                             const unsigned short* __restrict__ h1_lo,
                                             const unsigned short* __restrict__ w0tt_hi,
                                             const unsigned short* __restrict__ w0tt_lo,
                                             const float* __restrict__ b0,
                                             const unsigned short* __restrict__ w1tt_hi,
                                             const unsigned short* __restrict__ w1tt_lo,
                                             const float* __restrict__ b1,
                                             const float* __restrict__ w2,
                                             const float* __restrict__ b2,
                                             float* __restrict__ out) {
    __shared__ unsigned short xs_hi[16 * S1];
    __shared__ unsigned short xs_lo[16 * S1];
    __shared__ float xs2[16 * S2];
    const int tid = threadIdx.x;
    const int wv = tid >> 6, l = tid & 63;
    const int lr = l & 15, lg = l >> 4;
    const int row0 = blockIdx.x * 16;

    f32x4 acc[4];
#pragma unroll
    for (int t = 0; t < 4; ++t) {
        float bv = b0[wv * 64 + t * 16 + lr];
        acc[t] = (f32x4){bv, bv, bv, bv};
    }
    for (int kc = 0; kc < 32; ++kc) {
        const size_t aoff = ((size_t)blockIdx.x * 32 + kc) * 512 + l * 8;
        bf16x8 ahi = *(const bf16x8*)(h1_hi + aoff);
        bf16x8 alo = *(const bf16x8*)(h1_lo + aoff);
#pragma unroll
        for (int t = 0; t < 4; ++t) {
            size_t boff = ((size_t)(wv * 4 + t) * 32 + kc) * 512 + l * 8;
            bf16x8 bhi = *(const bf16x8*)(w0tt_hi + boff);
            bf16x8 blo = *(const bf16x8*)(w0tt_lo + boff);
            acc[t] = __builtin_amdgcn_mfma_f32_16x16x32_bf16(ahi, bhi, acc[t], 0, 0, 0);
            acc[t] = __builtin_amdgcn_mfma_f32_16x16x32_bf16(alo, bhi, acc[t], 0, 0, 0);
            acc[t] = __builtin_amdgcn_mfma_f32_16x16x32_bf16(ahi, blo, acc[t], 0, 0, 0);
        }
    }
#pragma unroll
    for (int t = 0; t < 4; ++t)
#pragma unroll
        for (int r = 0; r < 4; ++r) {
            float v = tanhf(acc[t][r]);
            unsigned short h = f2bf(v);
            int o = (lg * 4 + r) * S1 + wv * 64 + t * 16 + lr;
            xs_hi[o] = h;
            xs_lo[o] = f2bf(v - bf2f(h));
        }
    __syncthreads();

    f32x4 acc2[4];
#pragma unroll
    for (int t = 0; t < 4; ++t) {
        float bv = b1[wv * 64 + t * 16 + lr];
        acc2[t] = (f32x4){bv, bv, bv, bv};
    }
    for (int kc = 0; kc < 8; ++kc) {
        const int aoff = lr * S1 + kc * 32 + lg * 8;
        bf16x8 ahi = *(const bf16x8*)(xs_hi + aoff);
        bf16x8 alo = *(const bf16x8*)(xs_lo + aoff);
#pragma unroll
        for (int t = 0; t < 4; ++t) {
            size_t boff = ((size_t)(wv * 4 + t) * 8 + kc) * 512 + l * 8;
            bf16x8 bhi = *(const bf16x8*)(w1tt_hi + boff);
            bf16x8 blo = *(const bf16x8*)(w1tt_lo + boff);
            acc2[t] = __builtin_amdgcn_mfma_f32_16x16x32_bf16(ahi, bhi, acc2[t], 0, 0, 0);
            acc2[t] = __builtin_amdgcn_mfma_f32_16x16x32_bf16(alo, bhi, acc2[t], 0, 0, 0);
            acc2[t] = __builtin_amdgcn_mfma_f32_16x16x32_bf16(ahi, blo, acc2[t], 0, 0, 0);
        }
    }
#pragma unroll
    for (int t = 0; t < 4; ++t)
#pragma unroll
        for (int r = 0; r < 4; ++r)
            xs2[(lg * 4 + r) * S2 + wv * 64 + t * 16 + lr] = tanhf(acc2[t][r]);
    __syncthreads();

    {
        const int row = tid >> 4, seg = tid & 15;
        float p = 0.f;
#pragma unroll
        for (int c = 0; c < 16; ++c)
            p += xs2[row * S2 + seg * 16 + c] * w2[seg * 16 + c];
        p += __shfl_xor(p, 1);
        p += __shfl_xor(p, 2);
        p += __shfl_xor(p, 4);
        p += __shfl_xor(p, 8);
        if (seg == 0) out[row0 + row] = p + b2[0];
    }
}

extern "C" void kernel_launch(void* const* d_in, const int* in_sizes, int n_in,
                              void* d_out, int out_size, void* d_ws, size_t ws_size,
                              hipStream_t stream) {
    const float* obs  = (const float*)d_in[0];
    const int*   edge = (const int*)d_in[1];
    const float* ws0  = (const float*)d_in[2];
    const float* bs0  = (const float*)d_in[3];
    const float* wn0  = (const float*)d_in[4];
    const float* bn0  = (const float*)d_in[5];
    const float* ws1  = (const float*)d_in[6];
    const float* bs1  = (const float*)d_in[7];
    const float* wn1  = (const float*)d_in[8];
    const float* bn1  = (const float*)d_in[9];
    const float* w0   = (const float*)d_in[10];
    const float* b0   = (const float*)d_in[11];
    const float* w1   = (const float*)d_in[12];
    const float* b1   = (const float*)d_in[13];
    const float* w2   = (const float*)d_in[14];
    const float* b2   = (const float*)d_in[15];
    float* out = (float*)d_out;

    char* wsb = (char*)d_ws;
    int*   deg_i  = (int*)wsb;                                  // NN
    int*   off    = deg_i + NN;                                 // NN+1
    int*   cursor = off + NN + 1;                               // NN
    int*   bsum   = cursor + NN;                                // 256
    int*   boff   = bsum + 256;                                 // 256
    int*   csr    = boff + 256;                                 // NE
    float* agg0   = (float*)(csr + NE);                         // NN*16
    float* h0t    = agg0 + (size_t)NN * 16;                     // NN*128
    unsigned short* y1b     = (unsigned short*)(h0t + (size_t)NN * 128); // NN*64
    unsigned short* h1_hi   = y1b + (size_t)NN * 64;            // ROWS*1024
    unsigned short* h1_lo   = h1_hi + (size_t)ROWS * 1024;
    unsigned short* w0tt_hi = h1_lo + (size_t)ROWS * 1024;      // 256x1024
    unsigned short* w0tt_lo = w0tt_hi + 256 * 1024;
    unsigned short* w1tt_hi = w0tt_lo + 256 * 1024;             // 256x256
    unsigned short* w1tt_lo = w1tt_hi + 256 * 256;
    unsigned short* ws1tt_hi = w1tt_lo + 256 * 256;             // 64x128
    unsigned short* ws1tt_lo = ws1tt_hi + 64 * 128;
    unsigned short* wn1tt_hi = ws1tt_lo + 64 * 128;
    unsigned short* wn1tt_lo = wn1tt_hi + 64 * 128;

    hipMemsetAsync(deg_i, 0, (size_t)NN * sizeof(int), stream);

    k_prep<<<dim3(1024), dim3(256), 0, stream>>>(w0,  w0tt_hi, w0tt_lo, 8, 255, 32, 1024 * 256);
    k_prep<<<dim3(256),  dim3(256), 0, stream>>>(w1,  w1tt_hi, w1tt_lo, 8, 255, 8,  256 * 256);
    k_prep<<<dim3(32),   dim3(256), 0, stream>>>(ws1, ws1tt_hi, ws1tt_lo, 6, 63, 4, 128 * 64);
    k_prep<<<dim3(32),   dim3(256), 0, stream>>>(wn1, wn1tt_hi, wn1tt_lo, 6, 63, 4, 128 * 64);

    k_hist   <<<dim3(NE / 256), dim3(256), 0, stream>>>(edge, deg_i);
    k_scanA  <<<dim3(256),      dim3(256), 0, stream>>>(deg_i, bsum);
    k_scanB  <<<dim3(1),        dim3(256), 0, stream>>>(bsum, boff);
    k_scanC  <<<dim3(256),      dim3(256), 0, stream>>>(deg_i, boff, off, cursor);
    k_scatter<<<dim3(NE / 256), dim3(256), 0, stream>>>(edge, cursor, csr);

    k_agg0   <<<dim3(NN * 16 / 256), dim3(256), 0, stream>>>(obs, off, csr, agg0);
    k_node0  <<<dim3(NN / 4),        dim3(256), 0, stream>>>(obs, agg0, off, ws0, bs0, wn0, bn0, h0t);
    k_fused1 <<<dim3(NN / 128),      dim3(256), 0, stream>>>(h0t, ws1tt_hi, ws1tt_lo, wn1tt_hi, wn1tt_lo, bs1, h1_hi, h1_lo, y1b);
    k_agg1f  <<<dim3(NN / 128),      dim3(256), 0, stream>>>(y1b, off, csr, bn1, h1_hi, h1_lo);
    k_mlp    <<<dim3(ROWS / 16),     dim3(256), 0, stream>>>(h1_hi, h1_lo, w0tt_hi, w0tt_lo, b0, w1tt_hi, w1tt_lo, b1, w2, b2, out);
}

// Round 9
// 380.004 us; speedup vs baseline: 2.6149x; 1.1103x over previous
//
#include <hip/hip_runtime.h>

#define STEPS 64
#define NUM_CPU 4
#define AGENTS 64
#define PHASES 8
#define NN (STEPS*NUM_CPU*AGENTS*PHASES)   // 131072 nodes
#define NE (NN*8)                          // 1048576 edges
#define ROWS (NN/PHASES)                   // 16384 MLP rows

typedef __attribute__((ext_vector_type(8))) short bf16x8;
typedef __attribute__((ext_vector_type(4))) float f32x4;

__device__ inline unsigned short f2bf(float x) {
    unsigned int b = __float_as_uint(x);
    return (unsigned short)((b + 0x7FFF + ((b >> 16) & 1)) >> 16);
}
__device__ inline float bf2f(unsigned short h) {
    return __uint_as_float(((unsigned int)h) << 16);
}
__device__ inline void split8(const float* a, bf16x8& hi, bf16x8& lo) {
#pragma unroll
    for (int i = 0; i < 8; ++i) {
        float x = a[i];
        unsigned short h = f2bf(x);
        hi[i] = (short)h;
        lo[i] = (short)f2bf(x - bf2f(h));
    }
}

// fragment-tile offset: value (n, k) lives at
//   ((n>>4)*TK + (k>>5))*512 + ((n&15) + 16*((k>>3)&3))*8 + (k&7),  TK=K/32.

// ================= CSR construction (counting sort by dst) =============
__global__ __launch_bounds__(256) void k_hist(const int* __restrict__ edge,
                                              int* __restrict__ deg_i) {
    int e = blockIdx.x * 256 + threadIdx.x;
    if (e < NE) atomicAdd(&deg_i[edge[NE + e]], 1);
}

__global__ __launch_bounds__(256) void k_scanA(const int* __restrict__ deg,
                                               int* __restrict__ bsum) {
    __shared__ int s[256];
    const int b = blockIdx.x, t = threadIdx.x;
    const int2 v = *(const int2*)&deg[b * 512 + t * 2];
    s[t] = v.x + v.y;
    __syncthreads();
    for (int d = 128; d; d >>= 1) {
        if (t < d) s[t] += s[t + d];
        __syncthreads();
    }
    if (t == 0) bsum[b] = s[0];
}

__global__ __launch_bounds__(256) void k_scanB(const int* __restrict__ bsum,
                                               int* __restrict__ boff) {
    __shared__ int s[256];
    const int t = threadIdx.x;
    int v = bsum[t];
    s[t] = v;
    __syncthreads();
    for (int d = 1; d < 256; d <<= 1) {
        int x = (t >= d) ? s[t - d] : 0;
        __syncthreads();
        s[t] += x;
        __syncthreads();
    }
    boff[t] = s[t] - v;
}

__global__ __launch_bounds__(256) void k_scanC(const int* __restrict__ deg,
                                               const int* __restrict__ boff,
                                               int* __restrict__ off,
                                               int* __restrict__ cursor) {
    __shared__ int s[256];
    const int b = blockIdx.x, t = threadIdx.x;
    const int2 v = *(const int2*)&deg[b * 512 + t * 2];
    const int pair = v.x + v.y;
    s[t] = pair;
    __syncthreads();
    for (int d = 1; d < 256; d <<= 1) {
        int x = (t >= d) ? s[t - d] : 0;
        __syncthreads();
        s[t] += x;
        __syncthreads();
    }
    int pre = boff[b] + s[t] - pair;
    int i0 = b * 512 + t * 2;
    off[i0] = pre;          cursor[i0] = pre;
    off[i0 + 1] = pre + v.x; cursor[i0 + 1] = pre + v.x;
    if (b == 255 && t == 255) off[NN] = pre + pair;
}

__global__ __launch_bounds__(256) void k_scatter(const int* __restrict__ edge,
                                                 int* __restrict__ cursor,
                                                 int* __restrict__ csr) {
    int e = blockIdx.x * 256 + threadIdx.x;
    if (e >= NE) return;
    int dst = edge[NE + e];
    int pos = atomicAdd(&cursor[dst], 1);
    csr[pos] = edge[e];
}

// ===== weight prep: src[K][N] f32 -> fragment-tile bf16 hi/lo planes ====
__global__ __launch_bounds__(256) void k_prep(const float* __restrict__ src,
                                              unsigned short* __restrict__ dhi,
                                              unsigned short* __restrict__ dlo,
                                              int nshift, int nmask, int tk, int total) {
    int gid = blockIdx.x * 256 + threadIdx.x;
    if (gid >= total) return;
    int k = gid >> nshift, n = gid & nmask;
    float x = src[gid];
    unsigned short h = f2bf(x);
    size_t o = ((size_t)(n >> 4) * tk + (k >> 5)) * 512
             + ((n & 15) + 16 * ((k >> 3) & 3)) * 8 + (k & 7);
    dhi[o] = h;
    dlo[o] = f2bf(x - bf2f(h));
}

// ================= layer 0: per-node aggregate of obs (16 feats) ========
__global__ __launch_bounds__(256) void k_agg0(const float* __restrict__ obs,
                                              const int* __restrict__ off,
                                              const int* __restrict__ csr,
                                              float* __restrict__ agg0) {
    int gid = blockIdx.x * 256 + threadIdx.x;
    int node = gid >> 4, f = gid & 15;
    if (node >= NN) return;
    int e0 = off[node], e1 = off[node + 1];
    float s0 = 0.f, s1 = 0.f, s2 = 0.f, s3 = 0.f;
    int e = e0;
    for (; e + 3 < e1; e += 4) {
        s0 += obs[csr[e] * 16 + f];
        s1 += obs[csr[e + 1] * 16 + f];
        s2 += obs[csr[e + 2] * 16 + f];
        s3 += obs[csr[e + 3] * 16 + f];
    }
    for (; e < e1; ++e) s0 += obs[csr[e] * 16 + f];
    agg0[node * 16 + f] = (s0 + s1) + (s2 + s3);
}

// ====== layer 0: node transform -> h0 fragment tiles (f32, K=128) =======
__global__ __launch_bounds__(256) void k_node0(const float* __restrict__ obs,
                                               const float* __restrict__ agg0,
                                               const int* __restrict__ off,
                                               const float* __restrict__ ws0,
                                               const float* __restrict__ bs0,
                                               const float* __restrict__ wn0,
                                               const float* __restrict__ bn0,
                                               float* __restrict__ h0t) {
    int node = blockIdx.x * 4 + (threadIdx.x >> 6);
    int j = threadIdx.x & 63;
    if (node >= NN) return;
    int d = off[node + 1] - off[node];
    float inv = 1.f / (float)(d < 1 ? 1 : d);
    float s = bs0[j], n = bn0[j];
    const float* x = obs + node * 16;
    const float* a = agg0 + node * 16;
#pragma unroll
    for (int k = 0; k < 16; ++k) {
        s += x[k] * ws0[k * 64 + j];
        n += (a[k] * inv) * wn0[k * 64 + j];
    }
    size_t tb = (size_t)(node >> 4) * 4;
    size_t lanepart = (size_t)((node & 15) + 16 * ((j >> 3) & 3)) * 8 + (j & 7);
    h0t[(tb + (j >> 5)) * 512 + lanepart]     = s > 0.f ? s : 0.f;
    h0t[(tb + 2 + (j >> 5)) * 512 + lanepart] = n > 0.f ? n : 0.f;
}

// ==== fused layer-1 GEMMs (MFMA, hi/lo split), 128 nodes/block =========
//  h1_self -> LDS-staged fragment tiles (full-line writes);  y1 -> bf16
__global__ __launch_bounds__(256) void k_fused1(const float* __restrict__ h0t,
                                                const unsigned short* __restrict__ ws1tt_hi,
                                                const unsigned short* __restrict__ ws1tt_lo,
                                                const unsigned short* __restrict__ wn1tt_hi,
                                                const unsigned short* __restrict__ wn1tt_lo,
                                                const float* __restrict__ bs1,
                                                unsigned short* __restrict__ h1_hi,
                                                unsigned short* __restrict__ h1_lo,
                                                unsigned short* __restrict__ y1b) {
    __shared__ __align__(16) unsigned short s_hi[16 * 512];
    __shared__ __align__(16) unsigned short s_lo[16 * 512];
    const int tid = threadIdx.x;
    const int wv = tid >> 6, l = tid & 63;
    const int lr = l & 15, lg = l >> 4;
    const int nt = blockIdx.x;                    // 128-node / 16-MLP-row tile

    for (int half = 0; half < 2; ++half) {
        const int tile = nt * 8 + wv * 2 + half;  // 16-node tile index
        const int mrow0 = tile * 16;
        f32x4 acc[8];
#pragma unroll
        for (int t = 0; t < 8; ++t) {
            float bv = (t < 4) ? bs1[t * 16 + lr] : 0.f;
            acc[t] = (f32x4){bv, bv, bv, bv};
        }
        for (int kc = 0; kc < 4; ++kc) {
            float a8[8];
            const float* ap = h0t + ((size_t)tile * 4 + kc) * 512 + l * 8;
            *(float4*)&a8[0] = *(const float4*)ap;
            *(float4*)&a8[4] = *(const float4*)(ap + 4);
            bf16x8 ahi, alo;
            split8(a8, ahi, alo);
#pragma unroll
            for (int t = 0; t < 8; ++t) {
                const unsigned short* bh = (t < 4) ? ws1tt_hi : wn1tt_hi;
                const unsigned short* bl = (t < 4) ? ws1tt_lo : wn1tt_lo;
                size_t boff = ((size_t)(t & 3) * 4 + kc) * 512 + l * 8;
                bf16x8 bhi = *(const bf16x8*)(bh + boff);
                bf16x8 blo = *(const bf16x8*)(bl + boff);
                acc[t] = __builtin_amdgcn_mfma_f32_16x16x32_bf16(ahi, bhi, acc[t], 0, 0, 0);
                acc[t] = __builtin_amdgcn_mfma_f32_16x16x32_bf16(alo, bhi, acc[t], 0, 0, 0);
                acc[t] = __builtin_amdgcn_mfma_f32_16x16x32_bf16(ahi, blo, acc[t], 0, 0, 0);
            }
        }
        // D layout: m = lg*4+r, n = lr
#pragma unroll
        for (int t = 0; t < 8; ++t) {
#pragma unroll
            for (int r = 0; r < 4; ++r) {
                size_t node = mrow0 + lg * 4 + r;
                if (t < 4) {
                    float v = acc[t][r];
                    v = v > 0.f ? v : 0.f;
                    unsigned short h = f2bf(v);
                    int c = t * 16 + lr;           // col 0..63
                    int nl = (int)(node & 127);
                    int lt = (nl & 7) * 2 + (c >> 5);
                    int o = lt * 512 + ((nl >> 3) + 16 * ((c >> 3) & 3)) * 8 + (c & 7);
                    s_hi[o] = h;
                    s_lo[o] = f2bf(v - bf2f(h));
                } else {
                    y1b[node * 64 + (t - 4) * 16 + lr] = f2bf(acc[t][r]);
                }
            }
        }
    }
    __syncthreads();
    // copy tiles out: global tile g = nt*32 + (lt>>1)*4 + (lt&1)  (kc ≡ 0,1 mod 4)
    for (int idx = tid; idx < 1024; idx += 256) {
        int lt = idx >> 6, chunk = idx & 63;
        size_t goff = ((size_t)nt * 32 + (lt >> 1) * 4 + (lt & 1)) * 512 + chunk * 8;
        int loff = lt * 512 + chunk * 8;
        *(uint4*)&h1_hi[goff] = *(const uint4*)&s_hi[loff];
        *(uint4*)&h1_lo[goff] = *(const uint4*)&s_lo[loff];
    }
}

// ==== layer-1 neighbor aggregate (bf16 gather) + epilogue, 64/block =====
// 2048 blocks (8/CU) for occupancy; LDS half-tile staging keeps full-line
// writes (128B runs at (nt&1)*128 + q*256 within each 1KB tile).
__global__ __launch_bounds__(256) void k_agg1f(const unsigned short* __restrict__ y1b,
                                               const int* __restrict__ off,
                                               const int* __restrict__ csr,
                                               const float* __restrict__ bn1,
                                               unsigned short* __restrict__ h1_hi,
                                               unsigned short* __restrict__ h1_lo) {
    __shared__ __align__(16) unsigned short s_hi[16 * 256];   // 8 KB
    __shared__ __align__(16) unsigned short s_lo[16 * 256];   // 8 KB
    const int tid = threadIdx.x;
    const int wv = tid >> 6, lane = tid & 63;
    const int nt = blockIdx.x;                                // 64-node tile
    const float bias = bn1[lane];
    const int q = (lane >> 3) & 3, e7 = lane & 7, hi = lane >> 5;

    for (int i = 0; i < 16; ++i) {
        int nl = wv * 16 + i;                                 // local node 0..63
        int node = nt * 64 + nl;
        int e0 = off[node], e1 = off[node + 1];
        float s0 = 0.f, s1 = 0.f, s2 = 0.f, s3 = 0.f;
        int e = e0;
        for (; e + 3 < e1; e += 4) {
            s0 += bf2f(y1b[(size_t)csr[e] * 64 + lane]);
            s1 += bf2f(y1b[(size_t)csr[e + 1] * 64 + lane]);
            s2 += bf2f(y1b[(size_t)csr[e + 2] * 64 + lane]);
            s3 += bf2f(y1b[(size_t)csr[e + 3] * 64 + lane]);
        }
        for (; e < e1; ++e) s0 += bf2f(y1b[(size_t)csr[e] * 64 + lane]);
        float s = (s0 + s1) + (s2 + s3);
        int d = e1 - e0;
        float v = s / (float)(d < 1 ? 1 : d) + bias;
        v = v > 0.f ? v : 0.f;
        unsigned short h = f2bf(v);
        int lt = (nl & 7) * 2 + hi;
        int o = lt * 256 + ((nl >> 3) + 8 * q) * 8 + e7;
        s_hi[o] = h;
        s_lo[o] = f2bf(v - bf2f(h));
    }
    __syncthreads();
    // global tile g = (nt>>1)*32 + (lt>>1)*4 + 2 + (lt&1);  half-tile rows
    // (nt&1)*8 .. +7, cols q*4 groups -> 16B chunks, 128B contiguous runs.
    for (int idx = tid; idx < 512; idx += 256) {
        int lt = idx >> 5, sub = idx & 31;
        int ln = sub & 7, qq = sub >> 3;
        size_t g = (size_t)(nt >> 1) * 32 + (lt >> 1) * 4 + 2 + (lt & 1);
        size_t dst = g * 512 + (size_t)((nt & 1) * 8 + ln + 16 * qq) * 8;
        int src = lt * 256 + (ln + 8 * qq) * 8;
        *(uint4*)&h1_hi[dst] = *(const uint4*)&s_hi[src];
        *(uint4*)&h1_lo[dst] = *(const uint4*)&s_lo[src];
    }
}

// ============ fused MLP (MFMA hi/lo): [16384,1024] -> 256 -> 256 -> 1 ===
#define S1 264                                     // bf16 LDS row stride
#define S2 260                                     // f32  LDS row stride
__global__ __launch_bounds__(256) void k_mlp(const unsigned short* __restrict__ h1_hi,
                                             const unsigned short* __restrict__ h1_lo,
                                             const unsigned short* __restrict__ w0tt_hi,
                                             const unsigned short* __restrict__ w0tt_lo,
                                             const float* __restrict__ b0,
                                             const unsigned short* __restrict__ w1tt_hi,
                                             const unsigned short* __restrict__ w1tt_lo,
                                             const float* __restrict__ b1,
                                             const float* __restrict__ w2,
                                             const float* __restrict__ b2,
                                             float* __restrict__ out) {
    __shared__ unsigned short xs_hi[16 * S1];
    __shared__ unsigned short xs_lo[16 * S1];
    __shared__ float xs2[16 * S2];
    const int tid = threadIdx.x;
    const int wv = tid >> 6, l = tid & 63;
    const int lr = l & 15, lg = l >> 4;
    const int row0 = blockIdx.x * 16;

    f32x4 acc[4];
#pragma unroll
    for (int t = 0; t < 4; ++t) {
        float bv = b0[wv * 64 + t * 16 + lr];
        acc[t] = (f32x4){bv, bv, bv, bv};
    }
    for (int kc = 0; kc < 32; ++kc) {
        const size_t aoff = ((size_t)blockIdx.x * 32 + kc) * 512 + l * 8;
        bf16x8 ahi = *(const bf16x8*)(h1_hi + aoff);
        bf16x8 alo = *(const bf16x8*)(h1_lo + aoff);
#pragma unroll
        for (int t = 0; t < 4; ++t) {
            size_t boff = ((size_t)(wv * 4 + t) * 32 + kc) * 512 + l * 8;
            bf16x8 bhi = *(const bf16x8*)(w0tt_hi + boff);
            bf16x8 blo = *(const bf16x8*)(w0tt_lo + boff);
            acc[t] = __builtin_amdgcn_mfma_f32_16x16x32_bf16(ahi, bhi, acc[t], 0, 0, 0);
            acc[t] = __builtin_amdgcn_mfma_f32_16x16x32_bf16(alo, bhi, acc[t], 0, 0, 0);
            acc[t] = __builtin_amdgcn_mfma_f32_16x16x32_bf16(ahi, blo, acc[t], 0, 0, 0);
        }
    }
#pragma unroll
    for (int t = 0; t < 4; ++t)
#pragma unroll
        for (int r = 0; r < 4; ++r) {
            float v = tanhf(acc[t][r]);
            unsigned short h = f2bf(v);
            int o = (lg * 4 + r) * S1 + wv * 64 + t * 16 + lr;
            xs_hi[o] = h;
            xs_lo[o] = f2bf(v - bf2f(h));
        }
    __syncthreads();

    f32x4 acc2[4];
#pragma unroll
    for (int t = 0; t < 4; ++t) {
        float bv = b1[wv * 64 + t * 16 + lr];
        acc2[t] = (f32x4){bv, bv, bv, bv};
    }
    for (int kc = 0; kc < 8; ++kc) {
        const int aoff = lr * S1 + kc * 32 + lg * 8;
        bf16x8 ahi = *(const bf16x8*)(xs_hi + aoff);
        bf16x8 alo = *(const bf16x8*)(xs_lo + aoff);
#pragma unroll
        for (int t = 0; t < 4; ++t) {
            size_t boff = ((size_t)(wv * 4 + t) * 8 + kc) * 512 + l * 8;
            bf16x8 bhi = *(const bf16x8*)(w1tt_hi + boff);
            bf16x8 blo = *(const bf16x8*)(w1tt_lo + boff);
            acc2[t] = __builtin_amdgcn_mfma_f32_16x16x32_bf16(ahi, bhi, acc2[t], 0, 0, 0);
            acc2[t] = __builtin_amdgcn_mfma_f32_16x16x32_bf16(alo, bhi, acc2[t], 0, 0, 0);
            acc2[t] = __builtin_amdgcn_mfma_f32_16x16x32_bf16(ahi, blo, acc2[t], 0, 0, 0);
        }
    }
#pragma unroll
    for (int t = 0; t < 4; ++t)
#pragma unroll
        for (int r = 0; r < 4; ++r)
            xs2[(lg * 4 + r) * S2 + wv * 64 + t * 16 + lr] = tanhf(acc2[t][r]);
    __syncthreads();

    {
        const int row = tid >> 4, seg = tid & 15;
        float p = 0.f;
#pragma unroll
        for (int c = 0; c < 16; ++c)
            p += xs2[row * S2 + seg * 16 + c] * w2[seg * 16 + c];
        p += __shfl_xor(p, 1);
        p += __shfl_xor(p, 2);
        p += __shfl_xor(p, 4);
        p += __shfl_xor(p, 8);
        if (seg == 0) out[row0 + row] = p + b2[0];
    }
}

extern "C" void kernel_launch(void* const* d_in, const int* in_sizes, int n_in,
                              void* d_out, int out_size, void* d_ws, size_t ws_size,
                              hipStream_t stream) {
    const float* obs  = (const float*)d_in[0];
    const int*   edge = (const int*)d_in[1];
    const float* ws0  = (const float*)d_in[2];
    const float* bs0  = (const float*)d_in[3];
    const float* wn0  = (const float*)d_in[4];
    const float* bn0  = (const float*)d_in[5];
    const float* ws1  = (const float*)d_in[6];
    const float* bs1  = (const float*)d_in[7];
    const float* wn1  = (const float*)d_in[8];
    const float* bn1  = (const float*)d_in[9];
    const float* w0   = (const float*)d_in[10];
    const float* b0   = (const float*)d_in[11];
    const float* w1   = (const float*)d_in[12];
    const float* b1   = (const float*)d_in[13];
    const float* w2   = (const float*)d_in[14];
    const float* b2   = (const float*)d_in[15];
    float* out = (float*)d_out;

    char* wsb = (char*)d_ws;
    int*   deg_i  = (int*)wsb;                                  // NN
    int*   off    = deg_i + NN;                                 // NN+1
    int*   cursor = off + NN + 1;                               // NN
    int*   bsum   = cursor + NN;                                // 256
    int*   boff   = bsum + 256;                                 // 256
    int*   csr    = boff + 256;                                 // NE
    float* agg0   = (float*)(csr + NE);                         // NN*16
    float* h0t    = agg0 + (size_t)NN * 16;                     // NN*128
    unsigned short* y1b     = (unsigned short*)(h0t + (size_t)NN * 128); // NN*64
    unsigned short* h1_hi   = y1b + (size_t)NN * 64;            // ROWS*1024
    unsigned short* h1_lo   = h1_hi + (size_t)ROWS * 1024;
    unsigned short* w0tt_hi = h1_lo + (size_t)ROWS * 1024;      // 256x1024
    unsigned short* w0tt_lo = w0tt_hi + 256 * 1024;
    unsigned short* w1tt_hi = w0tt_lo + 256 * 1024;             // 256x256
    unsigned short* w1tt_lo = w1tt_hi + 256 * 256;
    unsigned short* ws1tt_hi = w1tt_lo + 256 * 256;             // 64x128
    unsigned short* ws1tt_lo = ws1tt_hi + 64 * 128;
    unsigned short* wn1tt_hi = ws1tt_lo + 64 * 128;
    unsigned short* wn1tt_lo = wn1tt_hi + 64 * 128;

    hipMemsetAsync(deg_i, 0, (size_t)NN * sizeof(int), stream);

    k_prep<<<dim3(1024), dim3(256), 0, stream>>>(w0,  w0tt_hi, w0tt_lo, 8, 255, 32, 1024 * 256);
    k_prep<<<dim3(256),  dim3(256), 0, stream>>>(w1,  w1tt_hi, w1tt_lo, 8, 255, 8,  256 * 256);
    k_prep<<<dim3(32),   dim3(256), 0, stream>>>(ws1, ws1tt_hi, ws1tt_lo, 6, 63, 4, 128 * 64);
    k_prep<<<dim3(32),   dim3(256), 0, stream>>>(wn1, wn1tt_hi, wn1tt_lo, 6, 63, 4, 128 * 64);

    k_hist   <<<dim3(NE / 256), dim3(256), 0, stream>>>(edge, deg_i);
    k_scanA  <<<dim3(256),      dim3(256), 0, stream>>>(deg_i, bsum);
    k_scanB  <<<dim3(1),        dim3(256), 0, stream>>>(bsum, boff);
    k_scanC  <<<dim3(256),      dim3(256), 0, stream>>>(deg_i, boff, off, cursor);
    k_scatter<<<dim3(NE / 256), dim3(256), 0, stream>>>(edge, cursor, csr);

    k_agg0   <<<dim3(NN * 16 / 256), dim3(256), 0, stream>>>(obs, off, csr, agg0);
    k_node0  <<<dim3(NN / 4),        dim3(256), 0, stream>>>(obs, agg0, off, ws0, bs0, wn0, bn0, h0t);
    k_fused1 <<<dim3(NN / 128),      dim3(256), 0, stream>>>(h0t, ws1tt_hi, ws1tt_lo, wn1tt_hi, wn1tt_lo, bs1, h1_hi, h1_lo, y1b);
    k_agg1f  <<<dim3(NN / 64),       dim3(256), 0, stream>>>(y1b, off, csr, bn1, h1_hi, h1_lo);
    k_mlp    <<<dim3(ROWS / 16),     dim3(256), 0, stream>>>(h1_hi, h1_lo, w0tt_hi, w0tt_lo, b0, w1tt_hi, w1tt_lo, b1, w2, b2, out);
}

// Round 10
// 309.675 us; speedup vs baseline: 3.2087x; 1.2271x over previous
//
#include <hip/hip_runtime.h>

#define STEPS 64
#define NUM_CPU 4
#define AGENTS 64
#define PHASES 8
#define NN (STEPS*NUM_CPU*AGENTS*PHASES)   // 131072 nodes
#define NE (NN*8)                          // 1048576 edges
#define ROWS (NN/PHASES)                   // 16384 MLP rows

typedef __attribute__((ext_vector_type(8))) short bf16x8;
typedef __attribute__((ext_vector_type(4))) float f32x4;

__device__ inline unsigned short f2bf(float x) {
    unsigned int b = __float_as_uint(x);
    return (unsigned short)((b + 0x7FFF + ((b >> 16) & 1)) >> 16);
}
__device__ inline float bf2f(unsigned short h) {
    return __uint_as_float(((unsigned int)h) << 16);
}
__device__ inline void split8(const float* a, bf16x8& hi, bf16x8& lo) {
#pragma unroll
    for (int i = 0; i < 8; ++i) {
        float x = a[i];
        unsigned short h = f2bf(x);
        hi[i] = (short)h;
        lo[i] = (short)f2bf(x - bf2f(h));
    }
}

// fragment-tile offset: value (n, k) lives at
//   ((n>>4)*TK + (k>>5))*512 + ((n&15) + 16*((k>>3)&3))*8 + (k&7),  TK=K/32.

// ================= CSR construction (counting sort by dst) =============
__global__ __launch_bounds__(256) void k_hist(const int* __restrict__ edge,
                                              int* __restrict__ deg_i) {
    int e = blockIdx.x * 256 + threadIdx.x;
    if (e < NE) atomicAdd(&deg_i[edge[NE + e]], 1);
}

__global__ __launch_bounds__(256) void k_scanA(const int* __restrict__ deg,
                                               int* __restrict__ bsum) {
    __shared__ int s[256];
    const int b = blockIdx.x, t = threadIdx.x;
    const int2 v = *(const int2*)&deg[b * 512 + t * 2];
    s[t] = v.x + v.y;
    __syncthreads();
    for (int d = 128; d; d >>= 1) {
        if (t < d) s[t] += s[t + d];
        __syncthreads();
    }
    if (t == 0) bsum[b] = s[0];
}

__global__ __launch_bounds__(256) void k_scanB(const int* __restrict__ bsum,
                                               int* __restrict__ boff) {
    __shared__ int s[256];
    const int t = threadIdx.x;
    int v = bsum[t];
    s[t] = v;
    __syncthreads();
    for (int d = 1; d < 256; d <<= 1) {
        int x = (t >= d) ? s[t - d] : 0;
        __syncthreads();
        s[t] += x;
        __syncthreads();
    }
    boff[t] = s[t] - v;
}

__global__ __launch_bounds__(256) void k_scanC(const int* __restrict__ deg,
                                               const int* __restrict__ boff,
                                               int* __restrict__ off,
                                               int* __restrict__ cursor) {
    __shared__ int s[256];
    const int b = blockIdx.x, t = threadIdx.x;
    const int2 v = *(const int2*)&deg[b * 512 + t * 2];
    const int pair = v.x + v.y;
    s[t] = pair;
    __syncthreads();
    for (int d = 1; d < 256; d <<= 1) {
        int x = (t >= d) ? s[t - d] : 0;
        __syncthreads();
        s[t] += x;
        __syncthreads();
    }
    int pre = boff[b] + s[t] - pair;
    int i0 = b * 512 + t * 2;
    off[i0] = pre;          cursor[i0] = pre;
    off[i0 + 1] = pre + v.x; cursor[i0 + 1] = pre + v.x;
    if (b == 255 && t == 255) off[NN] = pre + pair;
}

__global__ __launch_bounds__(256) void k_scatter(const int* __restrict__ edge,
                                                 int* __restrict__ cursor,
                                                 int* __restrict__ csr) {
    int e = blockIdx.x * 256 + threadIdx.x;
    if (e >= NE) return;
    int dst = edge[NE + e];
    int pos = atomicAdd(&cursor[dst], 1);
    csr[pos] = edge[e];
}

// ===== weight prep: src[K][N] f32 -> fragment-tile bf16 hi/lo planes ====
__global__ __launch_bounds__(256) void k_prep(const float* __restrict__ src,
                                              unsigned short* __restrict__ dhi,
                                              unsigned short* __restrict__ dlo,
                                              int nshift, int nmask, int tk, int total) {
    int gid = blockIdx.x * 256 + threadIdx.x;
    if (gid >= total) return;
    int k = gid >> nshift, n = gid & nmask;
    float x = src[gid];
    unsigned short h = f2bf(x);
    size_t o = ((size_t)(n >> 4) * tk + (k >> 5)) * 512
             + ((n & 15) + 16 * ((k >> 3) & 3)) * 8 + (k & 7);
    dhi[o] = h;
    dlo[o] = f2bf(x - bf2f(h));
}

// ================= layer 0: per-node aggregate of obs (16 feats) ========
__global__ __launch_bounds__(256) void k_agg0(const float* __restrict__ obs,
                                              const int* __restrict__ off,
                                              const int* __restrict__ csr,
                                              float* __restrict__ agg0) {
    int gid = blockIdx.x * 256 + threadIdx.x;
    int node = gid >> 4, f = gid & 15;
    if (node >= NN) return;
    int e0 = off[node], e1 = off[node + 1];
    float s0 = 0.f, s1 = 0.f, s2 = 0.f, s3 = 0.f;
    int e = e0;
    for (; e + 3 < e1; e += 4) {
        s0 += obs[csr[e] * 16 + f];
        s1 += obs[csr[e + 1] * 16 + f];
        s2 += obs[csr[e + 2] * 16 + f];
        s3 += obs[csr[e + 3] * 16 + f];
    }
    for (; e < e1; ++e) s0 += obs[csr[e] * 16 + f];
    agg0[node * 16 + f] = (s0 + s1) + (s2 + s3);
}

// ==== FUSED layer-0 transform + layer-1 GEMMs (MFMA hi/lo), 64 nodes/blk
//  lane computes its own A-fragments in-register (h0 never hits memory):
//    h0[node][j] = relu(bias + sum_k in[k]*w[k][j]),  w staged in LDS.
//  then h1_self = relu(h0@Ws1+bs1) -> LDS-staged fragment tiles,
//       y1 = h0@Wn1 -> bf16.
__global__ __launch_bounds__(256) void k_f01(const float* __restrict__ obs,
                                             const float* __restrict__ agg0,
                                             const int* __restrict__ off,
                                             const float* __restrict__ ws0,
                                             const float* __restrict__ bs0,
                                             const float* __restrict__ wn0,
                                             const float* __restrict__ bn0,
                                             const unsigned short* __restrict__ ws1tt_hi,
                                             const unsigned short* __restrict__ ws1tt_lo,
                                             const unsigned short* __restrict__ wn1tt_hi,
                                             const unsigned short* __restrict__ wn1tt_lo,
                                             const float* __restrict__ bs1,
                                             unsigned short* __restrict__ h1_hi,
                                             unsigned short* __restrict__ h1_lo,
                                             unsigned short* __restrict__ y1b) {
    __shared__ float w0s[16 * 64];                 // 4 KB
    __shared__ float w0n[16 * 64];                 // 4 KB
    __shared__ float biasS[64], biasN[64];
    __shared__ __align__(16) unsigned short s_hi[16 * 256];   // 8 KB
    __shared__ __align__(16) unsigned short s_lo[16 * 256];   // 8 KB
    const int tid = threadIdx.x;
    for (int t = tid; t < 1024; t += 256) { w0s[t] = ws0[t]; w0n[t] = wn0[t]; }
    if (tid < 64) { biasS[tid] = bs0[tid]; biasN[tid] = bn0[tid]; }
    __syncthreads();

    const int wv = tid >> 6, l = tid & 63;
    const int lr = l & 15, lg = l >> 4;
    const int nt = blockIdx.x;                     // 64-node tile
    const int tile = nt * 4 + wv;                  // 16-node MFMA tile
    const int node = tile * 16 + lr;

    // ---- per-lane inputs (node transform) ----
    float xin[16], ain[16];
    {
        const float* xp = obs + (size_t)node * 16;
        const float* ap = agg0 + (size_t)node * 16;
#pragma unroll
        for (int q = 0; q < 4; ++q) {
            *(float4*)&xin[q * 4] = *(const float4*)(xp + q * 4);
            *(float4*)&ain[q * 4] = *(const float4*)(ap + q * 4);
        }
        int d = off[node + 1] - off[node];
        float inv = 1.f / (float)(d < 1 ? 1 : d);
#pragma unroll
        for (int k = 0; k < 16; ++k) ain[k] *= inv;
    }

    // ---- compute the 4 A-fragments (exact f32, then hi/lo split) ----
    bf16x8 ahi[4], alo[4];
#pragma unroll
    for (int kc = 0; kc < 4; ++kc) {
        const int half = kc >> 1;                  // 0=self, 1=neigh
        const int jb = (kc & 1) * 32 + lg * 8;
        const float* w = half ? w0n : w0s;
        const float* bias = half ? biasN : biasS;
        const float* in = half ? ain : xin;
        float a8[8];
#pragma unroll
        for (int i = 0; i < 8; ++i) a8[i] = bias[jb + i];
        for (int k = 0; k < 16; ++k) {
            const float xv = in[k];
            const float4 wa = *(const float4*)&w[k * 64 + jb];
            const float4 wb = *(const float4*)&w[k * 64 + jb + 4];
            a8[0] += xv * wa.x; a8[1] += xv * wa.y;
            a8[2] += xv * wa.z; a8[3] += xv * wa.w;
            a8[4] += xv * wb.x; a8[5] += xv * wb.y;
            a8[6] += xv * wb.z; a8[7] += xv * wb.w;
        }
#pragma unroll
        for (int i = 0; i < 8; ++i) a8[i] = a8[i] > 0.f ? a8[i] : 0.f;
        split8(a8, ahi[kc], alo[kc]);
    }

    // ---- layer-1 MFMA: 8 output col-tiles (4 self -> h1, 4 -> y1) ----
    f32x4 acc[8];
#pragma unroll
    for (int t = 0; t < 8; ++t) {
        float bv = (t < 4) ? bs1[t * 16 + lr] : 0.f;
        acc[t] = (f32x4){bv, bv, bv, bv};
    }
#pragma unroll
    for (int kc = 0; kc < 4; ++kc) {
#pragma unroll
        for (int t = 0; t < 8; ++t) {
            const unsigned short* bh = (t < 4) ? ws1tt_hi : wn1tt_hi;
            const unsigned short* bl = (t < 4) ? ws1tt_lo : wn1tt_lo;
            size_t boff = ((size_t)(t & 3) * 4 + kc) * 512 + l * 8;
            bf16x8 bhi = *(const bf16x8*)(bh + boff);
            bf16x8 blo = *(const bf16x8*)(bl + boff);
            acc[t] = __builtin_amdgcn_mfma_f32_16x16x32_bf16(ahi[kc], bhi, acc[t], 0, 0, 0);
            acc[t] = __builtin_amdgcn_mfma_f32_16x16x32_bf16(alo[kc], bhi, acc[t], 0, 0, 0);
            acc[t] = __builtin_amdgcn_mfma_f32_16x16x32_bf16(ahi[kc], blo, acc[t], 0, 0, 0);
        }
    }

    // ---- epilogue: D layout m = lg*4+r, n = lr ----
#pragma unroll
    for (int t = 0; t < 8; ++t) {
#pragma unroll
        for (int r = 0; r < 4; ++r) {
            const int nl = wv * 16 + lg * 4 + r;   // local node 0..63
            const size_t gnode = (size_t)nt * 64 + nl;
            if (t < 4) {
                float v = acc[t][r];
                v = v > 0.f ? v : 0.f;
                unsigned short h = f2bf(v);
                const int c = t * 16 + lr;         // h1 col 0..63
                const int lt = (nl & 7) * 2 + (c >> 5);
                const int o = lt * 256 + ((nl >> 3) + 8 * ((c >> 3) & 3)) * 8 + (c & 7);
                s_hi[o] = h;
                s_lo[o] = f2bf(v - bf2f(h));
            } else {
                y1b[gnode * 64 + (t - 4) * 16 + lr] = f2bf(acc[t][r]);
            }
        }
    }
    __syncthreads();
    // copy out half-tiles: g = (nt>>1)*32 + (lt>>1)*4 + (lt&1)  (cols 0..63)
    for (int idx = tid; idx < 512; idx += 256) {
        int lt = idx >> 5, sub = idx & 31;
        int ln = sub & 7, qq = sub >> 3;
        size_t g = (size_t)(nt >> 1) * 32 + (lt >> 1) * 4 + (lt & 1);
        size_t dst = g * 512 + (size_t)((nt & 1) * 8 + ln + 16 * qq) * 8;
        int src = lt * 256 + (ln + 8 * qq) * 8;
        *(uint4*)&h1_hi[dst] = *(const uint4*)&s_hi[src];
        *(uint4*)&h1_lo[dst] = *(const uint4*)&s_lo[src];
    }
}

// ==== layer-1 neighbor aggregate (bf16 gather) + epilogue, 64/block =====
__global__ __launch_bounds__(256) void k_agg1f(const unsigned short* __restrict__ y1b,
                                               const int* __restrict__ off,
                                               const int* __restrict__ csr,
                                               const float* __restrict__ bn1,
                                               unsigned short* __restrict__ h1_hi,
                                               unsigned short* __restrict__ h1_lo) {
    __shared__ __align__(16) unsigned short s_hi[16 * 256];   // 8 KB
    __shared__ __align__(16) unsigned short s_lo[16 * 256];   // 8 KB
    const int tid = threadIdx.x;
    const int wv = tid >> 6, lane = tid & 63;
    const int nt = blockIdx.x;                                // 64-node tile
    const float bias = bn1[lane];
    const int q = (lane >> 3) & 3, e7 = lane & 7, hi = lane >> 5;

    for (int i = 0; i < 16; ++i) {
        int nl = wv * 16 + i;                                 // local node 0..63
        int node = nt * 64 + nl;
        int e0 = off[node], e1 = off[node + 1];
        float s0 = 0.f, s1 = 0.f, s2 = 0.f, s3 = 0.f;
        int e = e0;
        for (; e + 3 < e1; e += 4) {
            s0 += bf2f(y1b[(size_t)csr[e] * 64 + lane]);
            s1 += bf2f(y1b[(size_t)csr[e + 1] * 64 + lane]);
            s2 += bf2f(y1b[(size_t)csr[e + 2] * 64 + lane]);
            s3 += bf2f(y1b[(size_t)csr[e + 3] * 64 + lane]);
        }
        for (; e < e1; ++e) s0 += bf2f(y1b[(size_t)csr[e] * 64 + lane]);
        float s = (s0 + s1) + (s2 + s3);
        int d = e1 - e0;
        float v = s / (float)(d < 1 ? 1 : d) + bias;
        v = v > 0.f ? v : 0.f;
        unsigned short h = f2bf(v);
        int lt = (nl & 7) * 2 + hi;
        int o = lt * 256 + ((nl >> 3) + 8 * q) * 8 + e7;
        s_hi[o] = h;
        s_lo[o] = f2bf(v - bf2f(h));
    }
    __syncthreads();
    for (int idx = tid; idx < 512; idx += 256) {
        int lt = idx >> 5, sub = idx & 31;
        int ln = sub & 7, qq = sub >> 3;
        size_t g = (size_t)(nt >> 1) * 32 + (lt >> 1) * 4 + 2 + (lt & 1);
        size_t dst = g * 512 + (size_t)((nt & 1) * 8 + ln + 16 * qq) * 8;
        int src = lt * 256 + (ln + 8 * qq) * 8;
        *(uint4*)&h1_hi[dst] = *(const uint4*)&s_hi[src];
        *(uint4*)&h1_lo[dst] = *(const uint4*)&s_lo[src];
    }
}

// ============ fused MLP (MFMA hi/lo): [16384,1024] -> 256 -> 256 -> 1 ===
#define S1 264                                     // bf16 LDS row stride
#define S2 260                                     // f32  LDS row stride
__global__ __launch_bounds__(256) void k_mlp(const unsigned short* __restrict__ h1_hi,
                                             const unsigned short* __restrict__ h1_lo,
                                             const unsigned short* __restrict__ w0tt_hi,
                                             const unsigned short* __restrict__ w0tt_lo,
                                             const float* __restrict__ b0,
                                             const unsigned short* __restrict__ w1tt_hi,
                                             const unsigned short* __restrict__ w1tt_lo,
                                             const float* __restrict__ b1,
                                             const float* __restrict__ w2,
                                             const float* __restrict__ b2,
                                             float* __restrict__ out) {
    __shared__ unsigned short xs_hi[16 * S1];
    __shared__ unsigned short xs_lo[16 * S1];
    __shared__ float xs2[16 * S2];
    const int tid = threadIdx.x;
    const int wv = tid >> 6, l = tid & 63;
    const int lr = l & 15, lg = l >> 4;
    const int row0 = blockIdx.x * 16;

    f32x4 acc[4];
#pragma unroll
    for (int t = 0; t < 4; ++t) {
        float bv = b0[wv * 64 + t * 16 + lr];
        acc[t] = (f32x4){bv, bv, bv, bv};
    }
    for (int kc = 0; kc < 32; ++kc) {
        const size_t aoff = ((size_t)blockIdx.x * 32 + kc) * 512 + l * 8;
        bf16x8 ahi = *(const bf16x8*)(h1_hi + aoff);
        bf16x8 alo = *(const bf16x8*)(h1_lo + aoff);
#pragma unroll
        for (int t = 0; t < 4; ++t) {
            size_t boff = ((size_t)(wv * 4 + t) * 32 + kc) * 512 + l * 8;
            bf16x8 bhi = *(const bf16x8*)(w0tt_hi + boff);
            bf16x8 blo = *(const bf16x8*)(w0tt_lo + boff);
            acc[t] = __builtin_amdgcn_mfma_f32_16x16x32_bf16(ahi, bhi, acc[t], 0, 0, 0);
            acc[t] = __builtin_amdgcn_mfma_f32_16x16x32_bf16(alo, bhi, acc[t], 0, 0, 0);
            acc[t] = __builtin_amdgcn_mfma_f32_16x16x32_bf16(ahi, blo, acc[t], 0, 0, 0);
        }
    }
#pragma unroll
    for (int t = 0; t < 4; ++t)
#pragma unroll
        for (int r = 0; r < 4; ++r) {
            float v = tanhf(acc[t][r]);
            unsigned short h = f2bf(v);
            int o = (lg * 4 + r) * S1 + wv * 64 + t * 16 + lr;
            xs_hi[o] = h;
            xs_lo[o] = f2bf(v - bf2f(h));
        }
    __syncthreads();

    f32x4 acc2[4];
#pragma unroll
    for (int t = 0; t < 4; ++t) {
        float bv = b1[wv * 64 + t * 16 + lr];
        acc2[t] = (f32x4){bv, bv, bv, bv};
    }
    for (int kc = 0; kc < 8; ++kc) {
        const int aoff = lr * S1 + kc * 32 + lg * 8;
        bf16x8 ahi = *(const bf16x8*)(xs_hi + aoff);
        bf16x8 alo = *(const bf16x8*)(xs_lo + aoff);
#pragma unroll
        for (int t = 0; t < 4; ++t) {
            size_t boff = ((size_t)(wv * 4 + t) * 8 + kc) * 512 + l * 8;
            bf16x8 bhi = *(const bf16x8*)(w1tt_hi + boff);
            bf16x8 blo = *(const bf16x8*)(w1tt_lo + boff);
            acc2[t] = __builtin_amdgcn_mfma_f32_16x16x32_bf16(ahi, bhi, acc2[t], 0, 0, 0);
            acc2[t] = __builtin_amdgcn_mfma_f32_16x16x32_bf16(alo, bhi, acc2[t], 0, 0, 0);
            acc2[t] = __builtin_amdgcn_mfma_f32_16x16x32_bf16(ahi, blo, acc2[t], 0, 0, 0);
        }
    }
#pragma unroll
    for (int t = 0; t < 4; ++t)
#pragma unroll
        for (int r = 0; r < 4; ++r)
            xs2[(lg * 4 + r) * S2 + wv * 64 + t * 16 + lr] = tanhf(acc2[t][r]);
    __syncthreads();

    {
        const int row = tid >> 4, seg = tid & 15;
        float p = 0.f;
#pragma unroll
        for (int c = 0; c < 16; ++c)
            p += xs2[row * S2 + seg * 16 + c] * w2[seg * 16 + c];
        p += __shfl_xor(p, 1);
        p += __shfl_xor(p, 2);
        p += __shfl_xor(p, 4);
        p += __shfl_xor(p, 8);
        if (seg == 0) out[row0 + row] = p + b2[0];
    }
}

extern "C" void kernel_launch(void* const* d_in, const int* in_sizes, int n_in,
                              void* d_out, int out_size, void* d_ws, size_t ws_size,
                              hipStream_t stream) {
    const float* obs  = (const float*)d_in[0];
    const int*   edge = (const int*)d_in[1];
    const float* ws0  = (const float*)d_in[2];
    const float* bs0  = (const float*)d_in[3];
    const float* wn0  = (const float*)d_in[4];
    const float* bn0  = (const float*)d_in[5];
    const float* ws1  = (const float*)d_in[6];
    const float* bs1  = (const float*)d_in[7];
    const float* wn1  = (const float*)d_in[8];
    const float* bn1  = (const float*)d_in[9];
    const float* w0   = (const float*)d_in[10];
    const float* b0   = (const float*)d_in[11];
    const float* w1   = (const float*)d_in[12];
    const float* b1   = (const float*)d_in[13];
    const float* w2   = (const float*)d_in[14];
    const float* b2   = (const float*)d_in[15];
    float* out = (float*)d_out;

    char* wsb = (char*)d_ws;
    int*   deg_i  = (int*)wsb;                                  // NN
    int*   off    = deg_i + NN;                                 // NN+1
    int*   cursor = off + NN + 1;                               // NN
    int*   bsum   = cursor + NN;                                // 256
    int*   boff   = bsum + 256;                                 // 256
    int*   csr    = boff + 256;                                 // NE
    float* agg0   = (float*)(csr + NE);                         // NN*16
    unsigned short* y1b     = (unsigned short*)(agg0 + (size_t)NN * 16); // NN*64
    unsigned short* h1_hi   = y1b + (size_t)NN * 64;            // ROWS*1024
    unsigned short* h1_lo   = h1_hi + (size_t)ROWS * 1024;
    unsigned short* w0tt_hi = h1_lo + (size_t)ROWS * 1024;      // 256x1024
    unsigned short* w0tt_lo = w0tt_hi + 256 * 1024;
    unsigned short* w1tt_hi = w0tt_lo + 256 * 1024;             // 256x256
    unsigned short* w1tt_lo = w1tt_hi + 256 * 256;
    unsigned short* ws1tt_hi = w1tt_lo + 256 * 256;             // 64x128
    unsigned short* ws1tt_lo = ws1tt_hi + 64 * 128;
    unsigned short* wn1tt_hi = ws1tt_lo + 64 * 128;
    unsigned short* wn1tt_lo = wn1tt_hi + 64 * 128;

    hipMemsetAsync(deg_i, 0, (size_t)NN * sizeof(int), stream);

    k_prep<<<dim3(1024), dim3(256), 0, stream>>>(w0,  w0tt_hi, w0tt_lo, 8, 255, 32, 1024 * 256);
    k_prep<<<dim3(256),  dim3(256), 0, stream>>>(w1,  w1tt_hi, w1tt_lo, 8, 255, 8,  256 * 256);
    k_prep<<<dim3(32),   dim3(256), 0, stream>>>(ws1, ws1tt_hi, ws1tt_lo, 6, 63, 4, 128 * 64);
    k_prep<<<dim3(32),   dim3(256), 0, stream>>>(wn1, wn1tt_hi, wn1tt_lo, 6, 63, 4, 128 * 64);

    k_hist   <<<dim3(NE / 256), dim3(256), 0, stream>>>(edge, deg_i);
    k_scanA  <<<dim3(256),      dim3(256), 0, stream>>>(deg_i, bsum);
    k_scanB  <<<dim3(1),        dim3(256), 0, stream>>>(bsum, boff);
    k_scanC  <<<dim3(256),      dim3(256), 0, stream>>>(deg_i, boff, off, cursor);
    k_scatter<<<dim3(NE / 256), dim3(256), 0, stream>>>(edge, cursor, csr);

    k_agg0   <<<dim3(NN * 16 / 256), dim3(256), 0, stream>>>(obs, off, csr, agg0);
    k_f01    <<<dim3(NN / 64),       dim3(256), 0, stream>>>(obs, agg0, off, ws0, bs0, wn0, bn0,
                                                             ws1tt_hi, ws1tt_lo, wn1tt_hi, wn1tt_lo,
                                                             bs1, h1_hi, h1_lo, y1b);
    k_agg1f  <<<dim3(NN / 64),       dim3(256), 0, stream>>>(y1b, off, csr, bn1, h1_hi, h1_lo);
    k_mlp    <<<dim3(ROWS / 16),     dim3(256), 0, stream>>>(h1_hi, h1_lo, w0tt_hi, w0tt_lo, b0, w1tt_hi, w1tt_lo, b1, w2, b2, out);
}

// Round 11
// 252.870 us; speedup vs baseline: 3.9295x; 1.2246x over previous
//
#include <hip/hip_runtime.h>

#define STEPS 64
#define NUM_CPU 4
#define AGENTS 64
#define PHASES 8
#define NN (STEPS*NUM_CPU*AGENTS*PHASES)   // 131072 nodes
#define NE (NN*8)                          // 1048576 edges
#define ROWS (NN/PHASES)                   // 16384 MLP rows

typedef __attribute__((ext_vector_type(8))) short bf16x8;
typedef __attribute__((ext_vector_type(4))) float f32x4;

__device__ inline unsigned short f2bf(float x) {
    unsigned int b = __float_as_uint(x);
    return (unsigned short)((b + 0x7FFF + ((b >> 16) & 1)) >> 16);
}
__device__ inline float bf2f(unsigned short h) {
    return __uint_as_float(((unsigned int)h) << 16);
}
__device__ inline void split8(const float* a, bf16x8& hi, bf16x8& lo) {
#pragma unroll
    for (int i = 0; i < 8; ++i) {
        float x = a[i];
        unsigned short h = f2bf(x);
        hi[i] = (short)h;
        lo[i] = (short)f2bf(x - bf2f(h));
    }
}

// fragment-tile offset: value (n, k) lives at
//   ((n>>4)*TK + (k>>5))*512 + ((n&15) + 16*((k>>3)&3))*8 + (k&7),  TK=K/32.

// ============ bucketed counting sort (all global writes coalesced) ======
// coarse histogram: 256 buckets by dst>>9
__global__ __launch_bounds__(256) void k_hist256(const int* __restrict__ edge,
                                                 int* __restrict__ bcnt) {
    __shared__ int c[256];
    const int tid = threadIdx.x;
    c[tid] = 0;
    __syncthreads();
    const int base = blockIdx.x * 1024;
    for (int i = tid; i < 1024; i += 256)
        atomicAdd(&c[edge[NE + base + i] >> 9], 1);
    __syncthreads();
    atomicAdd(&bcnt[tid], c[tid]);
}

__global__ __launch_bounds__(256) void k_scan256(const int* __restrict__ bcnt,
                                                 int* __restrict__ bbase,
                                                 int* __restrict__ bcur) {
    __shared__ int s[256];
    const int t = threadIdx.x;
    int v = bcnt[t];
    s[t] = v;
    __syncthreads();
    for (int d = 1; d < 256; d <<= 1) {
        int x = (t >= d) ? s[t - d] : 0;
        __syncthreads();
        s[t] += x;
        __syncthreads();
    }
    int ex = s[t] - v;
    bbase[t] = ex;
    bcur[t] = ex;
    if (t == 255) bbase[256] = s[255];
}

// bin 4096 edges/block into bucket-major pairs[]; per-block LDS sort makes
// the global writes contiguous runs (avg 128B per bucket per block).
__global__ __launch_bounds__(256) void k_bucket(const int* __restrict__ edge,
                                                int* __restrict__ bcur,
                                                int2* __restrict__ pairs) {
    __shared__ int rs[4096], rd[4096];             // 32 KB raw
    __shared__ int ss[4096], sd[4096];             // 32 KB sorted
    __shared__ int cnt[256], lbase[256], lcur[256], gbase[256];
    const int tid = threadIdx.x;
    const int e0 = blockIdx.x * 4096;
    cnt[tid] = 0;
    for (int i = tid; i < 4096; i += 256) {
        rs[i] = edge[e0 + i];
        rd[i] = edge[NE + e0 + i];
    }
    __syncthreads();
    for (int i = tid; i < 4096; i += 256) atomicAdd(&cnt[rd[i] >> 9], 1);
    __syncthreads();
    {
        const int v = cnt[tid];
        lbase[tid] = v;
        __syncthreads();
        for (int d = 1; d < 256; d <<= 1) {
            int x = (tid >= d) ? lbase[tid - d] : 0;
            __syncthreads();
            lbase[tid] += x;
            __syncthreads();
        }
        const int ex = lbase[tid] - v;             // own-index only: safe
        lbase[tid] = ex;
        lcur[tid] = ex;
        gbase[tid] = atomicAdd(&bcur[tid], v);
    }
    __syncthreads();
    for (int i = tid; i < 4096; i += 256) {
        int b = rd[i] >> 9;
        int p = atomicAdd(&lcur[b], 1);
        ss[p] = rs[i];
        sd[p] = rd[i];
    }
    __syncthreads();
    for (int j = tid; j < 4096; j += 256) {
        int b = sd[j] >> 9;
        pairs[gbase[b] + (j - lbase[b])] = (int2){ss[j], sd[j]};
    }
}

// per-bucket degree histogram -> deg[] (coalesced writes, no global atomics)
__global__ __launch_bounds__(256) void k_deg(const int2* __restrict__ pairs,
                                             const int* __restrict__ bbase,
                                             int* __restrict__ deg) {
    __shared__ int c[512];
    const int b = blockIdx.x, tid = threadIdx.x;
    c[tid] = 0; c[tid + 256] = 0;
    __syncthreads();
    const int n0 = bbase[b], n1 = bbase[b + 1];
    for (int j = n0 + tid; j < n1; j += 256) atomicAdd(&c[pairs[j].y & 511], 1);
    __syncthreads();
    deg[b * 512 + tid] = c[tid];
    deg[b * 512 + 256 + tid] = c[tid + 256];
}

// ---- two-level exclusive scan over deg (unchanged structure) ----
__global__ __launch_bounds__(256) void k_scanA(const int* __restrict__ deg,
                                               int* __restrict__ bsum) {
    __shared__ int s[256];
    const int b = blockIdx.x, t = threadIdx.x;
    const int2 v = *(const int2*)&deg[b * 512 + t * 2];
    s[t] = v.x + v.y;
    __syncthreads();
    for (int d = 128; d; d >>= 1) {
        if (t < d) s[t] += s[t + d];
        __syncthreads();
    }
    if (t == 0) bsum[b] = s[0];
}

__global__ __launch_bounds__(256) void k_scanB(const int* __restrict__ bsum,
                                               int* __restrict__ boff) {
    __shared__ int s[256];
    const int t = threadIdx.x;
    int v = bsum[t];
    s[t] = v;
    __syncthreads();
    for (int d = 1; d < 256; d <<= 1) {
        int x = (t >= d) ? s[t - d] : 0;
        __syncthreads();
        s[t] += x;
        __syncthreads();
    }
    boff[t] = s[t] - v;
}

__global__ __launch_bounds__(256) void k_scanC(const int* __restrict__ deg,
                                               const int* __restrict__ boff,
                                               int* __restrict__ off) {
    __shared__ int s[256];
    const int b = blockIdx.x, t = threadIdx.x;
    const int2 v = *(const int2*)&deg[b * 512 + t * 2];
    const int pair = v.x + v.y;
    s[t] = pair;
    __syncthreads();
    for (int d = 1; d < 256; d <<= 1) {
        int x = (t >= d) ? s[t - d] : 0;
        __syncthreads();
        s[t] += x;
        __syncthreads();
    }
    int pre = boff[b] + s[t] - pair;
    int i0 = b * 512 + t * 2;
    off[i0] = pre;
    off[i0 + 1] = pre + v.x;
    if (b == 255 && t == 255) off[NN] = pre + pair;
}

// per-bucket fine counting sort -> csr (fully coalesced contiguous write)
__global__ __launch_bounds__(256) void k_sort(const int2* __restrict__ pairs,
                                              const int* __restrict__ bbase,
                                              const int* __restrict__ off,
                                              int* __restrict__ csr) {
    __shared__ int lcur[512];
    __shared__ int sorted[6144];                   // 24 KB; mean 4096, +32 sigma
    const int b = blockIdx.x, tid = threadIdx.x;
    const int off0 = off[b * 512];
    lcur[tid] = off[b * 512 + tid] - off0;
    lcur[tid + 256] = off[b * 512 + 256 + tid] - off0;
    __syncthreads();
    const int n0 = bbase[b], n1 = bbase[b + 1];
    for (int j = n0 + tid; j < n1; j += 256) {
        int2 p = pairs[j];
        int loc = atomicAdd(&lcur[p.y & 511], 1);
        sorted[loc] = p.x;
    }
    __syncthreads();
    const int cnt = n1 - n0;
    for (int j = tid; j < cnt; j += 256) csr[off0 + j] = sorted[j];
}

// ===== weight prep: src[K][N] f32 -> fragment-tile bf16 hi/lo planes ====
__global__ __launch_bounds__(256) void k_prep(const float* __restrict__ src,
                                              unsigned short* __restrict__ dhi,
                                              unsigned short* __restrict__ dlo,
                                              int nshift, int nmask, int tk, int total) {
    int gid = blockIdx.x * 256 + threadIdx.x;
    if (gid >= total) return;
    int k = gid >> nshift, n = gid & nmask;
    float x = src[gid];
    unsigned short h = f2bf(x);
    size_t o = ((size_t)(n >> 4) * tk + (k >> 5)) * 512
             + ((n & 15) + 16 * ((k >> 3) & 3)) * 8 + (k & 7);
    dhi[o] = h;
    dlo[o] = f2bf(x - bf2f(h));
}

// ================= layer 0: per-node aggregate of obs (16 feats) ========
__global__ __launch_bounds__(256) void k_agg0(const float* __restrict__ obs,
                                              const int* __restrict__ off,
                                              const int* __restrict__ csr,
                                              float* __restrict__ agg0) {
    int gid = blockIdx.x * 256 + threadIdx.x;
    int node = gid >> 4, f = gid & 15;
    if (node >= NN) return;
    int e0 = off[node], e1 = off[node + 1];
    float s0 = 0.f, s1 = 0.f, s2 = 0.f, s3 = 0.f;
    int e = e0;
    for (; e + 3 < e1; e += 4) {
        s0 += obs[csr[e] * 16 + f];
        s1 += obs[csr[e + 1] * 16 + f];
        s2 += obs[csr[e + 2] * 16 + f];
        s3 += obs[csr[e + 3] * 16 + f];
    }
    for (; e < e1; ++e) s0 += obs[csr[e] * 16 + f];
    agg0[node * 16 + f] = (s0 + s1) + (s2 + s3);
}

// ==== FUSED layer-0 transform + layer-1 GEMMs (MFMA hi/lo), 64 nodes/blk
__global__ __launch_bounds__(256) void k_f01(const float* __restrict__ obs,
                                             const float* __restrict__ agg0,
                                             const int* __restrict__ off,
                                             const float* __restrict__ ws0,
                                             const float* __restrict__ bs0,
                                             const float* __restrict__ wn0,
                                             const float* __restrict__ bn0,
                                             const unsigned short* __restrict__ ws1tt_hi,
                                             const unsigned short* __restrict__ ws1tt_lo,
                                             const unsigned short* __restrict__ wn1tt_hi,
                                             const unsigned short* __restrict__ wn1tt_lo,
                                             const float* __restrict__ bs1,
                                             unsigned short* __restrict__ h1_hi,
                                             unsigned short* __restrict__ h1_lo,
                                             unsigned short* __restrict__ y1b) {
    __shared__ float w0s[16 * 64];
    __shared__ float w0n[16 * 64];
    __shared__ float biasS[64], biasN[64];
    __shared__ __align__(16) unsigned short s_hi[16 * 256];
    __shared__ __align__(16) unsigned short s_lo[16 * 256];
    const int tid = threadIdx.x;
    for (int t = tid; t < 1024; t += 256) { w0s[t] = ws0[t]; w0n[t] = wn0[t]; }
    if (tid < 64) { biasS[tid] = bs0[tid]; biasN[tid] = bn0[tid]; }
    __syncthreads();

    const int wv = tid >> 6, l = tid & 63;
    const int lr = l & 15, lg = l >> 4;
    const int nt = blockIdx.x;
    const int tile = nt * 4 + wv;
    const int node = tile * 16 + lr;

    float xin[16], ain[16];
    {
        const float* xp = obs + (size_t)node * 16;
        const float* ap = agg0 + (size_t)node * 16;
#pragma unroll
        for (int q = 0; q < 4; ++q) {
            *(float4*)&xin[q * 4] = *(const float4*)(xp + q * 4);
            *(float4*)&ain[q * 4] = *(const float4*)(ap + q * 4);
        }
        int d = off[node + 1] - off[node];
        float inv = 1.f / (float)(d < 1 ? 1 : d);
#pragma unroll
        for (int k = 0; k < 16; ++k) ain[k] *= inv;
    }

    bf16x8 ahi[4], alo[4];
#pragma unroll
    for (int kc = 0; kc < 4; ++kc) {
        const int half = kc >> 1;
        const int jb = (kc & 1) * 32 + lg * 8;
        const float* w = half ? w0n : w0s;
        const float* bias = half ? biasN : biasS;
        const float* in = half ? ain : xin;
        float a8[8];
#pragma unroll
        for (int i = 0; i < 8; ++i) a8[i] = bias[jb + i];
        for (int k = 0; k < 16; ++k) {
            const float xv = in[k];
            const float4 wa = *(const float4*)&w[k * 64 + jb];
            const float4 wb = *(const float4*)&w[k * 64 + jb + 4];
            a8[0] += xv * wa.x; a8[1] += xv * wa.y;
            a8[2] += xv * wa.z; a8[3] += xv * wa.w;
            a8[4] += xv * wb.x; a8[5] += xv * wb.y;
            a8[6] += xv * wb.z; a8[7] += xv * wb.w;
        }
#pragma unroll
        for (int i = 0; i < 8; ++i) a8[i] = a8[i] > 0.f ? a8[i] : 0.f;
        split8(a8, ahi[kc], alo[kc]);
    }

    f32x4 acc[8];
#pragma unroll
    for (int t = 0; t < 8; ++t) {
        float bv = (t < 4) ? bs1[t * 16 + lr] : 0.f;
        acc[t] = (f32x4){bv, bv, bv, bv};
    }
#pragma unroll
    for (int kc = 0; kc < 4; ++kc) {
#pragma unroll
        for (int t = 0; t < 8; ++t) {
            const unsigned short* bh = (t < 4) ? ws1tt_hi : wn1tt_hi;
            const unsigned short* bl = (t < 4) ? ws1tt_lo : wn1tt_lo;
            size_t boff = ((size_t)(t & 3) * 4 + kc) * 512 + l * 8;
            bf16x8 bhi = *(const bf16x8*)(bh + boff);
            bf16x8 blo = *(const bf16x8*)(bl + boff);
            acc[t] = __builtin_amdgcn_mfma_f32_16x16x32_bf16(ahi[kc], bhi, acc[t], 0, 0, 0);
            acc[t] = __builtin_amdgcn_mfma_f32_16x16x32_bf16(alo[kc], bhi, acc[t], 0, 0, 0);
            acc[t] = __builtin_amdgcn_mfma_f32_16x16x32_bf16(ahi[kc], blo, acc[t], 0, 0, 0);
        }
    }

#pragma unroll
    for (int t = 0; t < 8; ++t) {
#pragma unroll
        for (int r = 0; r < 4; ++r) {
            const int nl = wv * 16 + lg * 4 + r;
            const size_t gnode = (size_t)nt * 64 + nl;
            if (t < 4) {
                float v = acc[t][r];
                v = v > 0.f ? v : 0.f;
                unsigned short h = f2bf(v);
                const int c = t * 16 + lr;
                const int lt = (nl & 7) * 2 + (c >> 5);
                const int o = lt * 256 + ((nl >> 3) + 8 * ((c >> 3) & 3)) * 8 + (c & 7);
                s_hi[o] = h;
                s_lo[o] = f2bf(v - bf2f(h));
            } else {
                y1b[gnode * 64 + (t - 4) * 16 + lr] = f2bf(acc[t][r]);
            }
        }
    }
    __syncthreads();
    for (int idx = tid; idx < 512; idx += 256) {
        int lt = idx >> 5, sub = idx & 31;
        int ln = sub & 7, qq = sub >> 3;
        size_t g = (size_t)(nt >> 1) * 32 + (lt >> 1) * 4 + (lt & 1);
        size_t dst = g * 512 + (size_t)((nt & 1) * 8 + ln + 16 * qq) * 8;
        int src = lt * 256 + (ln + 8 * qq) * 8;
        *(uint4*)&h1_hi[dst] = *(const uint4*)&s_hi[src];
        *(uint4*)&h1_lo[dst] = *(const uint4*)&s_lo[src];
    }
}

// ==== layer-1 neighbor aggregate (bf16 gather) + epilogue, 64/block =====
__global__ __launch_bounds__(256) void k_agg1f(const unsigned short* __restrict__ y1b,
                                               const int* __restrict__ off,
                                               const int* __restrict__ csr,
                                               const float* __restrict__ bn1,
                                               unsigned short* __restrict__ h1_hi,
                                               unsigned short* __restrict__ h1_lo) {
    __shared__ __align__(16) unsigned short s_hi[16 * 256];
    __shared__ __align__(16) unsigned short s_lo[16 * 256];
    const int tid = threadIdx.x;
    const int wv = tid >> 6, lane = tid & 63;
    const int nt = blockIdx.x;
    const float bias = bn1[lane];
    const int q = (lane >> 3) & 3, e7 = lane & 7, hi = lane >> 5;

    for (int i = 0; i < 16; ++i) {
        int nl = wv * 16 + i;
        int node = nt * 64 + nl;
        int e0 = off[node], e1 = off[node + 1];
        float s0 = 0.f, s1 = 0.f, s2 = 0.f, s3 = 0.f;
        int e = e0;
        for (; e + 3 < e1; e += 4) {
            s0 += bf2f(y1b[(size_t)csr[e] * 64 + lane]);
            s1 += bf2f(y1b[(size_t)csr[e + 1] * 64 + lane]);
            s2 += bf2f(y1b[(size_t)csr[e + 2] * 64 + lane]);
            s3 += bf2f(y1b[(size_t)csr[e + 3] * 64 + lane]);
        }
        for (; e < e1; ++e) s0 += bf2f(y1b[(size_t)csr[e] * 64 + lane]);
        float s = (s0 + s1) + (s2 + s3);
        int d = e1 - e0;
        float v = s / (float)(d < 1 ? 1 : d) + bias;
        v = v > 0.f ? v : 0.f;
        unsigned short h = f2bf(v);
        int lt = (nl & 7) * 2 + hi;
        int o = lt * 256 + ((nl >> 3) + 8 * q) * 8 + e7;
        s_hi[o] = h;
        s_lo[o] = f2bf(v - bf2f(h));
    }
    __syncthreads();
    for (int idx = tid; idx < 512; idx += 256) {
        int lt = idx >> 5, sub = idx & 31;
        int ln = sub & 7, qq = sub >> 3;
        size_t g = (size_t)(nt >> 1) * 32 + (lt >> 1) * 4 + 2 + (lt & 1);
        size_t dst = g * 512 + (size_t)((nt & 1) * 8 + ln + 16 * qq) * 8;
        int src = lt * 256 + (ln + 8 * qq) * 8;
        *(uint4*)&h1_hi[dst] = *(const uint4*)&s_hi[src];
        *(uint4*)&h1_lo[dst] = *(const uint4*)&s_lo[src];
    }
}

// ============ fused MLP (MFMA hi/lo): [16384,1024] -> 256 -> 256 -> 1 ===
#define S1 264
#define S2 260
__global__ __launch_bounds__(256) void k_mlp(const unsigned short* __restrict__ h1_hi,
                                             const unsigned short* __restrict__ h1_lo,
                                             const unsigned short* __restrict__ w0tt_hi,
                                             const unsigned short* __restrict__ w0tt_lo,
                                             const float* __restrict__ b0,
                                             const unsigned short* __restrict__ w1tt_hi,
                                             const unsigned short* __restrict__ w1tt_lo,
                                             const float* __restrict__ b1,
                                             const float* __restrict__ w2,
                                             const float* __restrict__ b2,
                                             float* __restrict__ out) {
    __shared__ unsigned short xs_hi[16 * S1];
    __shared__ unsigned short xs_lo[16 * S1];
    __shared__ float xs2[16 * S2];
    const int tid = threadIdx.x;
    const int wv = tid >> 6, l = tid & 63;
    const int lr = l & 15, lg = l >> 4;
    const int row0 = blockIdx.x * 16;

    f32x4 acc[4];
#pragma unroll
    for (int t = 0; t < 4; ++t) {
        float bv = b0[wv * 64 + t * 16 + lr];
        acc[t] = (f32x4){bv, bv, bv, bv};
    }
    for (int kc = 0; kc < 32; ++kc) {
        const size_t aoff = ((size_t)blockIdx.x * 32 + kc) * 512 + l * 8;
        bf16x8 ahi = *(const bf16x8*)(h1_hi + aoff);
        bf16x8 alo = *(const bf16x8*)(h1_lo + aoff);
#pragma unroll
        for (int t = 0; t < 4; ++t) {
            size_t boff = ((size_t)(wv * 4 + t) * 32 + kc) * 512 + l * 8;
            bf16x8 bhi = *(const bf16x8*)(w0tt_hi + boff);
            bf16x8 blo = *(const bf16x8*)(w0tt_lo + boff);
            acc[t] = __builtin_amdgcn_mfma_f32_16x16x32_bf16(ahi, bhi, acc[t], 0, 0, 0);
            acc[t] = __builtin_amdgcn_mfma_f32_16x16x32_bf16(alo, bhi, acc[t], 0, 0, 0);
            acc[t] = __builtin_amdgcn_mfma_f32_16x16x32_bf16(ahi, blo, acc[t], 0, 0, 0);
        }
    }
#pragma unroll
    for (int t = 0; t < 4; ++t)
#pragma unroll
        for (int r = 0; r < 4; ++r) {
            float v = tanhf(acc[t][r]);
            unsigned short h = f2bf(v);
            int o = (lg * 4 + r) * S1 + wv * 64 + t * 16 + lr;
            xs_hi[o] = h;
            xs_lo[o] = f2bf(v - bf2f(h));
        }
    __syncthreads();

    f32x4 acc2[4];
#pragma unroll
    for (int t = 0; t < 4; ++t) {
        float bv = b1[wv * 64 + t * 16 + lr];
        acc2[t] = (f32x4){bv, bv, bv, bv};
    }
    for (int kc = 0; kc < 8; ++kc) {
        const int aoff = lr * S1 + kc * 32 + lg * 8;
        bf16x8 ahi = *(const bf16x8*)(xs_hi + aoff);
        bf16x8 alo = *(const bf16x8*)(xs_lo + aoff);
#pragma unroll
        for (int t = 0; t < 4; ++t) {
            size_t boff = ((size_t)(wv * 4 + t) * 8 + kc) * 512 + l * 8;
            bf16x8 bhi = *(const bf16x8*)(w1tt_hi + boff);
            bf16x8 blo = *(const bf16x8*)(w1tt_lo + boff);
            acc2[t] = __builtin_amdgcn_mfma_f32_16x16x32_bf16(ahi, bhi, acc2[t], 0, 0, 0);
            acc2[t] = __builtin_amdgcn_mfma_f32_16x16x32_bf16(alo, bhi, acc2[t], 0, 0, 0);
            acc2[t] = __builtin_amdgcn_mfma_f32_16x16x32_bf16(ahi, blo, acc2[t], 0, 0, 0);
        }
    }
#pragma unroll
    for (int t = 0; t < 4; ++t)
#pragma unroll
        for (int r = 0; r < 4; ++r)
            xs2[(lg * 4 + r) * S2 + wv * 64 + t * 16 + lr] = tanhf(acc2[t][r]);
    __syncthreads();

    {
        const int row = tid >> 4, seg = tid & 15;
        float p = 0.f;
#pragma unroll
        for (int c = 0; c < 16; ++c)
            p += xs2[row * S2 + seg * 16 + c] * w2[seg * 16 + c];
        p += __shfl_xor(p, 1);
        p += __shfl_xor(p, 2);
        p += __shfl_xor(p, 4);
        p += __shfl_xor(p, 8);
        if (seg == 0) out[row0 + row] = p + b2[0];
    }
}

extern "C" void kernel_launch(void* const* d_in, const int* in_sizes, int n_in,
                              void* d_out, int out_size, void* d_ws, size_t ws_size,
                              hipStream_t stream) {
    const float* obs  = (const float*)d_in[0];
    const int*   edge = (const int*)d_in[1];
    const float* ws0  = (const float*)d_in[2];
    const float* bs0  = (const float*)d_in[3];
    const float* wn0  = (const float*)d_in[4];
    const float* bn0  = (const float*)d_in[5];
    const float* ws1  = (const float*)d_in[6];
    const float* bs1  = (const float*)d_in[7];
    const float* wn1  = (const float*)d_in[8];
    const float* bn1  = (const float*)d_in[9];
    const float* w0   = (const float*)d_in[10];
    const float* b0   = (const float*)d_in[11];
    const float* w1   = (const float*)d_in[12];
    const float* b1   = (const float*)d_in[13];
    const float* w2   = (const float*)d_in[14];
    const float* b2   = (const float*)d_in[15];
    float* out = (float*)d_out;

    char* wsb = (char*)d_ws;
    // pairs (8 MB) and agg0 (8 MB) alias: pairs dead before k_agg0 writes.
    int2*  pairs  = (int2*)wsb;                                 // NE int2
    float* agg0   = (float*)wsb;                                // NN*16 f32
    int*   bcnt   = (int*)(wsb + (size_t)NE * 8);               // 256
    int*   bbase  = bcnt + 256;                                 // 257
    int*   bcur   = bbase + 257;                                // 256
    int*   bsum   = bcur + 256;                                 // 256
    int*   boff   = bsum + 256;                                 // 256
    int*   deg    = boff + 256 + 3;                             // NN (8B aligned)
    int*   off    = deg + NN;                                   // NN+1
    int*   csr    = off + NN + 1;                               // NE
    unsigned short* y1b     = (unsigned short*)(csr + NE);      // NN*64
    unsigned short* h1_hi   = y1b + (size_t)NN * 64;            // ROWS*1024
    unsigned short* h1_lo   = h1_hi + (size_t)ROWS * 1024;
    unsigned short* w0tt_hi = h1_lo + (size_t)ROWS * 1024;      // 256x1024
    unsigned short* w0tt_lo = w0tt_hi + 256 * 1024;
    unsigned short* w1tt_hi = w0tt_lo + 256 * 1024;             // 256x256
    unsigned short* w1tt_lo = w1tt_hi + 256 * 256;
    unsigned short* ws1tt_hi = w1tt_lo + 256 * 256;             // 64x128
    unsigned short* ws1tt_lo = ws1tt_hi + 64 * 128;
    unsigned short* wn1tt_hi = ws1tt_lo + 64 * 128;
    unsigned short* wn1tt_lo = wn1tt_hi + 64 * 128;

    hipMemsetAsync(bcnt, 0, 256 * sizeof(int), stream);

    k_prep<<<dim3(1024), dim3(256), 0, stream>>>(w0,  w0tt_hi, w0tt_lo, 8, 255, 32, 1024 * 256);
    k_prep<<<dim3(256),  dim3(256), 0, stream>>>(w1,  w1tt_hi, w1tt_lo, 8, 255, 8,  256 * 256);
    k_prep<<<dim3(32),   dim3(256), 0, stream>>>(ws1, ws1tt_hi, ws1tt_lo, 6, 63, 4, 128 * 64);
    k_prep<<<dim3(32),   dim3(256), 0, stream>>>(wn1, wn1tt_hi, wn1tt_lo, 6, 63, 4, 128 * 64);

    k_hist256<<<dim3(NE / 1024), dim3(256), 0, stream>>>(edge, bcnt);
    k_scan256<<<dim3(1),         dim3(256), 0, stream>>>(bcnt, bbase, bcur);
    k_bucket <<<dim3(NE / 4096), dim3(256), 0, stream>>>(edge, bcur, pairs);
    k_deg    <<<dim3(256),       dim3(256), 0, stream>>>(pairs, bbase, deg);
    k_scanA  <<<dim3(256),       dim3(256), 0, stream>>>(deg, bsum);
    k_scanB  <<<dim3(1),         dim3(256), 0, stream>>>(bsum, boff);
    k_scanC  <<<dim3(256),       dim3(256), 0, stream>>>(deg, boff, off);
    k_sort   <<<dim3(256),       dim3(256), 0, stream>>>(pairs, bbase, off, csr);

    k_agg0   <<<dim3(NN * 16 / 256), dim3(256), 0, stream>>>(obs, off, csr, agg0);
    k_f01    <<<dim3(NN / 64),       dim3(256), 0, stream>>>(obs, agg0, off, ws0, bs0, wn0, bn0,
                                                             ws1tt_hi, ws1tt_lo, wn1tt_hi, wn1tt_lo,
                                                             bs1, h1_hi, h1_lo, y1b);
    k_agg1f  <<<dim3(NN / 64),       dim3(256), 0, stream>>>(y1b, off, csr, bn1, h1_hi, h1_lo);
    k_mlp    <<<dim3(ROWS / 16),     dim3(256), 0, stream>>>(h1_hi, h1_lo, w0tt_hi, w0tt_lo, b0, w1tt_hi, w1tt_lo, b1, w2, b2, out);
}

// Round 12
// 227.210 us; speedup vs baseline: 4.3733x; 1.1129x over previous
//
#include <hip/hip_runtime.h>

#define STEPS 64
#define NUM_CPU 4
#define AGENTS 64
#define PHASES 8
#define NN (STEPS*NUM_CPU*AGENTS*PHASES)   // 131072 nodes
#define NE (NN*8)                          // 1048576 edges
#define ROWS (NN/PHASES)                   // 16384 MLP rows

typedef __attribute__((ext_vector_type(8))) short bf16x8;
typedef __attribute__((ext_vector_type(4))) float f32x4;

__device__ inline unsigned short f2bf(float x) {
    unsigned int b = __float_as_uint(x);
    return (unsigned short)((b + 0x7FFF + ((b >> 16) & 1)) >> 16);
}
__device__ inline float bf2f(unsigned short h) {
    return __uint_as_float(((unsigned int)h) << 16);
}
__device__ inline void split8(const float* a, bf16x8& hi, bf16x8& lo) {
#pragma unroll
    for (int i = 0; i < 8; ++i) {
        float x = a[i];
        unsigned short h = f2bf(x);
        hi[i] = (short)h;
        lo[i] = (short)f2bf(x - bf2f(h));
    }
}

// fragment-tile offset: value (n, k) lives at
//   ((n>>4)*TK + (k>>5))*512 + ((n&15) + 16*((k>>3)&3))*8 + (k&7),  TK=K/32.

// ============ bucketed counting sort (all global writes coalesced) ======
__global__ __launch_bounds__(256) void k_hist256(const int* __restrict__ edge,
                                                 int* __restrict__ bcnt) {
    __shared__ int c[256];
    const int tid = threadIdx.x;
    c[tid] = 0;
    __syncthreads();
    const int base = blockIdx.x * 1024;
    for (int i = tid; i < 1024; i += 256)
        atomicAdd(&c[edge[NE + base + i] >> 9], 1);
    __syncthreads();
    atomicAdd(&bcnt[tid], c[tid]);
}

__global__ __launch_bounds__(256) void k_scan256(const int* __restrict__ bcnt,
                                                 int* __restrict__ bbase,
                                                 int* __restrict__ bcur) {
    __shared__ int s[256];
    const int t = threadIdx.x;
    int v = bcnt[t];
    s[t] = v;
    __syncthreads();
    for (int d = 1; d < 256; d <<= 1) {
        int x = (t >= d) ? s[t - d] : 0;
        __syncthreads();
        s[t] += x;
        __syncthreads();
    }
    int ex = s[t] - v;
    bbase[t] = ex;
    bcur[t] = ex;
    if (t == 255) bbase[256] = s[255];
}

__global__ __launch_bounds__(256) void k_bucket(const int* __restrict__ edge,
                                                int* __restrict__ bcur,
                                                int2* __restrict__ pairs) {
    __shared__ int rs[4096], rd[4096];
    __shared__ int ss[4096], sd[4096];
    __shared__ int cnt[256], lbase[256], lcur[256], gbase[256];
    const int tid = threadIdx.x;
    const int e0 = blockIdx.x * 4096;
    cnt[tid] = 0;
    for (int i = tid; i < 4096; i += 256) {
        rs[i] = edge[e0 + i];
        rd[i] = edge[NE + e0 + i];
    }
    __syncthreads();
    for (int i = tid; i < 4096; i += 256) atomicAdd(&cnt[rd[i] >> 9], 1);
    __syncthreads();
    {
        const int v = cnt[tid];
        lbase[tid] = v;
        __syncthreads();
        for (int d = 1; d < 256; d <<= 1) {
            int x = (tid >= d) ? lbase[tid - d] : 0;
            __syncthreads();
            lbase[tid] += x;
            __syncthreads();
        }
        const int ex = lbase[tid] - v;
        lbase[tid] = ex;
        lcur[tid] = ex;
        gbase[tid] = atomicAdd(&bcur[tid], v);
    }
    __syncthreads();
    for (int i = tid; i < 4096; i += 256) {
        int b = rd[i] >> 9;
        int p = atomicAdd(&lcur[b], 1);
        ss[p] = rs[i];
        sd[p] = rd[i];
    }
    __syncthreads();
    for (int j = tid; j < 4096; j += 256) {
        int b = sd[j] >> 9;
        pairs[gbase[b] + (j - lbase[b])] = (int2){ss[j], sd[j]};
    }
}

__global__ __launch_bounds__(256) void k_deg(const int2* __restrict__ pairs,
                                             const int* __restrict__ bbase,
                                             int* __restrict__ deg) {
    __shared__ int c[512];
    const int b = blockIdx.x, tid = threadIdx.x;
    c[tid] = 0; c[tid + 256] = 0;
    __syncthreads();
    const int n0 = bbase[b], n1 = bbase[b + 1];
    for (int j = n0 + tid; j < n1; j += 256) atomicAdd(&c[pairs[j].y & 511], 1);
    __syncthreads();
    deg[b * 512 + tid] = c[tid];
    deg[b * 512 + 256 + tid] = c[tid + 256];
}

__global__ __launch_bounds__(256) void k_scanA(const int* __restrict__ deg,
                                               int* __restrict__ bsum) {
    __shared__ int s[256];
    const int b = blockIdx.x, t = threadIdx.x;
    const int2 v = *(const int2*)&deg[b * 512 + t * 2];
    s[t] = v.x + v.y;
    __syncthreads();
    for (int d = 128; d; d >>= 1) {
        if (t < d) s[t] += s[t + d];
        __syncthreads();
    }
    if (t == 0) bsum[b] = s[0];
}

__global__ __launch_bounds__(256) void k_scanB(const int* __restrict__ bsum,
                                               int* __restrict__ boff) {
    __shared__ int s[256];
    const int t = threadIdx.x;
    int v = bsum[t];
    s[t] = v;
    __syncthreads();
    for (int d = 1; d < 256; d <<= 1) {
        int x = (t >= d) ? s[t - d] : 0;
        __syncthreads();
        s[t] += x;
        __syncthreads();
    }
    boff[t] = s[t] - v;
}

__global__ __launch_bounds__(256) void k_scanC(const int* __restrict__ deg,
                                               const int* __restrict__ boff,
                                               int* __restrict__ off) {
    __shared__ int s[256];
    const int b = blockIdx.x, t = threadIdx.x;
    const int2 v = *(const int2*)&deg[b * 512 + t * 2];
    const int pair = v.x + v.y;
    s[t] = pair;
    __syncthreads();
    for (int d = 1; d < 256; d <<= 1) {
        int x = (t >= d) ? s[t - d] : 0;
        __syncthreads();
        s[t] += x;
        __syncthreads();
    }
    int pre = boff[b] + s[t] - pair;
    int i0 = b * 512 + t * 2;
    off[i0] = pre;
    off[i0 + 1] = pre + v.x;
    if (b == 255 && t == 255) off[NN] = pre + pair;
}

__global__ __launch_bounds__(256) void k_sort(const int2* __restrict__ pairs,
                                              const int* __restrict__ bbase,
                                              const int* __restrict__ off,
                                              int* __restrict__ csr) {
    __shared__ int lcur[512];
    __shared__ int sorted[6144];
    const int b = blockIdx.x, tid = threadIdx.x;
    const int off0 = off[b * 512];
    lcur[tid] = off[b * 512 + tid] - off0;
    lcur[tid + 256] = off[b * 512 + 256 + tid] - off0;
    __syncthreads();
    const int n0 = bbase[b], n1 = bbase[b + 1];
    for (int j = n0 + tid; j < n1; j += 256) {
        int2 p = pairs[j];
        int loc = atomicAdd(&lcur[p.y & 511], 1);
        sorted[loc] = p.x;
    }
    __syncthreads();
    const int cnt = n1 - n0;
    for (int j = tid; j < cnt; j += 256) csr[off0 + j] = sorted[j];
}

// ===== weight prep: src[K][N] f32 -> fragment-tile bf16 hi/lo planes ====
__global__ __launch_bounds__(256) void k_prep(const float* __restrict__ src,
                                              unsigned short* __restrict__ dhi,
                                              unsigned short* __restrict__ dlo,
                                              int nshift, int nmask, int tk, int total) {
    int gid = blockIdx.x * 256 + threadIdx.x;
    if (gid >= total) return;
    int k = gid >> nshift, n = gid & nmask;
    float x = src[gid];
    unsigned short h = f2bf(x);
    size_t o = ((size_t)(n >> 4) * tk + (k >> 5)) * 512
             + ((n & 15) + 16 * ((k >> 3) & 3)) * 8 + (k & 7);
    dhi[o] = h;
    dlo[o] = f2bf(x - bf2f(h));
}

// ================= layer 0: per-node aggregate of obs (16 feats) ========
__global__ __launch_bounds__(256) void k_agg0(const float* __restrict__ obs,
                                              const int* __restrict__ off,
                                              const int* __restrict__ csr,
                                              float* __restrict__ agg0) {
    int gid = blockIdx.x * 256 + threadIdx.x;
    int node = gid >> 4, f = gid & 15;
    if (node >= NN) return;
    int e0 = off[node], e1 = off[node + 1];
    float s0 = 0.f, s1 = 0.f, s2 = 0.f, s3 = 0.f;
    int e = e0;
    for (; e + 3 < e1; e += 4) {
        s0 += obs[csr[e] * 16 + f];
        s1 += obs[csr[e + 1] * 16 + f];
        s2 += obs[csr[e + 2] * 16 + f];
        s3 += obs[csr[e + 3] * 16 + f];
    }
    for (; e < e1; ++e) s0 += obs[csr[e] * 16 + f];
    agg0[node * 16 + f] = (s0 + s1) + (s2 + s3);
}

// ==== FUSED layer-0 transform + layer-1 GEMMs (MFMA hi/lo), 64 nodes/blk
//  h1 is now a SINGLE bf16 plane (MLP tolerates single rounding).
__global__ __launch_bounds__(256) void k_f01(const float* __restrict__ obs,
                                             const float* __restrict__ agg0,
                                             const int* __restrict__ off,
                                             const float* __restrict__ ws0,
                                             const float* __restrict__ bs0,
                                             const float* __restrict__ wn0,
                                             const float* __restrict__ bn0,
                                             const unsigned short* __restrict__ ws1tt_hi,
                                             const unsigned short* __restrict__ ws1tt_lo,
                                             const unsigned short* __restrict__ wn1tt_hi,
                                             const unsigned short* __restrict__ wn1tt_lo,
                                             const float* __restrict__ bs1,
                                             unsigned short* __restrict__ h1b,
                                             unsigned short* __restrict__ y1b) {
    __shared__ float w0s[16 * 64];
    __shared__ float w0n[16 * 64];
    __shared__ float biasS[64], biasN[64];
    __shared__ __align__(16) unsigned short s_hi[16 * 256];
    const int tid = threadIdx.x;
    for (int t = tid; t < 1024; t += 256) { w0s[t] = ws0[t]; w0n[t] = wn0[t]; }
    if (tid < 64) { biasS[tid] = bs0[tid]; biasN[tid] = bn0[tid]; }
    __syncthreads();

    const int wv = tid >> 6, l = tid & 63;
    const int lr = l & 15, lg = l >> 4;
    const int nt = blockIdx.x;
    const int tile = nt * 4 + wv;
    const int node = tile * 16 + lr;

    float xin[16], ain[16];
    {
        const float* xp = obs + (size_t)node * 16;
        const float* ap = agg0 + (size_t)node * 16;
#pragma unroll
        for (int q = 0; q < 4; ++q) {
            *(float4*)&xin[q * 4] = *(const float4*)(xp + q * 4);
            *(float4*)&ain[q * 4] = *(const float4*)(ap + q * 4);
        }
        int d = off[node + 1] - off[node];
        float inv = 1.f / (float)(d < 1 ? 1 : d);
#pragma unroll
        for (int k = 0; k < 16; ++k) ain[k] *= inv;
    }

    bf16x8 ahi[4], alo[4];
#pragma unroll
    for (int kc = 0; kc < 4; ++kc) {
        const int half = kc >> 1;
        const int jb = (kc & 1) * 32 + lg * 8;
        const float* w = half ? w0n : w0s;
        const float* bias = half ? biasN : biasS;
        const float* in = half ? ain : xin;
        float a8[8];
#pragma unroll
        for (int i = 0; i < 8; ++i) a8[i] = bias[jb + i];
        for (int k = 0; k < 16; ++k) {
            const float xv = in[k];
            const float4 wa = *(const float4*)&w[k * 64 + jb];
            const float4 wb = *(const float4*)&w[k * 64 + jb + 4];
            a8[0] += xv * wa.x; a8[1] += xv * wa.y;
            a8[2] += xv * wa.z; a8[3] += xv * wa.w;
            a8[4] += xv * wb.x; a8[5] += xv * wb.y;
            a8[6] += xv * wb.z; a8[7] += xv * wb.w;
        }
#pragma unroll
        for (int i = 0; i < 8; ++i) a8[i] = a8[i] > 0.f ? a8[i] : 0.f;
        split8(a8, ahi[kc], alo[kc]);
    }

    f32x4 acc[8];
#pragma unroll
    for (int t = 0; t < 8; ++t) {
        float bv = (t < 4) ? bs1[t * 16 + lr] : 0.f;
        acc[t] = (f32x4){bv, bv, bv, bv};
    }
#pragma unroll
    for (int kc = 0; kc < 4; ++kc) {
#pragma unroll
        for (int t = 0; t < 8; ++t) {
            const unsigned short* bh = (t < 4) ? ws1tt_hi : wn1tt_hi;
            const unsigned short* bl = (t < 4) ? ws1tt_lo : wn1tt_lo;
            size_t boff = ((size_t)(t & 3) * 4 + kc) * 512 + l * 8;
            bf16x8 bhi = *(const bf16x8*)(bh + boff);
            bf16x8 blo = *(const bf16x8*)(bl + boff);
            acc[t] = __builtin_amdgcn_mfma_f32_16x16x32_bf16(ahi[kc], bhi, acc[t], 0, 0, 0);
            acc[t] = __builtin_amdgcn_mfma_f32_16x16x32_bf16(alo[kc], bhi, acc[t], 0, 0, 0);
            acc[t] = __builtin_amdgcn_mfma_f32_16x16x32_bf16(ahi[kc], blo, acc[t], 0, 0, 0);
        }
    }

#pragma unroll
    for (int t = 0; t < 8; ++t) {
#pragma unroll
        for (int r = 0; r < 4; ++r) {
            const int nl = wv * 16 + lg * 4 + r;
            const size_t gnode = (size_t)nt * 64 + nl;
            if (t < 4) {
                float v = acc[t][r];
                v = v > 0.f ? v : 0.f;
                const int c = t * 16 + lr;
                const int lt = (nl & 7) * 2 + (c >> 5);
                const int o = lt * 256 + ((nl >> 3) + 8 * ((c >> 3) & 3)) * 8 + (c & 7);
                s_hi[o] = f2bf(v);
            } else {
                y1b[gnode * 64 + (t - 4) * 16 + lr] = f2bf(acc[t][r]);
            }
        }
    }
    __syncthreads();
    for (int idx = tid; idx < 512; idx += 256) {
        int lt = idx >> 5, sub = idx & 31;
        int ln = sub & 7, qq = sub >> 3;
        size_t g = (size_t)(nt >> 1) * 32 + (lt >> 1) * 4 + (lt & 1);
        size_t dst = g * 512 + (size_t)((nt & 1) * 8 + ln + 16 * qq) * 8;
        int src = lt * 256 + (ln + 8 * qq) * 8;
        *(uint4*)&h1b[dst] = *(const uint4*)&s_hi[src];
    }
}

// ==== layer-1 neighbor aggregate (bf16 gather) + epilogue, 64/block =====
__global__ __launch_bounds__(256) void k_agg1f(const unsigned short* __restrict__ y1b,
                                               const int* __restrict__ off,
                                               const int* __restrict__ csr,
                                               const float* __restrict__ bn1,
                                               unsigned short* __restrict__ h1b) {
    __shared__ __align__(16) unsigned short s_hi[16 * 256];
    const int tid = threadIdx.x;
    const int wv = tid >> 6, lane = tid & 63;
    const int nt = blockIdx.x;
    const float bias = bn1[lane];
    const int q = (lane >> 3) & 3, e7 = lane & 7, hi = lane >> 5;

    for (int i = 0; i < 16; ++i) {
        int nl = wv * 16 + i;
        int node = nt * 64 + nl;
        int e0 = off[node], e1 = off[node + 1];
        float s0 = 0.f, s1 = 0.f, s2 = 0.f, s3 = 0.f;
        int e = e0;
        for (; e + 3 < e1; e += 4) {
            s0 += bf2f(y1b[(size_t)csr[e] * 64 + lane]);
            s1 += bf2f(y1b[(size_t)csr[e + 1] * 64 + lane]);
            s2 += bf2f(y1b[(size_t)csr[e + 2] * 64 + lane]);
            s3 += bf2f(y1b[(size_t)csr[e + 3] * 64 + lane]);
        }
        for (; e < e1; ++e) s0 += bf2f(y1b[(size_t)csr[e] * 64 + lane]);
        float s = (s0 + s1) + (s2 + s3);
        int d = e1 - e0;
        float v = s / (float)(d < 1 ? 1 : d) + bias;
        v = v > 0.f ? v : 0.f;
        int lt = (nl & 7) * 2 + hi;
        int o = lt * 256 + ((nl >> 3) + 8 * q) * 8 + e7;
        s_hi[o] = f2bf(v);
    }
    __syncthreads();
    for (int idx = tid; idx < 512; idx += 256) {
        int lt = idx >> 5, sub = idx & 31;
        int ln = sub & 7, qq = sub >> 3;
        size_t g = (size_t)(nt >> 1) * 32 + (lt >> 1) * 4 + 2 + (lt & 1);
        size_t dst = g * 512 + (size_t)((nt & 1) * 8 + ln + 16 * qq) * 8;
        int src = lt * 256 + (ln + 8 * qq) * 8;
        *(uint4*)&h1b[dst] = *(const uint4*)&s_hi[src];
    }
}

// ====== fused MLP (pure bf16 MFMA): [16384,1024] -> 256 -> 256 -> 1 =====
#define S1 264                                     // bf16 LDS row stride
__global__ __launch_bounds__(256) void k_mlp(const unsigned short* __restrict__ h1b,
                                             const unsigned short* __restrict__ w0tt,
                                             const float* __restrict__ b0,
                                             const unsigned short* __restrict__ w1tt,
                                             const float* __restrict__ b1,
                                             const float* __restrict__ w2,
                                             const float* __restrict__ b2,
                                             float* __restrict__ out) {
    __shared__ unsigned short xs[16 * S1];         // layer-0 tanh out (bf16)
    __shared__ unsigned short xs2[16 * S1];        // layer-1 tanh out (bf16)
    const int tid = threadIdx.x;
    const int wv = tid >> 6, l = tid & 63;
    const int lr = l & 15, lg = l >> 4;
    const int row0 = blockIdx.x * 16;

    // ---- layer 0: 1024 -> 256 (wave = 64-col quadrant) ----
    f32x4 acc[4];
#pragma unroll
    for (int t = 0; t < 4; ++t) {
        float bv = b0[wv * 64 + t * 16 + lr];
        acc[t] = (f32x4){bv, bv, bv, bv};
    }
    for (int kc = 0; kc < 32; ++kc) {
        bf16x8 a = *(const bf16x8*)(h1b + ((size_t)blockIdx.x * 32 + kc) * 512 + l * 8);
#pragma unroll
        for (int t = 0; t < 4; ++t) {
            bf16x8 b = *(const bf16x8*)(w0tt + ((size_t)(wv * 4 + t) * 32 + kc) * 512 + l * 8);
            acc[t] = __builtin_amdgcn_mfma_f32_16x16x32_bf16(a, b, acc[t], 0, 0, 0);
        }
    }
#pragma unroll
    for (int t = 0; t < 4; ++t)
#pragma unroll
        for (int r = 0; r < 4; ++r)
            xs[(lg * 4 + r) * S1 + wv * 64 + t * 16 + lr] = f2bf(tanhf(acc[t][r]));
    __syncthreads();

    // ---- layer 1: 256 -> 256 ----
    f32x4 acc2[4];
#pragma unroll
    for (int t = 0; t < 4; ++t) {
        float bv = b1[wv * 64 + t * 16 + lr];
        acc2[t] = (f32x4){bv, bv, bv, bv};
    }
    for (int kc = 0; kc < 8; ++kc) {
        bf16x8 a = *(const bf16x8*)(xs + lr * S1 + kc * 32 + lg * 8);
#pragma unroll
        for (int t = 0; t < 4; ++t) {
            bf16x8 b = *(const bf16x8*)(w1tt + ((size_t)(wv * 4 + t) * 8 + kc) * 512 + l * 8);
            acc2[t] = __builtin_amdgcn_mfma_f32_16x16x32_bf16(a, b, acc2[t], 0, 0, 0);
        }
    }
#pragma unroll
    for (int t = 0; t < 4; ++t)
#pragma unroll
        for (int r = 0; r < 4; ++r)
            xs2[(lg * 4 + r) * S1 + wv * 64 + t * 16 + lr] = f2bf(tanhf(acc2[t][r]));
    __syncthreads();

    // ---- layer 2: 256 -> 1; thread = (row, 16-col segment) ----
    {
        const int row = tid >> 4, seg = tid & 15;
        float p = 0.f;
#pragma unroll
        for (int c = 0; c < 16; ++c)
            p += bf2f(xs2[row * S1 + seg * 16 + c]) * w2[seg * 16 + c];
        p += __shfl_xor(p, 1);
        p += __shfl_xor(p, 2);
        p += __shfl_xor(p, 4);
        p += __shfl_xor(p, 8);
        if (seg == 0) out[row0 + row] = p + b2[0];
    }
}

extern "C" void kernel_launch(void* const* d_in, const int* in_sizes, int n_in,
                              void* d_out, int out_size, void* d_ws, size_t ws_size,
                              hipStream_t stream) {
    const float* obs  = (const float*)d_in[0];
    const int*   edge = (const int*)d_in[1];
    const float* ws0  = (const float*)d_in[2];
    const float* bs0  = (const float*)d_in[3];
    const float* wn0  = (const float*)d_in[4];
    const float* bn0  = (const float*)d_in[5];
    const float* ws1  = (const float*)d_in[6];
    const float* bs1  = (const float*)d_in[7];
    const float* wn1  = (const float*)d_in[8];
    const float* bn1  = (const float*)d_in[9];
    const float* w0   = (const float*)d_in[10];
    const float* b0   = (const float*)d_in[11];
    const float* w1   = (const float*)d_in[12];
    const float* b1   = (const float*)d_in[13];
    const float* w2   = (const float*)d_in[14];
    const float* b2   = (const float*)d_in[15];
    float* out = (float*)d_out;

    char* wsb = (char*)d_ws;
    // pairs (8 MB) and agg0 (8 MB) alias: pairs dead before k_agg0 writes.
    int2*  pairs  = (int2*)wsb;                                 // NE int2
    float* agg0   = (float*)wsb;                                // NN*16 f32
    int*   bcnt   = (int*)(wsb + (size_t)NE * 8);               // 256
    int*   bbase  = bcnt + 256;                                 // 257
    int*   bcur   = bbase + 257;                                // 256
    int*   bsum   = bcur + 256;                                 // 256
    int*   boff   = bsum + 256;                                 // 256
    int*   deg    = boff + 256 + 3;                             // NN (8B aligned)
    int*   off    = deg + NN;                                   // NN+1
    int*   csr    = off + NN + 1;                               // NE
    unsigned short* y1b     = (unsigned short*)(csr + NE);      // NN*64
    unsigned short* h1b     = y1b + (size_t)NN * 64;            // ROWS*1024
    unsigned short* w0tt_hi = h1b + (size_t)ROWS * 1024;        // 256x1024
    unsigned short* w0tt_lo = w0tt_hi + 256 * 1024;
    unsigned short* w1tt_hi = w0tt_lo + 256 * 1024;             // 256x256
    unsigned short* w1tt_lo = w1tt_hi + 256 * 256;
    unsigned short* ws1tt_hi = w1tt_lo + 256 * 256;             // 64x128
    unsigned short* ws1tt_lo = ws1tt_hi + 64 * 128;
    unsigned short* wn1tt_hi = ws1tt_lo + 64 * 128;
    unsigned short* wn1tt_lo = wn1tt_hi + 64 * 128;

    hipMemsetAsync(bcnt, 0, 256 * sizeof(int), stream);

    k_prep<<<dim3(1024), dim3(256), 0, stream>>>(w0,  w0tt_hi, w0tt_lo, 8, 255, 32, 1024 * 256);
    k_prep<<<dim3(256),  dim3(256), 0, stream>>>(w1,  w1tt_hi, w1tt_lo, 8, 255, 8,  256 * 256);
    k_prep<<<dim3(32),   dim3(256), 0, stream>>>(ws1, ws1tt_hi, ws1tt_lo, 6, 63, 4, 128 * 64);
    k_prep<<<dim3(32),   dim3(256), 0, stream>>>(wn1, wn1tt_hi, wn1tt_lo, 6, 63, 4, 128 * 64);

    k_hist256<<<dim3(NE / 1024), dim3(256), 0, stream>>>(edge, bcnt);
    k_scan256<<<dim3(1),         dim3(256), 0, stream>>>(bcnt, bbase, bcur);
    k_bucket <<<dim3(NE / 4096), dim3(256), 0, stream>>>(edge, bcur, pairs);
    k_deg    <<<dim3(256),       dim3(256), 0, stream>>>(pairs, bbase, deg);
    k_scanA  <<<dim3(256),       dim3(256), 0, stream>>>(deg, bsum);
    k_scanB  <<<dim3(1),         dim3(256), 0, stream>>>(bsum, boff);
    k_scanC  <<<dim3(256),       dim3(256), 0, stream>>>(deg, boff, off);
    k_sort   <<<dim3(256),       dim3(256), 0, stream>>>(pairs, bbase, off, csr);

    k_agg0   <<<dim3(NN * 16 / 256), dim3(256), 0, stream>>>(obs, off, csr, agg0);
    k_f01    <<<dim3(NN / 64),       dim3(256), 0, stream>>>(obs, agg0, off, ws0, bs0, wn0, bn0,
                                                             ws1tt_hi, ws1tt_lo, wn1tt_hi, wn1tt_lo,
                                                             bs1, h1b, y1b);
    k_agg1f  <<<dim3(NN / 64),       dim3(256), 0, stream>>>(y1b, off, csr, bn1, h1b);
    k_mlp    <<<dim3(ROWS / 16),     dim3(256), 0, stream>>>(h1b, w0tt_hi, b0, w1tt_hi, b1, w2, b2, out);
}

// Round 13
// 208.578 us; speedup vs baseline: 4.7640x; 1.0893x over previous
//
#include <hip/hip_runtime.h>

#define STEPS 64
#define NUM_CPU 4
#define AGENTS 64
#define PHASES 8
#define NN (STEPS*NUM_CPU*AGENTS*PHASES)   // 131072 nodes
#define NE (NN*8)                          // 1048576 edges
#define ROWS (NN/PHASES)                   // 16384 MLP rows

typedef __attribute__((ext_vector_type(8))) short bf16x8;
typedef __attribute__((ext_vector_type(4))) float f32x4;

__device__ inline unsigned short f2bf(float x) {
    unsigned int b = __float_as_uint(x);
    return (unsigned short)((b + 0x7FFF + ((b >> 16) & 1)) >> 16);
}
__device__ inline float bf2f(unsigned short h) {
    return __uint_as_float(((unsigned int)h) << 16);
}
__device__ inline void split8(const float* a, bf16x8& hi, bf16x8& lo) {
#pragma unroll
    for (int i = 0; i < 8; ++i) {
        float x = a[i];
        unsigned short h = f2bf(x);
        hi[i] = (short)h;
        lo[i] = (short)f2bf(x - bf2f(h));
    }
}

// fragment-tile offset: value (n, k) lives at
//   ((n>>4)*TK + (k>>5))*512 + ((n&15) + 16*((k>>3)&3))*8 + (k&7),  TK=K/32.

// ============ bucketed counting sort (all global writes coalesced) ======
__global__ __launch_bounds__(256) void k_hist256(const int* __restrict__ edge,
                                                 int* __restrict__ bcnt) {
    __shared__ int c[256];
    const int tid = threadIdx.x;
    c[tid] = 0;
    __syncthreads();
    const int base = blockIdx.x * 1024;
    for (int i = tid; i < 1024; i += 256)
        atomicAdd(&c[edge[NE + base + i] >> 9], 1);
    __syncthreads();
    atomicAdd(&bcnt[tid], c[tid]);
}

__global__ __launch_bounds__(256) void k_scan256(const int* __restrict__ bcnt,
                                                 int* __restrict__ bbase,
                                                 int* __restrict__ bcur) {
    __shared__ int s[256];
    const int t = threadIdx.x;
    int v = bcnt[t];
    s[t] = v;
    __syncthreads();
    for (int d = 1; d < 256; d <<= 1) {
        int x = (t >= d) ? s[t - d] : 0;
        __syncthreads();
        s[t] += x;
        __syncthreads();
    }
    int ex = s[t] - v;
    bbase[t] = ex;
    bcur[t] = ex;
    if (t == 255) bbase[256] = s[255];
}

__global__ __launch_bounds__(256) void k_bucket(const int* __restrict__ edge,
                                                int* __restrict__ bcur,
                                                int2* __restrict__ pairs) {
    __shared__ int rs[4096], rd[4096];
    __shared__ int ss[4096], sd[4096];
    __shared__ int cnt[256], lbase[256], lcur[256], gbase[256];
    const int tid = threadIdx.x;
    const int e0 = blockIdx.x * 4096;
    cnt[tid] = 0;
    for (int i = tid; i < 4096; i += 256) {
        rs[i] = edge[e0 + i];
        rd[i] = edge[NE + e0 + i];
    }
    __syncthreads();
    for (int i = tid; i < 4096; i += 256) atomicAdd(&cnt[rd[i] >> 9], 1);
    __syncthreads();
    {
        const int v = cnt[tid];
        lbase[tid] = v;
        __syncthreads();
        for (int d = 1; d < 256; d <<= 1) {
            int x = (tid >= d) ? lbase[tid - d] : 0;
            __syncthreads();
            lbase[tid] += x;
            __syncthreads();
        }
        const int ex = lbase[tid] - v;
        lbase[tid] = ex;
        lcur[tid] = ex;
        gbase[tid] = atomicAdd(&bcur[tid], v);
    }
    __syncthreads();
    for (int i = tid; i < 4096; i += 256) {
        int b = rd[i] >> 9;
        int p = atomicAdd(&lcur[b], 1);
        ss[p] = rs[i];
        sd[p] = rd[i];
    }
    __syncthreads();
    for (int j = tid; j < 4096; j += 256) {
        int b = sd[j] >> 9;
        pairs[gbase[b] + (j - lbase[b])] = (int2){ss[j], sd[j]};
    }
}

__global__ __launch_bounds__(256) void k_deg(const int2* __restrict__ pairs,
                                             const int* __restrict__ bbase,
                                             int* __restrict__ deg) {
    __shared__ int c[512];
    const int b = blockIdx.x, tid = threadIdx.x;
    c[tid] = 0; c[tid + 256] = 0;
    __syncthreads();
    const int n0 = bbase[b], n1 = bbase[b + 1];
    for (int j = n0 + tid; j < n1; j += 256) atomicAdd(&c[pairs[j].y & 511], 1);
    __syncthreads();
    deg[b * 512 + tid] = c[tid];
    deg[b * 512 + 256 + tid] = c[tid + 256];
}

__global__ __launch_bounds__(256) void k_scanA(const int* __restrict__ deg,
                                               int* __restrict__ bsum) {
    __shared__ int s[256];
    const int b = blockIdx.x, t = threadIdx.x;
    const int2 v = *(const int2*)&deg[b * 512 + t * 2];
    s[t] = v.x + v.y;
    __syncthreads();
    for (int d = 128; d; d >>= 1) {
        if (t < d) s[t] += s[t + d];
        __syncthreads();
    }
    if (t == 0) bsum[b] = s[0];
}

__global__ __launch_bounds__(256) void k_scanB(const int* __restrict__ bsum,
                                               int* __restrict__ boff) {
    __shared__ int s[256];
    const int t = threadIdx.x;
    int v = bsum[t];
    s[t] = v;
    __syncthreads();
    for (int d = 1; d < 256; d <<= 1) {
        int x = (t >= d) ? s[t - d] : 0;
        __syncthreads();
        s[t] += x;
        __syncthreads();
    }
    boff[t] = s[t] - v;
}

__global__ __launch_bounds__(256) void k_scanC(const int* __restrict__ deg,
                                               const int* __restrict__ boff,
                                               int* __restrict__ off) {
    __shared__ int s[256];
    const int b = blockIdx.x, t = threadIdx.x;
    const int2 v = *(const int2*)&deg[b * 512 + t * 2];
    const int pair = v.x + v.y;
    s[t] = pair;
    __syncthreads();
    for (int d = 1; d < 256; d <<= 1) {
        int x = (t >= d) ? s[t - d] : 0;
        __syncthreads();
        s[t] += x;
        __syncthreads();
    }
    int pre = boff[b] + s[t] - pair;
    int i0 = b * 512 + t * 2;
    off[i0] = pre;
    off[i0 + 1] = pre + v.x;
    if (b == 255 && t == 255) off[NN] = pre + pair;
}

__global__ __launch_bounds__(256) void k_sort(const int2* __restrict__ pairs,
                                              const int* __restrict__ bbase,
                                              const int* __restrict__ off,
                                              int* __restrict__ csr) {
    __shared__ int lcur[512];
    __shared__ int sorted[6144];
    const int b = blockIdx.x, tid = threadIdx.x;
    const int off0 = off[b * 512];
    lcur[tid] = off[b * 512 + tid] - off0;
    lcur[tid + 256] = off[b * 512 + 256 + tid] - off0;
    __syncthreads();
    const int n0 = bbase[b], n1 = bbase[b + 1];
    for (int j = n0 + tid; j < n1; j += 256) {
        int2 p = pairs[j];
        int loc = atomicAdd(&lcur[p.y & 511], 1);
        sorted[loc] = p.x;
    }
    __syncthreads();
    const int cnt = n1 - n0;
    for (int j = tid; j < cnt; j += 256) csr[off0 + j] = sorted[j];
}

// ===== weight prep: src[K][N] f32 -> fragment-tile bf16 hi/lo planes ====
__global__ __launch_bounds__(256) void k_prep(const float* __restrict__ src,
                                              unsigned short* __restrict__ dhi,
                                              unsigned short* __restrict__ dlo,
                                              int nshift, int nmask, int tk, int total) {
    int gid = blockIdx.x * 256 + threadIdx.x;
    if (gid >= total) return;
    int k = gid >> nshift, n = gid & nmask;
    float x = src[gid];
    unsigned short h = f2bf(x);
    size_t o = ((size_t)(n >> 4) * tk + (k >> 5)) * 512
             + ((n & 15) + 16 * ((k >> 3) & 3)) * 8 + (k & 7);
    dhi[o] = h;
    dlo[o] = f2bf(x - bf2f(h));
}

// ========== layer 0: per-node aggregate of obs (16 feats), 8-deep =======
__global__ __launch_bounds__(256) void k_agg0(const float* __restrict__ obs,
                                              const int* __restrict__ off,
                                              const int* __restrict__ csr,
                                              float* __restrict__ agg0) {
    int gid = blockIdx.x * 256 + threadIdx.x;
    int node = gid >> 4, f = gid & 15;
    if (node >= NN) return;
    int e0 = off[node], e1 = off[node + 1];
    float s0 = 0.f, s1 = 0.f, s2 = 0.f, s3 = 0.f;
    float s4 = 0.f, s5 = 0.f, s6 = 0.f, s7 = 0.f;
    int e = e0;
    for (; e + 7 < e1; e += 8) {
        s0 += obs[csr[e] * 16 + f];
        s1 += obs[csr[e + 1] * 16 + f];
        s2 += obs[csr[e + 2] * 16 + f];
        s3 += obs[csr[e + 3] * 16 + f];
        s4 += obs[csr[e + 4] * 16 + f];
        s5 += obs[csr[e + 5] * 16 + f];
        s6 += obs[csr[e + 6] * 16 + f];
        s7 += obs[csr[e + 7] * 16 + f];
    }
    for (; e + 3 < e1; e += 4) {
        s0 += obs[csr[e] * 16 + f];
        s1 += obs[csr[e + 1] * 16 + f];
        s2 += obs[csr[e + 2] * 16 + f];
        s3 += obs[csr[e + 3] * 16 + f];
    }
    for (; e < e1; ++e) s0 += obs[csr[e] * 16 + f];
    agg0[node * 16 + f] = ((s0 + s1) + (s2 + s3)) + ((s4 + s5) + (s6 + s7));
}

// ==== FUSED layer-0 transform + layer-1 GEMMs (MFMA hi/lo), 64 nodes/blk
__global__ __launch_bounds__(256) void k_f01(const float* __restrict__ obs,
                                             const float* __restrict__ agg0,
                                             const int* __restrict__ off,
                                             const float* __restrict__ ws0,
                                             const float* __restrict__ bs0,
                                             const float* __restrict__ wn0,
                                             const float* __restrict__ bn0,
                                             const unsigned short* __restrict__ ws1tt_hi,
                                             const unsigned short* __restrict__ ws1tt_lo,
                                             const unsigned short* __restrict__ wn1tt_hi,
                                             const unsigned short* __restrict__ wn1tt_lo,
                                             const float* __restrict__ bs1,
                                             unsigned short* __restrict__ h1b,
                                             unsigned short* __restrict__ y1b) {
    __shared__ float w0s[16 * 64];
    __shared__ float w0n[16 * 64];
    __shared__ float biasS[64], biasN[64];
    __shared__ __align__(16) unsigned short s_hi[16 * 256];
    const int tid = threadIdx.x;
    for (int t = tid; t < 1024; t += 256) { w0s[t] = ws0[t]; w0n[t] = wn0[t]; }
    if (tid < 64) { biasS[tid] = bs0[tid]; biasN[tid] = bn0[tid]; }
    __syncthreads();

    const int wv = tid >> 6, l = tid & 63;
    const int lr = l & 15, lg = l >> 4;
    const int nt = blockIdx.x;
    const int tile = nt * 4 + wv;
    const int node = tile * 16 + lr;

    float xin[16], ain[16];
    {
        const float* xp = obs + (size_t)node * 16;
        const float* ap = agg0 + (size_t)node * 16;
#pragma unroll
        for (int q = 0; q < 4; ++q) {
            *(float4*)&xin[q * 4] = *(const float4*)(xp + q * 4);
            *(float4*)&ain[q * 4] = *(const float4*)(ap + q * 4);
        }
        int d = off[node + 1] - off[node];
        float inv = 1.f / (float)(d < 1 ? 1 : d);
#pragma unroll
        for (int k = 0; k < 16; ++k) ain[k] *= inv;
    }

    bf16x8 ahi[4], alo[4];
#pragma unroll
    for (int kc = 0; kc < 4; ++kc) {
        const int half = kc >> 1;
        const int jb = (kc & 1) * 32 + lg * 8;
        const float* w = half ? w0n : w0s;
        const float* bias = half ? biasN : biasS;
        const float* in = half ? ain : xin;
        float a8[8];
#pragma unroll
        for (int i = 0; i < 8; ++i) a8[i] = bias[jb + i];
        for (int k = 0; k < 16; ++k) {
            const float xv = in[k];
            const float4 wa = *(const float4*)&w[k * 64 + jb];
            const float4 wb = *(const float4*)&w[k * 64 + jb + 4];
            a8[0] += xv * wa.x; a8[1] += xv * wa.y;
            a8[2] += xv * wa.z; a8[3] += xv * wa.w;
            a8[4] += xv * wb.x; a8[5] += xv * wb.y;
            a8[6] += xv * wb.z; a8[7] += xv * wb.w;
        }
#pragma unroll
        for (int i = 0; i < 8; ++i) a8[i] = a8[i] > 0.f ? a8[i] : 0.f;
        split8(a8, ahi[kc], alo[kc]);
    }

    f32x4 acc[8];
#pragma unroll
    for (int t = 0; t < 8; ++t) {
        float bv = (t < 4) ? bs1[t * 16 + lr] : 0.f;
        acc[t] = (f32x4){bv, bv, bv, bv};
    }
#pragma unroll
    for (int kc = 0; kc < 4; ++kc) {
#pragma unroll
        for (int t = 0; t < 8; ++t) {
            const unsigned short* bh = (t < 4) ? ws1tt_hi : wn1tt_hi;
            const unsigned short* bl = (t < 4) ? ws1tt_lo : wn1tt_lo;
            size_t boff = ((size_t)(t & 3) * 4 + kc) * 512 + l * 8;
            bf16x8 bhi = *(const bf16x8*)(bh + boff);
            bf16x8 blo = *(const bf16x8*)(bl + boff);
            acc[t] = __builtin_amdgcn_mfma_f32_16x16x32_bf16(ahi[kc], bhi, acc[t], 0, 0, 0);
            acc[t] = __builtin_amdgcn_mfma_f32_16x16x32_bf16(alo[kc], bhi, acc[t], 0, 0, 0);
            acc[t] = __builtin_amdgcn_mfma_f32_16x16x32_bf16(ahi[kc], blo, acc[t], 0, 0, 0);
        }
    }

#pragma unroll
    for (int t = 0; t < 8; ++t) {
#pragma unroll
        for (int r = 0; r < 4; ++r) {
            const int nl = wv * 16 + lg * 4 + r;
            const size_t gnode = (size_t)nt * 64 + nl;
            if (t < 4) {
                float v = acc[t][r];
                v = v > 0.f ? v : 0.f;
                const int c = t * 16 + lr;
                const int lt = (nl & 7) * 2 + (c >> 5);
                const int o = lt * 256 + ((nl >> 3) + 8 * ((c >> 3) & 3)) * 8 + (c & 7);
                s_hi[o] = f2bf(v);
            } else {
                y1b[gnode * 64 + (t - 4) * 16 + lr] = f2bf(acc[t][r]);
            }
        }
    }
    __syncthreads();
    for (int idx = tid; idx < 512; idx += 256) {
        int lt = idx >> 5, sub = idx & 31;
        int ln = sub & 7, qq = sub >> 3;
        size_t g = (size_t)(nt >> 1) * 32 + (lt >> 1) * 4 + (lt & 1);
        size_t dst = g * 512 + (size_t)((nt & 1) * 8 + ln + 16 * qq) * 8;
        int src = lt * 256 + (ln + 8 * qq) * 8;
        *(uint4*)&h1b[dst] = *(const uint4*)&s_hi[src];
    }
}

// ==== layer-1 neighbor aggregate (bf16 gather, 8-deep ILP), 64/block ====
__global__ __launch_bounds__(256) void k_agg1f(const unsigned short* __restrict__ y1b,
                                               const int* __restrict__ off,
                                               const int* __restrict__ csr,
                                               const float* __restrict__ bn1,
                                               unsigned short* __restrict__ h1b) {
    __shared__ __align__(16) unsigned short s_hi[16 * 256];
    const int tid = threadIdx.x;
    const int wv = tid >> 6, lane = tid & 63;
    const int nt = blockIdx.x;
    const float bias = bn1[lane];
    const int q = (lane >> 3) & 3, e7 = lane & 7, hi = lane >> 5;

    for (int i = 0; i < 16; ++i) {
        int nl = wv * 16 + i;
        int node = nt * 64 + nl;
        int e0 = off[node], e1 = off[node + 1];
        float s0 = 0.f, s1 = 0.f, s2 = 0.f, s3 = 0.f;
        float s4 = 0.f, s5 = 0.f, s6 = 0.f, s7 = 0.f;
        int e = e0;
        for (; e + 7 < e1; e += 8) {
            s0 += bf2f(y1b[(size_t)csr[e] * 64 + lane]);
            s1 += bf2f(y1b[(size_t)csr[e + 1] * 64 + lane]);
            s2 += bf2f(y1b[(size_t)csr[e + 2] * 64 + lane]);
            s3 += bf2f(y1b[(size_t)csr[e + 3] * 64 + lane]);
            s4 += bf2f(y1b[(size_t)csr[e + 4] * 64 + lane]);
            s5 += bf2f(y1b[(size_t)csr[e + 5] * 64 + lane]);
            s6 += bf2f(y1b[(size_t)csr[e + 6] * 64 + lane]);
            s7 += bf2f(y1b[(size_t)csr[e + 7] * 64 + lane]);
        }
        for (; e + 3 < e1; e += 4) {
            s0 += bf2f(y1b[(size_t)csr[e] * 64 + lane]);
            s1 += bf2f(y1b[(size_t)csr[e + 1] * 64 + lane]);
            s2 += bf2f(y1b[(size_t)csr[e + 2] * 64 + lane]);
            s3 += bf2f(y1b[(size_t)csr[e + 3] * 64 + lane]);
        }
        for (; e < e1; ++e) s0 += bf2f(y1b[(size_t)csr[e] * 64 + lane]);
        float s = ((s0 + s1) + (s2 + s3)) + ((s4 + s5) + (s6 + s7));
        int d = e1 - e0;
        float v = s / (float)(d < 1 ? 1 : d) + bias;
        v = v > 0.f ? v : 0.f;
        int lt = (nl & 7) * 2 + hi;
        int o = lt * 256 + ((nl >> 3) + 8 * q) * 8 + e7;
        s_hi[o] = f2bf(v);
    }
    __syncthreads();
    for (int idx = tid; idx < 512; idx += 256) {
        int lt = idx >> 5, sub = idx & 31;
        int ln = sub & 7, qq = sub >> 3;
        size_t g = (size_t)(nt >> 1) * 32 + (lt >> 1) * 4 + 2 + (lt & 1);
        size_t dst = g * 512 + (size_t)((nt & 1) * 8 + ln + 16 * qq) * 8;
        int src = lt * 256 + (ln + 8 * qq) * 8;
        *(uint4*)&h1b[dst] = *(const uint4*)&s_hi[src];
    }
}

// == fused MLP (pure bf16 MFMA, 32 rows/block, 2-way A reg-block) ========
#define S1 264                                     // bf16 LDS row stride
__global__ __launch_bounds__(256) void k_mlp(const unsigned short* __restrict__ h1b,
                                             const unsigned short* __restrict__ w0tt,
                                             const float* __restrict__ b0,
                                             const unsigned short* __restrict__ w1tt,
                                             const float* __restrict__ b1,
                                             const float* __restrict__ w2,
                                             const float* __restrict__ b2,
                                             float* __restrict__ out) {
    __shared__ unsigned short xs[32 * S1];         // layer-0 tanh out (bf16)
    __shared__ unsigned short xs2[32 * S1];        // layer-1 tanh out (bf16)
    const int tid = threadIdx.x;
    const int wv = tid >> 6, l = tid & 63;
    const int lr = l & 15, lg = l >> 4;
    const int row0 = blockIdx.x * 32;

    // ---- layer 0: 1024 -> 256 (wave = 64-col quadrant, 2 row-tiles) ----
    f32x4 acc[2][4];
#pragma unroll
    for (int t = 0; t < 4; ++t) {
        float bv = b0[wv * 64 + t * 16 + lr];
        acc[0][t] = (f32x4){bv, bv, bv, bv};
        acc[1][t] = (f32x4){bv, bv, bv, bv};
    }
    const size_t at0 = (size_t)(blockIdx.x * 2) * 32;
    for (int kc = 0; kc < 32; ++kc) {
        bf16x8 a0 = *(const bf16x8*)(h1b + (at0 + kc) * 512 + l * 8);
        bf16x8 a1 = *(const bf16x8*)(h1b + (at0 + 32 + kc) * 512 + l * 8);
#pragma unroll
        for (int t = 0; t < 4; ++t) {
            bf16x8 b = *(const bf16x8*)(w0tt + ((size_t)(wv * 4 + t) * 32 + kc) * 512 + l * 8);
            acc[0][t] = __builtin_amdgcn_mfma_f32_16x16x32_bf16(a0, b, acc[0][t], 0, 0, 0);
            acc[1][t] = __builtin_amdgcn_mfma_f32_16x16x32_bf16(a1, b, acc[1][t], 0, 0, 0);
        }
    }
#pragma unroll
    for (int h = 0; h < 2; ++h)
#pragma unroll
        for (int t = 0; t < 4; ++t)
#pragma unroll
            for (int r = 0; r < 4; ++r)
                xs[(h * 16 + lg * 4 + r) * S1 + wv * 64 + t * 16 + lr] = f2bf(tanhf(acc[h][t][r]));
    __syncthreads();

    // ---- layer 1: 256 -> 256 ----
    f32x4 acc2[2][4];
#pragma unroll
    for (int t = 0; t < 4; ++t) {
        float bv = b1[wv * 64 + t * 16 + lr];
        acc2[0][t] = (f32x4){bv, bv, bv, bv};
        acc2[1][t] = (f32x4){bv, bv, bv, bv};
    }
    for (int kc = 0; kc < 8; ++kc) {
        bf16x8 a0 = *(const bf16x8*)(xs + lr * S1 + kc * 32 + lg * 8);
        bf16x8 a1 = *(const bf16x8*)(xs + (16 + lr) * S1 + kc * 32 + lg * 8);
#pragma unroll
        for (int t = 0; t < 4; ++t) {
            bf16x8 b = *(const bf16x8*)(w1tt + ((size_t)(wv * 4 + t) * 8 + kc) * 512 + l * 8);
            acc2[0][t] = __builtin_amdgcn_mfma_f32_16x16x32_bf16(a0, b, acc2[0][t], 0, 0, 0);
            acc2[1][t] = __builtin_amdgcn_mfma_f32_16x16x32_bf16(a1, b, acc2[1][t], 0, 0, 0);
        }
    }
#pragma unroll
    for (int h = 0; h < 2; ++h)
#pragma unroll
        for (int t = 0; t < 4; ++t)
#pragma unroll
            for (int r = 0; r < 4; ++r)
                xs2[(h * 16 + lg * 4 + r) * S1 + wv * 64 + t * 16 + lr] = f2bf(tanhf(acc2[h][t][r]));
    __syncthreads();

    // ---- layer 2: 256 -> 1; thread = (row, 32-col segment) ----
    {
        const int row = tid >> 3, seg = tid & 7;
        float p = 0.f;
#pragma unroll
        for (int c = 0; c < 32; ++c)
            p += bf2f(xs2[row * S1 + seg * 32 + c]) * w2[seg * 32 + c];
        p += __shfl_xor(p, 1);
        p += __shfl_xor(p, 2);
        p += __shfl_xor(p, 4);
        if (seg == 0) out[row0 + row] = p + b2[0];
    }
}

extern "C" void kernel_launch(void* const* d_in, const int* in_sizes, int n_in,
                              void* d_out, int out_size, void* d_ws, size_t ws_size,
                              hipStream_t stream) {
    const float* obs  = (const float*)d_in[0];
    const int*   edge = (const int*)d_in[1];
    const float* ws0  = (const float*)d_in[2];
    const float* bs0  = (const float*)d_in[3];
    const float* wn0  = (const float*)d_in[4];
    const float* bn0  = (const float*)d_in[5];
    const float* ws1  = (const float*)d_in[6];
    const float* bs1  = (const float*)d_in[7];
    const float* wn1  = (const float*)d_in[8];
    const float* bn1  = (const float*)d_in[9];
    const float* w0   = (const float*)d_in[10];
    const float* b0   = (const float*)d_in[11];
    const float* w1   = (const float*)d_in[12];
    const float* b1   = (const float*)d_in[13];
    const float* w2   = (const float*)d_in[14];
    const float* b2   = (const float*)d_in[15];
    float* out = (float*)d_out;

    char* wsb = (char*)d_ws;
    // pairs (8 MB) and agg0 (8 MB) alias: pairs dead before k_agg0 writes.
    int2*  pairs  = (int2*)wsb;                                 // NE int2
    float* agg0   = (float*)wsb;                                // NN*16 f32
    int*   bcnt   = (int*)(wsb + (size_t)NE * 8);               // 256
    int*   bbase  = bcnt + 256;                                 // 257
    int*   bcur   = bbase + 257;                                // 256
    int*   bsum   = bcur + 256;                                 // 256
    int*   boff   = bsum + 256;                                 // 256
    int*   deg    = boff + 256 + 3;                             // NN (8B aligned)
    int*   off    = deg + NN;                                   // NN+1
    int*   csr    = off + NN + 1;                               // NE
    unsigned short* y1b     = (unsigned short*)(csr + NE);      // NN*64
    unsigned short* h1b     = y1b + (size_t)NN * 64;            // ROWS*1024
    unsigned short* w0tt_hi = h1b + (size_t)ROWS * 1024;        // 256x1024
    unsigned short* w0tt_lo = w0tt_hi + 256 * 1024;
    unsigned short* w1tt_hi = w0tt_lo + 256 * 1024;             // 256x256
    unsigned short* w1tt_lo = w1tt_hi + 256 * 256;
    unsigned short* ws1tt_hi = w1tt_lo + 256 * 256;             // 64x128
    unsigned short* ws1tt_lo = ws1tt_hi + 64 * 128;
    unsigned short* wn1tt_hi = ws1tt_lo + 64 * 128;
    unsigned short* wn1tt_lo = wn1tt_hi + 64 * 128;

    hipMemsetAsync(bcnt, 0, 256 * sizeof(int), stream);

    k_prep<<<dim3(1024), dim3(256), 0, stream>>>(w0,  w0tt_hi, w0tt_lo, 8, 255, 32, 1024 * 256);
    k_prep<<<dim3(256),  dim3(256), 0, stream>>>(w1,  w1tt_hi, w1tt_lo, 8, 255, 8,  256 * 256);
    k_prep<<<dim3(32),   dim3(256), 0, stream>>>(ws1, ws1tt_hi, ws1tt_lo, 6, 63, 4, 128 * 64);
    k_prep<<<dim3(32),   dim3(256), 0, stream>>>(wn1, wn1tt_hi, wn1tt_lo, 6, 63, 4, 128 * 64);

    k_hist256<<<dim3(NE / 1024), dim3(256), 0, stream>>>(edge, bcnt);
    k_scan256<<<dim3(1),         dim3(256), 0, stream>>>(bcnt, bbase, bcur);
    k_bucket <<<dim3(NE / 4096), dim3(256), 0, stream>>>(edge, bcur, pairs);
    k_deg    <<<dim3(256),       dim3(256), 0, stream>>>(pairs, bbase, deg);
    k_scanA  <<<dim3(256),       dim3(256), 0, stream>>>(deg, bsum);
    k_scanB  <<<dim3(1),         dim3(256), 0, stream>>>(bsum, boff);
    k_scanC  <<<dim3(256),       dim3(256), 0, stream>>>(deg, boff, off);
    k_sort   <<<dim3(256),       dim3(256), 0, stream>>>(pairs, bbase, off, csr);

    k_agg0   <<<dim3(NN * 16 / 256), dim3(256), 0, stream>>>(obs, off, csr, agg0);
    k_f01    <<<dim3(NN / 64),       dim3(256), 0, stream>>>(obs, agg0, off, ws0, bs0, wn0, bn0,
                                                             ws1tt_hi, ws1tt_lo, wn1tt_hi, wn1tt_lo,
                                                             bs1, h1b, y1b);
    k_agg1f  <<<dim3(NN / 64),       dim3(256), 0, stream>>>(y1b, off, csr, bn1, h1b);
    k_mlp    <<<dim3(ROWS / 32),     dim3(256), 0, stream>>>(h1b, w0tt_hi, b0, w1tt_hi, b1, w2, b2, out);
}